// Round 1
// baseline (1066.225 us; speedup 1.0000x reference)
//
#include <hip/hip_runtime.h>
#include <math.h>

// Sizes
// U=128, D=256, B=1024, E=64, H=8
// kernel1: per (u, 32-row batch tile) fused universe chain -> enc[B][U][64], scores[B][U]
// kernel2: per (b, head-half): Q/K + softmax column means -> smean[2][B][U] (partial over heads)
// kernel3: per b: consensus MLP + stats -> outputs
// kernel4: global mean of smean -> out[4096]

__global__ __launch_bounds__(256, 2)
void fused_universe(const float* __restrict__ x, const float* __restrict__ fs, const float* __restrict__ dm,
                    const float* __restrict__ W1, const float* __restrict__ b1, const float* __restrict__ g1, const float* __restrict__ be1,
                    const float* __restrict__ W2, const float* __restrict__ b2, const float* __restrict__ g2, const float* __restrict__ be2,
                    const float* __restrict__ W3, const float* __restrict__ b3,
                    const float* __restrict__ Wr, const float* __restrict__ br,
                    const float* __restrict__ Wa1, const float* __restrict__ ba1,
                    const float* __restrict__ Wa2, const float* __restrict__ ba2,
                    const float* __restrict__ Wa3, const float* __restrict__ ba3,
                    float* __restrict__ enc_g, float* __restrict__ scores_g)
{
    __shared__ __align__(16) float sm[14592];
    float* H1s = sm;            // 8192 floats [32][256]
    float* H2s = sm + 8192;     // 4096 floats [32][128]
    float* Ws  = sm + 12288;    // 2048 floats (weight panel)
    float* Xsp = sm + 14336;    // 256 floats  [32][8]
    // aliases after GEMM2 (H1s dead):
    float* ENCs = sm;           // 2048 floats [32][64]
    float* Zs   = sm + 2048;    // 2048 floats [32][64]
    float* A1s  = sm + 4096;    // 1024 floats [32][32]
    float* A2s  = sm + 5120;    // 512  floats [32][16]

    const int bx  = blockIdx.x;
    const int xcd = bx & 7;
    const int idx = bx >> 3;
    const int u   = ((idx >> 5) << 3) + xcd;    // 16 u-groups * 8 xcd = 128
    const int b0  = (idx & 31) * 32;            // 32 batch tiles
    const int t   = threadIdx.x;
    const int r   = t >> 5;       // 0..7
    const int c   = t & 31;       // 0..31
    const int rowbase = r * 4;

    const float corru = fs[u] * 137.036f;

    // ================= GEMM1: h1[32][256] = x_tile @ W1[u] =================
    float acc[4][8] = {};
    {
        const float* W1u = W1 + (size_t)u * 65536;
        for (int kp = 0; kp < 32; ++kp) {
            {
                const float4* src = (const float4*)(W1u + kp * 2048);
                float4* dst = (float4*)Ws;
                dst[t] = src[t];
                dst[t + 256] = src[t + 256];
                if (t < 64) {
                    const int row = t >> 1, q = t & 1;
                    ((float4*)Xsp)[row * 2 + q] =
                        *(const float4*)(x + (size_t)(b0 + row) * 256 + kp * 8 + 4 * q);
                }
            }
            __syncthreads();
            #pragma unroll
            for (int k = 0; k < 8; ++k) {
                const float a0 = Xsp[(rowbase + 0) * 8 + k];
                const float a1 = Xsp[(rowbase + 1) * 8 + k];
                const float a2 = Xsp[(rowbase + 2) * 8 + k];
                const float a3 = Xsp[(rowbase + 3) * 8 + k];
                const float* wrow = &Ws[k * 256 + 2 * c];
                #pragma unroll
                for (int j = 0; j < 4; ++j) {
                    const float2 w = *(const float2*)(wrow + j * 64);
                    acc[0][2*j] += a0 * w.x; acc[0][2*j+1] += a0 * w.y;
                    acc[1][2*j] += a1 * w.x; acc[1][2*j+1] += a1 * w.y;
                    acc[2][2*j] += a2 * w.x; acc[2][2*j+1] += a2 * w.y;
                    acc[3][2*j] += a3 * w.x; acc[3][2*j+1] += a3 * w.y;
                }
            }
            __syncthreads();
        }
    }
    // LN1 + relu -> H1s   (h = x@W1*corr + b1; LN over 256)
    {
        #pragma unroll
        for (int i = 0; i < 4; ++i) {
            float v[8];
            float s = 0.f, sq = 0.f;
            #pragma unroll
            for (int j = 0; j < 4; ++j) {
                const float2 bb = *(const float2*)&b1[(size_t)u * 256 + j * 64 + 2 * c];
                const float v0 = acc[i][2*j]   * corru + bb.x;
                const float v1 = acc[i][2*j+1] * corru + bb.y;
                v[2*j] = v0; v[2*j+1] = v1;
                s += v0 + v1; sq += v0 * v0 + v1 * v1;
            }
            #pragma unroll
            for (int m = 1; m < 32; m <<= 1) { s += __shfl_xor(s, m); sq += __shfl_xor(sq, m); }
            const float mean = s * (1.f / 256.f);
            float var = sq * (1.f / 256.f) - mean * mean; var = fmaxf(var, 0.f);
            const float rstd = rsqrtf(var + 1e-5f);
            #pragma unroll
            for (int j = 0; j < 4; ++j) {
                const float2 gg = *(const float2*)&g1[(size_t)u * 256 + j * 64 + 2 * c];
                const float2 ee = *(const float2*)&be1[(size_t)u * 256 + j * 64 + 2 * c];
                const float h0 = fmaxf((v[2*j]   - mean) * rstd * gg.x + ee.x, 0.f);
                const float h1 = fmaxf((v[2*j+1] - mean) * rstd * gg.y + ee.y, 0.f);
                *(float2*)&H1s[(rowbase + i) * 256 + j * 64 + 2 * c] = make_float2(h0, h1);
            }
        }
    }
    __syncthreads();

    // ================= GEMM2: h2[32][128] = H1s @ W2[u] =================
    float acc2[4][4] = {};
    {
        for (int kp = 0; kp < 16; ++kp) {
            {
                const float4* src = (const float4*)(W2 + (size_t)u * 32768 + kp * 2048);
                float4* dst = (float4*)Ws;
                dst[t] = src[t];
                dst[t + 256] = src[t + 256];
            }
            __syncthreads();
            #pragma unroll
            for (int k = 0; k < 16; ++k) {
                const int kg = kp * 16 + k;
                const float a0 = H1s[(rowbase + 0) * 256 + kg];
                const float a1 = H1s[(rowbase + 1) * 256 + kg];
                const float a2 = H1s[(rowbase + 2) * 256 + kg];
                const float a3 = H1s[(rowbase + 3) * 256 + kg];
                const float* wrow = &Ws[k * 128 + 2 * c];
                #pragma unroll
                for (int j = 0; j < 2; ++j) {
                    const float2 w = *(const float2*)(wrow + j * 64);
                    acc2[0][2*j] += a0 * w.x; acc2[0][2*j+1] += a0 * w.y;
                    acc2[1][2*j] += a1 * w.x; acc2[1][2*j+1] += a1 * w.y;
                    acc2[2][2*j] += a2 * w.x; acc2[2][2*j+1] += a2 * w.y;
                    acc2[3][2*j] += a3 * w.x; acc2[3][2*j+1] += a3 * w.y;
                }
            }
            __syncthreads();
        }
    }
    // LN2 + relu -> H2s (LN over 128)
    {
        #pragma unroll
        for (int i = 0; i < 4; ++i) {
            float v[4];
            float s = 0.f, sq = 0.f;
            #pragma unroll
            for (int j = 0; j < 2; ++j) {
                const float2 bb = *(const float2*)&b2[(size_t)u * 128 + j * 64 + 2 * c];
                const float v0 = acc2[i][2*j]   + bb.x;
                const float v1 = acc2[i][2*j+1] + bb.y;
                v[2*j] = v0; v[2*j+1] = v1;
                s += v0 + v1; sq += v0 * v0 + v1 * v1;
            }
            #pragma unroll
            for (int m = 1; m < 32; m <<= 1) { s += __shfl_xor(s, m); sq += __shfl_xor(sq, m); }
            const float mean = s * (1.f / 128.f);
            float var = sq * (1.f / 128.f) - mean * mean; var = fmaxf(var, 0.f);
            const float rstd = rsqrtf(var + 1e-5f);
            #pragma unroll
            for (int j = 0; j < 2; ++j) {
                const float2 gg = *(const float2*)&g2[(size_t)u * 128 + j * 64 + 2 * c];
                const float2 ee = *(const float2*)&be2[(size_t)u * 128 + j * 64 + 2 * c];
                const float h0 = fmaxf((v[2*j]   - mean) * rstd * gg.x + ee.x, 0.f);
                const float h1 = fmaxf((v[2*j+1] - mean) * rstd * gg.y + ee.y, 0.f);
                *(float2*)&H2s[(rowbase + i) * 128 + j * 64 + 2 * c] = make_float2(h0, h1);
            }
        }
    }
    __syncthreads();

    // ================= GEMM3: enc[32][64] = H2s @ W3[u] + b3 =================
    float acc3[4][2] = {};
    {
        for (int kp = 0; kp < 4; ++kp) {
            {
                const float4* src = (const float4*)(W3 + (size_t)u * 8192 + kp * 2048);
                float4* dst = (float4*)Ws;
                dst[t] = src[t];
                dst[t + 256] = src[t + 256];
            }
            __syncthreads();
            #pragma unroll
            for (int k = 0; k < 32; ++k) {
                const int kg = kp * 32 + k;
                const float a0 = H2s[(rowbase + 0) * 128 + kg];
                const float a1 = H2s[(rowbase + 1) * 128 + kg];
                const float a2 = H2s[(rowbase + 2) * 128 + kg];
                const float a3 = H2s[(rowbase + 3) * 128 + kg];
                const float2 w = *(const float2*)&Ws[k * 64 + 2 * c];
                acc3[0][0] += a0 * w.x; acc3[0][1] += a0 * w.y;
                acc3[1][0] += a1 * w.x; acc3[1][1] += a1 * w.y;
                acc3[2][0] += a2 * w.x; acc3[2][1] += a2 * w.y;
                acc3[3][0] += a3 * w.x; acc3[3][1] += a3 * w.y;
            }
            __syncthreads();
        }
    }
    // enc epilogue: +b3, sumsq -> dmi, stage ENCs (aliases H1s; safe: H1s dead)
    float dmiv[4];
    {
        const float dmu = dm[u];
        const float2 b3v = *(const float2*)&b3[(size_t)u * 64 + 2 * c];
        #pragma unroll
        for (int i = 0; i < 4; ++i) {
            const float e0 = acc3[i][0] + b3v.x;
            const float e1 = acc3[i][1] + b3v.y;
            float ssq = e0 * e0 + e1 * e1;
            #pragma unroll
            for (int m = 1; m < 32; m <<= 1) ssq += __shfl_xor(ssq, m);
            dmiv[i] = tanhf(dmu * ssq);
            *(float2*)&ENCs[(rowbase + i) * 64 + 2 * c] = make_float2(e0, e1);
        }
    }
    __syncthreads();
    // write enc to global: enc_g[(b*128+u)*64 + e]
    {
        const float4* es = (const float4*)ENCs;
        #pragma unroll
        for (int q2 = 0; q2 < 2; ++q2) {
            const int f = t + q2 * 256;
            const int row = f >> 4, e4 = f & 15;
            ((float4*)(enc_g + ((size_t)(b0 + row) * 128 + u) * 64))[e4] = es[f];
        }
    }

    // ================= re = ENCs @ Wr[u] + br; z = re + dmi*enc =================
    float accR[4][2] = {};
    {
        for (int kp = 0; kp < 2; ++kp) {
            {
                const float4* src = (const float4*)(Wr + (size_t)u * 4096 + kp * 2048);
                float4* dst = (float4*)Ws;
                dst[t] = src[t];
                dst[t + 256] = src[t + 256];
            }
            __syncthreads();
            #pragma unroll
            for (int k = 0; k < 32; ++k) {
                const int kg = kp * 32 + k;
                const float a0 = ENCs[(rowbase + 0) * 64 + kg];
                const float a1 = ENCs[(rowbase + 1) * 64 + kg];
                const float a2 = ENCs[(rowbase + 2) * 64 + kg];
                const float a3 = ENCs[(rowbase + 3) * 64 + kg];
                const float2 w = *(const float2*)&Ws[k * 64 + 2 * c];
                accR[0][0] += a0 * w.x; accR[0][1] += a0 * w.y;
                accR[1][0] += a1 * w.x; accR[1][1] += a1 * w.y;
                accR[2][0] += a2 * w.x; accR[2][1] += a2 * w.y;
                accR[3][0] += a3 * w.x; accR[3][1] += a3 * w.y;
            }
            __syncthreads();
        }
    }
    {
        const float2 brv = *(const float2*)&br[(size_t)u * 64 + 2 * c];
        #pragma unroll
        for (int i = 0; i < 4; ++i) {
            const float2 ev = *(const float2*)&ENCs[(rowbase + i) * 64 + 2 * c];
            const float z0 = accR[i][0] + brv.x + dmiv[i] * ev.x;
            const float z1 = accR[i][1] + brv.y + dmiv[i] * ev.y;
            *(float2*)&Zs[(rowbase + i) * 64 + 2 * c] = make_float2(z0, z1);
        }
        // stage Wa1 (2048 floats) into Ws (safe: Ws reads done via last barrier)
        const float4* src = (const float4*)(Wa1 + (size_t)u * 2048);
        float4* dst = (float4*)Ws;
        dst[t] = src[t];
        dst[t + 256] = src[t + 256];
    }
    __syncthreads();

    // ================= a1[32][32] = relu(Zs @ Wa1 + ba1) =================
    {
        float accA[4] = {};
        #pragma unroll
        for (int k = 0; k < 64; ++k) {
            const float a0 = Zs[(rowbase + 0) * 64 + k];
            const float a1 = Zs[(rowbase + 1) * 64 + k];
            const float a2 = Zs[(rowbase + 2) * 64 + k];
            const float a3 = Zs[(rowbase + 3) * 64 + k];
            const float w = Ws[k * 32 + c];
            accA[0] += a0 * w; accA[1] += a1 * w; accA[2] += a2 * w; accA[3] += a3 * w;
        }
        const float bv = ba1[(size_t)u * 32 + c];
        #pragma unroll
        for (int i = 0; i < 4; ++i)
            A1s[(rowbase + i) * 32 + c] = fmaxf(accA[i] + bv, 0.f);
    }
    __syncthreads();
    // stage Wa2 (512 floats)
    if (t < 128) ((float4*)Ws)[t] = ((const float4*)(Wa2 + (size_t)u * 512))[t];
    __syncthreads();

    // ================= a2[32][16] = relu(A1s @ Wa2 + ba2) =================
    {
        const int r2 = t >> 4, c2 = t & 15;
        float accB[2] = {};
        #pragma unroll
        for (int k = 0; k < 32; ++k) {
            const float a0 = A1s[(r2 * 2 + 0) * 32 + k];
            const float a1 = A1s[(r2 * 2 + 1) * 32 + k];
            const float w = Ws[k * 16 + c2];
            accB[0] += a0 * w; accB[1] += a1 * w;
        }
        const float bv = ba2[(size_t)u * 16 + c2];
        A2s[(r2 * 2 + 0) * 16 + c2] = fmaxf(accB[0] + bv, 0.f);
        A2s[(r2 * 2 + 1) * 16 + c2] = fmaxf(accB[1] + bv, 0.f);
    }
    __syncthreads();

    // ================= scores = sigmoid(A2s @ Wa3 + ba3) =================
    if (t < 32) {
        float a = ba3[u];
        #pragma unroll
        for (int k = 0; k < 16; ++k) a += A2s[t * 16 + k] * Wa3[(size_t)u * 16 + k];
        scores_g[(size_t)(b0 + t) * 128 + u] = 1.f / (1.f + __expf(-a));
    }
}

// kernel2: per (b, part): 4 heads. Computes Q,K (scaled), then per-head row softmax
// stats (pass1, row-parallel) + column-sum accumulation (pass2, column-parallel).
__global__ __launch_bounds__(256, 2)
void attn_kernel(const float* __restrict__ enc_g, const float* __restrict__ Wqkv,
                 const float* __restrict__ bqkv, float* __restrict__ smean)
{
    __shared__ __align__(16) float Qs[128 * 34];
    __shared__ __align__(16) float Ks[128 * 34];
    __shared__ __align__(16) float WqS[512];
    __shared__ float mrow[128];
    __shared__ float zrow[128];

    const int bx = blockIdx.x;
    const int b = bx >> 1, part = bx & 1;
    const int hb8 = part * 32;     // f-offset of this block's 4 heads
    const int t = threadIdx.x;
    const int role = t >> 7;       // 0 = Q, 1 = K
    const int uu = t & 127;

    float er[64];
    {
        const float4* ep = (const float4*)(enc_g + ((size_t)b * 128 + uu) * 64);
        #pragma unroll
        for (int i = 0; i < 16; ++i) {
            const float4 v4 = ep[i];
            er[4*i] = v4.x; er[4*i+1] = v4.y; er[4*i+2] = v4.z; er[4*i+3] = v4.w;
        }
    }
    const float invsq = 0.35355339059327373f;  // 1/sqrt(8)

    for (int ch = 0; ch < 8; ++ch) {
        if (t < 128) {  // stage 4 Q rows + 4 K rows
            const int p2 = t >> 6;          // 0: Q rows, 1: K rows
            const int fr = (t >> 4) & 3;
            const int fe = t & 15;
            ((float4*)WqS)[t] =
                ((const float4*)(Wqkv + ((size_t)(p2 * 64 + hb8 + ch * 4 + fr)) * 64))[fe];
        }
        __syncthreads();
        #pragma unroll
        for (int fi = 0; fi < 4; ++fi) {
            const int fl = ch * 4 + fi;
            float a = bqkv[role * 64 + hb8 + fl];
            const float* wr = &WqS[(role * 4 + fi) * 64];
            #pragma unroll
            for (int e = 0; e < 64; e += 4) {
                const float4 w = *(const float4*)(wr + e);
                a += er[e] * w.x + er[e+1] * w.y + er[e+2] * w.z + er[e+3] * w.w;
            }
            if (role == 0) Qs[uu * 34 + fl] = a * invsq;
            else           Ks[uu * 34 + fl] = a;
        }
        __syncthreads();
    }

    const int q = t >> 1, half = t & 1;   // pass1 row id / pass2 column id
    float creg = 0.f;
    for (int h = 0; h < 4; ++h) {
        const int hf = h * 8;
        // ---- pass1: row (q over all 128 k's split by half) ----
        float qv[8];
        #pragma unroll
        for (int d = 0; d < 8; d += 2) {
            const float2 v2 = *(const float2*)&Qs[q * 34 + hf + d];
            qv[d] = v2.x; qv[d+1] = v2.y;
        }
        float S[64];
        float mx = -3.0e38f;
        #pragma unroll
        for (int kk = 0; kk < 64; ++kk) {
            const float* kr = &Ks[(half * 64 + kk) * 34 + hf];
            float s = 0.f;
            #pragma unroll
            for (int d = 0; d < 8; d += 2) {
                const float2 v2 = *(const float2*)(kr + d);
                s += qv[d] * v2.x + qv[d+1] * v2.y;
            }
            S[kk] = s;
            mx = fmaxf(mx, s);
        }
        mx = fmaxf(mx, __shfl_xor(mx, 1));
        float Z = 0.f;
        #pragma unroll
        for (int kk = 0; kk < 64; ++kk) Z += __expf(S[kk] - mx);
        Z += __shfl_xor(Z, 1);
        if (half == 0) { mrow[q] = mx; zrow[q] = 1.f / Z; }
        __syncthreads();
        // ---- pass2: column kcol=q, rows qhalf*64..+64 ----
        float kv[8];
        #pragma unroll
        for (int d = 0; d < 8; d += 2) {
            const float2 v2 = *(const float2*)&Ks[q * 34 + hf + d];
            kv[d] = v2.x; kv[d+1] = v2.y;
        }
        float cs = 0.f;
        for (int qq = 0; qq < 64; ++qq) {
            const int qr = half * 64 + qq;
            const float* qrp = &Qs[qr * 34 + hf];
            float s = 0.f;
            #pragma unroll
            for (int d = 0; d < 8; d += 2) {
                const float2 v2 = *(const float2*)(qrp + d);
                s += kv[d] * v2.x + kv[d+1] * v2.y;
            }
            cs += __expf(s - mrow[qr]) * zrow[qr];
        }
        creg += cs;
        __syncthreads();
    }
    creg += __shfl_xor(creg, 1);
    if (half == 0)
        smean[(size_t)part * 131072 + (size_t)b * 128 + q] = creg * (1.f / 1024.f);
}

__global__ __launch_bounds__(64)
void final_kernel(const float* __restrict__ scores_g, const float* __restrict__ smean,
                  const float* __restrict__ Wc1, const float* __restrict__ bc1,
                  const float* __restrict__ Wc2, const float* __restrict__ bc2,
                  const float* __restrict__ Wc3, const float* __restrict__ bc3,
                  float* __restrict__ out)
{
    __shared__ float sc[128];
    __shared__ float c1[64];
    __shared__ float c2[32];
    const int b = blockIdx.x, t = threadIdx.x;
    const float s0 = scores_g[(size_t)b * 128 + t];
    const float s1 = scores_g[(size_t)b * 128 + 64 + t];
    sc[t] = s0; sc[64 + t] = s1;
    const float v0 = smean[(size_t)b * 128 + t]      + smean[131072 + (size_t)b * 128 + t];
    const float v1 = smean[(size_t)b * 128 + 64 + t] + smean[131072 + (size_t)b * 128 + 64 + t];
    __syncthreads();
    float a = bc1[t];
    #pragma unroll 8
    for (int i = 0; i < 128; ++i) a += sc[i] * Wc1[i * 64 + t];
    c1[t] = fmaxf(a, 0.f);
    __syncthreads();
    if (t < 32) {
        float a2 = bc2[t];
        #pragma unroll 8
        for (int i = 0; i < 64; ++i) a2 += c1[i] * Wc2[i * 32 + t];
        c2[t] = fmaxf(a2, 0.f);
    }
    __syncthreads();
    float p = (t < 32) ? c2[t] * Wc3[t] : 0.f;
    #pragma unroll
    for (int m = 1; m < 64; m <<= 1) p += __shfl_xor(p, m);
    const float cons = 1.f / (1.f + __expf(-(p + bc3[0])));

    float sum = s0 + s1;
    float sq  = s0 * s0 + s1 * s1;
    float wsm = s0 * v0 + s1 * v1;
    float na  = (s0 > 0.1f ? 1.f : 0.f) + (s1 > 0.1f ? 1.f : 0.f);
    #pragma unroll
    for (int m = 1; m < 64; m <<= 1) {
        sum += __shfl_xor(sum, m); sq += __shfl_xor(sq, m);
        wsm += __shfl_xor(wsm, m); na += __shfl_xor(na, m);
    }
    if (t == 0) {
        const float mean = sum * (1.f / 128.f);
        float var = (sq - 128.f * mean * mean) * (1.f / 127.f);
        var = fmaxf(var, 0.f);
        const float agree = 1.f - sqrtf(var) / (mean + 1e-8f);
        out[b]        = cons * wsm;
        out[1024 + b] = (cons > 0.95f) ? 1.f : 0.f;
        out[2048 + b] = agree;
        out[3072 + b] = cons;
        out[4097 + b] = na;
    }
}

__global__ void attnmean_kernel(const float* __restrict__ smean, float* __restrict__ out)
{
    __shared__ float red[256];
    const int t = threadIdx.x;
    float s = 0.f;
    for (int i = t; i < 262144; i += 256) s += smean[i];
    red[t] = s;
    __syncthreads();
    for (int w = 128; w > 0; w >>= 1) {
        if (t < w) red[t] += red[t + w];
        __syncthreads();
    }
    if (t == 0) out[4096] = red[0] * (1.f / 131072.f);
}

extern "C" void kernel_launch(void* const* d_in, const int* in_sizes, int n_in,
                              void* d_out, int out_size, void* d_ws, size_t ws_size,
                              hipStream_t stream)
{
    const float* x    = (const float*)d_in[0];
    const float* fs   = (const float*)d_in[1];
    const float* dm   = (const float*)d_in[2];
    const float* W1   = (const float*)d_in[3];
    const float* b1   = (const float*)d_in[4];
    const float* g1   = (const float*)d_in[5];
    const float* be1  = (const float*)d_in[6];
    const float* W2   = (const float*)d_in[7];
    const float* b2   = (const float*)d_in[8];
    const float* g2   = (const float*)d_in[9];
    const float* be2  = (const float*)d_in[10];
    const float* W3   = (const float*)d_in[11];
    const float* b3   = (const float*)d_in[12];
    const float* Wr   = (const float*)d_in[13];
    const float* br   = (const float*)d_in[14];
    const float* Wa1  = (const float*)d_in[15];
    const float* ba1  = (const float*)d_in[16];
    const float* Wa2  = (const float*)d_in[17];
    const float* ba2  = (const float*)d_in[18];
    const float* Wa3  = (const float*)d_in[19];
    const float* ba3  = (const float*)d_in[20];
    const float* Wqkv = (const float*)d_in[21];
    const float* bqkv = (const float*)d_in[22];
    // d_in[23]=Wo, d_in[24]=bo : unused downstream in the reference
    const float* Wc1  = (const float*)d_in[25];
    const float* bc1  = (const float*)d_in[26];
    const float* Wc2  = (const float*)d_in[27];
    const float* bc2  = (const float*)d_in[28];
    const float* Wc3  = (const float*)d_in[29];
    const float* bc3  = (const float*)d_in[30];

    float* out = (float*)d_out;
    float* ws  = (float*)d_ws;
    float* enc    = ws;                       // 1024*128*64 = 8388608 floats
    float* scores = ws + 8388608;             // 131072 floats
    float* smean  = ws + 8388608 + 131072;    // 2*131072 floats

    fused_universe<<<4096, 256, 0, stream>>>(x, fs, dm, W1, b1, g1, be1,
                                             W2, b2, g2, be2, W3, b3, Wr, br,
                                             Wa1, ba1, Wa2, ba2, Wa3, ba3,
                                             enc, scores);
    attn_kernel<<<2048, 256, 0, stream>>>(enc, Wqkv, bqkv, smean);
    final_kernel<<<1024, 64, 0, stream>>>(scores, smean, Wc1, bc1, Wc2, bc2, Wc3, bc3, out);
    attnmean_kernel<<<1, 256, 0, stream>>>(smean, out);
}

// Round 2
// 627.260 us; speedup vs baseline: 1.6998x; 1.6998x over previous
//
#include <hip/hip_runtime.h>
#include <math.h>

// U=128, D=256, B=1024, E=64, H=8
// prep_kernel : f32 -> bf16 transposed weights ([n][k]) + x -> bf16
// fused_mfma  : per (u, 64-row batch tile): GEMM1(MFMA)+LN -> GEMM2(MFMA)+LN ->
//               GEMM3(MFMA) -> enc, dmi -> Wr(MFMA) -> z -> VALU tail -> scores
// attn_kernel : QK^T row-softmax column means (unchanged)
// final/attnmean: outputs (unchanged)

typedef float f32x4 __attribute__((ext_vector_type(4)));
typedef int   i32x4 __attribute__((ext_vector_type(4)));

__device__ __forceinline__ void mfma_bf16(f32x4& c, i32x4 a, i32x4 b) {
    asm("v_mfma_f32_16x16x32_bf16 %0, %1, %2, %0" : "+v"(c) : "v"(a), "v"(b));
}

__device__ __forceinline__ void gl_lds16(const void* g, void* l) {
    __builtin_amdgcn_global_load_lds(
        (const __attribute__((address_space(1))) unsigned int*)g,
        (__attribute__((address_space(3))) unsigned int*)l, 16, 0, 0);
}

__device__ __forceinline__ unsigned short f2bf(float v) {
    union { __bf16 b; unsigned short u; } cv;
    cv.b = (__bf16)v;
    return cv.u;
}

// ---------------- prep: convert + transpose weights to bf16 ----------------
__global__ __launch_bounds__(256)
void prep_kernel(const float* __restrict__ W1, const float* __restrict__ W2,
                 const float* __restrict__ W3, const float* __restrict__ Wr,
                 const float* __restrict__ x,
                 unsigned short* __restrict__ W1t, unsigned short* __restrict__ W2t,
                 unsigned short* __restrict__ W3t, unsigned short* __restrict__ Wrt,
                 unsigned short* __restrict__ xb)
{
    const int bid = blockIdx.x, t = threadIdx.x;
    if (bid >= 3456) {  // x convert, no transpose
        const int base = (bid - 3456) * 2048 + t * 8;
        const float4 v0 = *(const float4*)(x + base);
        const float4 v1 = *(const float4*)(x + base + 4);
        __align__(16) unsigned short o[8];
        o[0]=f2bf(v0.x); o[1]=f2bf(v0.y); o[2]=f2bf(v0.z); o[3]=f2bf(v0.w);
        o[4]=f2bf(v1.x); o[5]=f2bf(v1.y); o[6]=f2bf(v1.z); o[7]=f2bf(v1.w);
        *(uint4*)(xb + base) = *(const uint4*)o;
        return;
    }
    const float* src; unsigned short* dst; int u, k0, n0, K, N;
    if (bid < 2048)      { u = bid >> 4;        int tl = bid & 15;       k0 = (tl>>2)*64; n0 = (tl&3)*64; K=256; N=256; src = W1 + (size_t)u*65536; dst = W1t + (size_t)u*65536; }
    else if (bid < 3072) { int b2 = bid - 2048; u = b2 >> 3; int tl = b2 & 7; k0 = (tl>>1)*64; n0 = (tl&1)*64; K=256; N=128; src = W2 + (size_t)u*32768; dst = W2t + (size_t)u*32768; }
    else if (bid < 3328) { int b3 = bid - 3072; u = b3 >> 1; int tl = b3 & 1; k0 = tl*64;      n0 = 0;         K=128; N=64;  src = W3 + (size_t)u*8192;  dst = W3t + (size_t)u*8192;  }
    else                 { u = bid - 3328;      k0 = 0; n0 = 0;                                 K=64;  N=64;  src = Wr + (size_t)u*4096;  dst = Wrt + (size_t)u*4096;  }

    __shared__ unsigned short tile[64 * 65];
    #pragma unroll
    for (int i = 0; i < 16; ++i) {
        const int e = i * 256 + t;
        const int kk = e >> 6, nn = e & 63;
        tile[kk * 65 + nn] = f2bf(src[(size_t)(k0 + kk) * N + n0 + nn]);
    }
    __syncthreads();
    #pragma unroll
    for (int i = 0; i < 16; ++i) {
        const int e = i * 256 + t;
        const int nn = e >> 6, kk = e & 63;
        dst[(size_t)(n0 + nn) * K + k0 + kk] = tile[kk * 65 + nn];
    }
}

// ---------------- fused universe chain (MFMA) ----------------
__global__ __launch_bounds__(256, 2)
void fused_mfma(const unsigned short* __restrict__ xb,
                const unsigned short* __restrict__ W1t, const unsigned short* __restrict__ W2t,
                const unsigned short* __restrict__ W3t, const unsigned short* __restrict__ Wrt,
                const float* __restrict__ fs, const float* __restrict__ dm,
                const float* __restrict__ b1, const float* __restrict__ g1, const float* __restrict__ be1,
                const float* __restrict__ b2, const float* __restrict__ g2, const float* __restrict__ be2,
                const float* __restrict__ b3, const float* __restrict__ br,
                const float* __restrict__ Wa1, const float* __restrict__ ba1,
                const float* __restrict__ Wa2, const float* __restrict__ ba2,
                const float* __restrict__ Wa3, const float* __restrict__ ba3,
                float* __restrict__ enc_g, float* __restrict__ scores_g)
{
    __shared__ __align__(128) char sm[69632];
    char* R0 = sm;             // 32 KB: A_x -> H1 -> H2/enc_bf/z
    char* R1 = sm + 32768;     // 32 KB: B panels -> Wa1/a1/Wa2/a2/Wa3
    char* R2 = sm + 65536;     // 4 KB : pS, pQ(+1024), rstats(+2048), dmi(+2560)
    float* pS = (float*)R2;
    float* pQ = (float*)(R2 + 1024);
    float2* rst = (float2*)(R2 + 2048);
    float* dmis = (float*)(R2 + 2560);

    const int t = threadIdx.x;
    const int wid = t >> 6, lane = t & 63, l15 = lane & 15, lk = lane >> 4;
    const int swz = (l15 & 7) << 4;
    const int bx = blockIdx.x;
    const int xcd = bx & 7, idx = bx >> 3;
    const int u = ((idx >> 4) << 3) + xcd;
    const int b0 = (idx & 15) * 64;

    const float corru = fs[u] * 137.036f;
    const float dmu = dm[u];

    const char* xbase = (const char*)xb + (size_t)b0 * 512;
    const char* w1u = (const char*)W1t + (size_t)u * 131072;
    const char* w2u = (const char*)W2t + (size_t)u * 65536;
    const char* w3u = (const char*)W3t + (size_t)u * 16384;
    const char* wru = (const char*)Wrt + (size_t)u * 8192;

    // stage A_x [64][256]bf16 (swz, S=512) + GEMM1 B panel0 [256][64]bf16 (swz, S=128)
    #pragma unroll
    for (int it = 0; it < 8; ++it) {
        const int d = it * 4096 + t * 16;
        const int s = d ^ (((d >> 9) & 7) << 4);
        gl_lds16(xbase + s, R0 + it * 4096 + wid * 1024);
    }
    #pragma unroll
    for (int it = 0; it < 8; ++it) {
        const int d = it * 4096 + t * 16;
        const int s = d ^ (((d >> 7) & 7) << 4);
        gl_lds16(w1u + (s >> 7) * 512 + (s & 127), R1 + it * 4096 + wid * 1024);
    }
    __syncthreads();

    // ===== GEMM1: [64][256] = A_x @ W1t, K=256, panels of K=64 =====
    const f32x4 z4 = {0.f, 0.f, 0.f, 0.f};
    f32x4 acc[4][4];
    #pragma unroll
    for (int mi = 0; mi < 4; ++mi)
        #pragma unroll
        for (int ni = 0; ni < 4; ++ni) acc[mi][ni] = z4;

    for (int p = 0; p < 4; ++p) {
        #pragma unroll
        for (int ks = 0; ks < 2; ++ks) {
            i32x4 af[4], bf[4];
            #pragma unroll
            for (int mi = 0; mi < 4; ++mi) {
                const int off = ((mi * 16 + l15) << 9) + p * 128 + ks * 64 + lk * 16;
                af[mi] = *(const i32x4*)(R0 + (off ^ swz));
            }
            #pragma unroll
            for (int ni = 0; ni < 4; ++ni) {
                const int off = ((wid * 64 + ni * 16 + l15) << 7) + ks * 64 + lk * 16;
                bf[ni] = *(const i32x4*)(R1 + (off ^ swz));
            }
            #pragma unroll
            for (int mi = 0; mi < 4; ++mi)
                #pragma unroll
                for (int ni = 0; ni < 4; ++ni) mfma_bf16(acc[mi][ni], af[mi], bf[ni]);
        }
        if (p < 3) {
            __syncthreads();
            #pragma unroll
            for (int it = 0; it < 8; ++it) {
                const int d = it * 4096 + t * 16;
                const int s = d ^ (((d >> 7) & 7) << 4);
                gl_lds16(w1u + (s >> 7) * 512 + (p + 1) * 128 + (s & 127), R1 + it * 4096 + wid * 1024);
            }
            __syncthreads();
        }
    }

    // ===== LN1 (over 256) + relu -> H1 bf16 [64][256] swz at R0 =====
    float bb[4], gg[4], ee[4];
    #pragma unroll
    for (int ni = 0; ni < 4; ++ni) {
        const int c = wid * 64 + ni * 16 + l15;
        bb[ni] = b1[u * 256 + c]; gg[ni] = g1[u * 256 + c]; ee[ni] = be1[u * 256 + c];
    }
    #pragma unroll
    for (int mi = 0; mi < 4; ++mi) {
        #pragma unroll
        for (int j = 0; j < 4; ++j) {
            float s = 0.f, q = 0.f;
            #pragma unroll
            for (int ni = 0; ni < 4; ++ni) {
                const float h = acc[mi][ni][j] * corru + bb[ni];
                acc[mi][ni][j] = h;
                s += h; q += h * h;
            }
            #pragma unroll
            for (int m = 1; m < 16; m <<= 1) { s += __shfl_xor(s, m); q += __shfl_xor(q, m); }
            if (l15 == 0) {
                const int r = mi * 16 + lk * 4 + j;
                pS[wid * 64 + r] = s; pQ[wid * 64 + r] = q;
            }
        }
    }
    __syncthreads();  // A: GEMM1 reads done, partials ready
    if (t < 64) {
        const float s = pS[t] + pS[64 + t] + pS[128 + t] + pS[192 + t];
        const float q = pQ[t] + pQ[64 + t] + pQ[128 + t] + pQ[192 + t];
        const float mean = s * (1.f / 256.f);
        const float var = fmaxf(q * (1.f / 256.f) - mean * mean, 0.f);
        rst[t] = make_float2(mean, rsqrtf(var + 1e-5f));
    }
    // stage GEMM2 B panel0 [128][64] into R1 half0
    #pragma unroll
    for (int it = 0; it < 4; ++it) {
        const int d = it * 4096 + t * 16;
        const int s = d ^ (((d >> 7) & 7) << 4);
        gl_lds16(w2u + (s >> 7) * 512 + (s & 127), R1 + it * 4096 + wid * 1024);
    }
    __syncthreads();  // B: stats ready, staging drained
    #pragma unroll
    for (int mi = 0; mi < 4; ++mi) {
        #pragma unroll
        for (int j = 0; j < 4; ++j) {
            const int r = mi * 16 + lk * 4 + j;
            const float2 st = rst[r];
            #pragma unroll
            for (int ni = 0; ni < 4; ++ni) {
                const float h = fmaxf((acc[mi][ni][j] - st.x) * st.y * gg[ni] + ee[ni], 0.f);
                const int c = wid * 64 + ni * 16 + l15;
                const int off = (r << 9) + c * 2;
                *(__bf16*)(R0 + (off ^ ((r & 7) << 4))) = (__bf16)h;
            }
        }
    }
    __syncthreads();  // C: H1 ready

    // ===== GEMM2: [64][128] = H1 @ W2t, K=256, dbuf panels of K=64 =====
    f32x4 acc2[4][2];
    #pragma unroll
    for (int mi = 0; mi < 4; ++mi) { acc2[mi][0] = z4; acc2[mi][1] = z4; }
    for (int p = 0; p < 4; ++p) {
        if (p < 3) {
            #pragma unroll
            for (int it = 0; it < 4; ++it) {
                const int d = it * 4096 + t * 16;
                const int s = d ^ (((d >> 7) & 7) << 4);
                gl_lds16(w2u + (s >> 7) * 512 + (p + 1) * 128 + (s & 127),
                         R1 + ((p + 1) & 1) * 16384 + it * 4096 + wid * 1024);
            }
        }
        #pragma unroll
        for (int ks = 0; ks < 2; ++ks) {
            i32x4 af[4], bf2[2];
            #pragma unroll
            for (int mi = 0; mi < 4; ++mi) {
                const int off = ((mi * 16 + l15) << 9) + p * 128 + ks * 64 + lk * 16;
                af[mi] = *(const i32x4*)(R0 + (off ^ swz));
            }
            #pragma unroll
            for (int ni = 0; ni < 2; ++ni) {
                const int off = ((wid * 32 + ni * 16 + l15) << 7) + ks * 64 + lk * 16;
                bf2[ni] = *(const i32x4*)(R1 + (p & 1) * 16384 + (off ^ swz));
            }
            #pragma unroll
            for (int mi = 0; mi < 4; ++mi)
                #pragma unroll
                for (int ni = 0; ni < 2; ++ni) mfma_bf16(acc2[mi][ni], af[mi], bf2[ni]);
        }
        __syncthreads();
    }

    // ===== LN2 (over 128) + relu -> H2 bf16 [64][128] swz at R0 =====
    float bb2[2], gg2[2], ee2[2];
    #pragma unroll
    for (int ni = 0; ni < 2; ++ni) {
        const int c = wid * 32 + ni * 16 + l15;
        bb2[ni] = b2[u * 128 + c]; gg2[ni] = g2[u * 128 + c]; ee2[ni] = be2[u * 128 + c];
    }
    #pragma unroll
    for (int mi = 0; mi < 4; ++mi) {
        #pragma unroll
        for (int j = 0; j < 4; ++j) {
            float s = 0.f, q = 0.f;
            #pragma unroll
            for (int ni = 0; ni < 2; ++ni) {
                const float h = acc2[mi][ni][j] + bb2[ni];
                acc2[mi][ni][j] = h;
                s += h; q += h * h;
            }
            #pragma unroll
            for (int m = 1; m < 16; m <<= 1) { s += __shfl_xor(s, m); q += __shfl_xor(q, m); }
            if (l15 == 0) {
                const int r = mi * 16 + lk * 4 + j;
                pS[wid * 64 + r] = s; pQ[wid * 64 + r] = q;
            }
        }
    }
    __syncthreads();  // D
    if (t < 64) {
        const float s = pS[t] + pS[64 + t] + pS[128 + t] + pS[192 + t];
        const float q = pQ[t] + pQ[64 + t] + pQ[128 + t] + pQ[192 + t];
        const float mean = s * (1.f / 128.f);
        const float var = fmaxf(q * (1.f / 128.f) - mean * mean, 0.f);
        rst[t] = make_float2(mean, rsqrtf(var + 1e-5f));
    }
    // stage W3t full [64][128]bf16 (S=256) into R1
    #pragma unroll
    for (int it = 0; it < 4; ++it) {
        const int d = it * 4096 + t * 16;
        const int s = d ^ (((d >> 8) & 7) << 4);
        gl_lds16(w3u + (s >> 8) * 256 + (s & 255), R1 + it * 4096 + wid * 1024);
    }
    __syncthreads();  // E
    #pragma unroll
    for (int mi = 0; mi < 4; ++mi) {
        #pragma unroll
        for (int j = 0; j < 4; ++j) {
            const int r = mi * 16 + lk * 4 + j;
            const float2 st = rst[r];
            #pragma unroll
            for (int ni = 0; ni < 2; ++ni) {
                const float h = fmaxf((acc2[mi][ni][j] - st.x) * st.y * gg2[ni] + ee2[ni], 0.f);
                const int c = wid * 32 + ni * 16 + l15;
                const int off = (r << 8) + c * 2;
                *(__bf16*)(R0 + (off ^ ((r & 7) << 4))) = (__bf16)h;
            }
        }
    }
    __syncthreads();  // F: H2 ready

    // ===== GEMM3: enc [64][64] = H2 @ W3t, K=128 =====
    f32x4 acc3[4];
    #pragma unroll
    for (int mi = 0; mi < 4; ++mi) acc3[mi] = z4;
    #pragma unroll
    for (int ks = 0; ks < 4; ++ks) {
        i32x4 af[4], bfr;
        #pragma unroll
        for (int mi = 0; mi < 4; ++mi) {
            const int off = ((mi * 16 + l15) << 8) + ks * 64 + lk * 16;
            af[mi] = *(const i32x4*)(R0 + (off ^ swz));
        }
        {
            const int off = ((wid * 16 + l15) << 8) + ks * 64 + lk * 16;
            bfr = *(const i32x4*)(R1 + (off ^ swz));
        }
        #pragma unroll
        for (int mi = 0; mi < 4; ++mi) mfma_bf16(acc3[mi], af[mi], bfr);
    }
    // epilogue: +b3, global enc write, sumsq partials
    const int c16 = wid * 16 + l15;
    const float b3v = b3[u * 64 + c16];
    float encr[4][4];
    #pragma unroll
    for (int mi = 0; mi < 4; ++mi) {
        #pragma unroll
        for (int j = 0; j < 4; ++j) {
            const float e = acc3[mi][j] + b3v;
            encr[mi][j] = e;
            const int r = mi * 16 + lk * 4 + j;
            enc_g[((size_t)(b0 + r) * 128 + u) * 64 + c16] = e;
            float q = e * e;
            #pragma unroll
            for (int m = 1; m < 16; m <<= 1) q += __shfl_xor(q, m);
            if (l15 == 0) pQ[wid * 64 + r] = q;
        }
    }
    __syncthreads();  // G: GEMM3 reads done
    if (t < 64) {
        const float q = pQ[t] + pQ[64 + t] + pQ[128 + t] + pQ[192 + t];
        dmis[t] = tanhf(dmu * q);
    }
    // stage Wrt [64][64]bf16 (S=128) into R1
    #pragma unroll
    for (int it = 0; it < 2; ++it) {
        const int d = it * 4096 + t * 16;
        const int s = d ^ (((d >> 7) & 7) << 4);
        gl_lds16(wru + (s >> 7) * 128 + (s & 127), R1 + it * 4096 + wid * 1024);
    }
    // enc bf16 [64][64] swz at R0 (overwrites H2 low half; safe after G)
    #pragma unroll
    for (int mi = 0; mi < 4; ++mi) {
        #pragma unroll
        for (int j = 0; j < 4; ++j) {
            const int r = mi * 16 + lk * 4 + j;
            const int off = (r << 7) + c16 * 2;
            *(__bf16*)(R0 + (off ^ ((r & 7) << 4))) = (__bf16)encr[mi][j];
        }
    }
    __syncthreads();  // H: enc_bf + Wrt + dmi ready

    // ===== Wr: re [64][64] = enc_bf @ Wrt, K=64 =====
    f32x4 accR[4];
    #pragma unroll
    for (int mi = 0; mi < 4; ++mi) accR[mi] = z4;
    #pragma unroll
    for (int ks = 0; ks < 2; ++ks) {
        i32x4 af[4], bfr;
        #pragma unroll
        for (int mi = 0; mi < 4; ++mi) {
            const int off = ((mi * 16 + l15) << 7) + ks * 64 + lk * 16;
            af[mi] = *(const i32x4*)(R0 + (off ^ swz));
        }
        {
            const int off = ((wid * 16 + l15) << 7) + ks * 64 + lk * 16;
            bfr = *(const i32x4*)(R1 + (off ^ swz));
        }
        #pragma unroll
        for (int mi = 0; mi < 4; ++mi) mfma_bf16(accR[mi], af[mi], bfr);
    }
    // z = re + br + dmi*enc -> f32 [64][68] at R0+8192
    const float brv = br[u * 64 + c16];
    #pragma unroll
    for (int mi = 0; mi < 4; ++mi) {
        #pragma unroll
        for (int j = 0; j < 4; ++j) {
            const int r = mi * 16 + lk * 4 + j;
            const float zv = accR[mi][j] + brv + dmis[r] * encr[mi][j];
            *(float*)(R0 + 8192 + r * 272 + c16 * 4) = zv;
        }
    }
    __syncthreads();  // I: z ready, Wr reads done

    // stage Wa1 f32 [64][32] (8KB) at R1; Wa2 f32 (2KB) at R1+17408; Wa3/ba3 at R1+24064
    #pragma unroll
    for (int it = 0; it < 2; ++it)
        gl_lds16((const char*)Wa1 + (size_t)u * 8192 + it * 4096 + t * 16,
                 R1 + it * 4096 + wid * 1024);
    if (t < 128)
        gl_lds16((const char*)Wa2 + (size_t)u * 2048 + t * 16, R1 + 17408 + wid * 1024);
    if (t < 16) ((float*)(R1 + 24064))[t] = Wa3[u * 16 + t];
    if (t == 16) ((float*)(R1 + 24064))[16] = ba3[u];
    __syncthreads();  // J

    // ===== tail: a1 = relu(z@Wa1+ba1) =====
    {
        const int row = t >> 2, g4 = t & 3;
        float accA[8] = {0.f,0.f,0.f,0.f,0.f,0.f,0.f,0.f};
        const float* zrow = (const float*)(R0 + 8192 + row * 272);
        const float* wa1s = (const float*)R1;
        for (int k = 0; k < 64; ++k) {
            const float zv = zrow[k];
            const float4 wA = *(const float4*)(wa1s + k * 32 + g4 * 8);
            const float4 wB = *(const float4*)(wa1s + k * 32 + g4 * 8 + 4);
            accA[0] += zv * wA.x; accA[1] += zv * wA.y; accA[2] += zv * wA.z; accA[3] += zv * wA.w;
            accA[4] += zv * wB.x; accA[5] += zv * wB.y; accA[6] += zv * wB.z; accA[7] += zv * wB.w;
        }
        const float4 bA = *(const float4*)(ba1 + u * 32 + g4 * 8);
        const float4 bB = *(const float4*)(ba1 + u * 32 + g4 * 8 + 4);
        float* a1s = (float*)(R1 + 8192);
        a1s[row * 34 + g4 * 8 + 0] = fmaxf(accA[0] + bA.x, 0.f);
        a1s[row * 34 + g4 * 8 + 1] = fmaxf(accA[1] + bA.y, 0.f);
        a1s[row * 34 + g4 * 8 + 2] = fmaxf(accA[2] + bA.z, 0.f);
        a1s[row * 34 + g4 * 8 + 3] = fmaxf(accA[3] + bA.w, 0.f);
        a1s[row * 34 + g4 * 8 + 4] = fmaxf(accA[4] + bB.x, 0.f);
        a1s[row * 34 + g4 * 8 + 5] = fmaxf(accA[5] + bB.y, 0.f);
        a1s[row * 34 + g4 * 8 + 6] = fmaxf(accA[6] + bB.z, 0.f);
        a1s[row * 34 + g4 * 8 + 7] = fmaxf(accA[7] + bB.w, 0.f);
    }
    __syncthreads();  // K

    // a2 = relu(a1@Wa2+ba2)
    {
        const int row = t >> 2, g4 = t & 3;
        const float* a1s = (const float*)(R1 + 8192);
        const float* wa2s = (const float*)(R1 + 17408);
        float accB[4] = {0.f,0.f,0.f,0.f};
        for (int k = 0; k < 32; ++k) {
            const float av = a1s[row * 34 + k];
            const float4 w = *(const float4*)(wa2s + k * 16 + g4 * 4);
            accB[0] += av * w.x; accB[1] += av * w.y; accB[2] += av * w.z; accB[3] += av * w.w;
        }
        const float4 bB = *(const float4*)(ba2 + u * 16 + g4 * 4);
        float* a2s = (float*)(R1 + 19456);
        a2s[row * 18 + g4 * 4 + 0] = fmaxf(accB[0] + bB.x, 0.f);
        a2s[row * 18 + g4 * 4 + 1] = fmaxf(accB[1] + bB.y, 0.f);
        a2s[row * 18 + g4 * 4 + 2] = fmaxf(accB[2] + bB.z, 0.f);
        a2s[row * 18 + g4 * 4 + 3] = fmaxf(accB[3] + bB.w, 0.f);
    }
    __syncthreads();  // L

    if (t < 64) {
        const float* a2s = (const float*)(R1 + 19456);
        const float* w3s = (const float*)(R1 + 24064);
        float a = w3s[16];
        #pragma unroll
        for (int k = 0; k < 16; ++k) a += a2s[t * 18 + k] * w3s[k];
        scores_g[(size_t)(b0 + t) * 128 + u] = 1.f / (1.f + __expf(-a));
    }
}

// ---------------- attention column-means (unchanged) ----------------
__global__ __launch_bounds__(256, 2)
void attn_kernel(const float* __restrict__ enc_g, const float* __restrict__ Wqkv,
                 const float* __restrict__ bqkv, float* __restrict__ smean)
{
    __shared__ __align__(16) float Qs[128 * 34];
    __shared__ __align__(16) float Ks[128 * 34];
    __shared__ __align__(16) float WqS[512];
    __shared__ float mrow[128];
    __shared__ float zrow[128];

    const int bx = blockIdx.x;
    const int b = bx >> 1, part = bx & 1;
    const int hb8 = part * 32;
    const int t = threadIdx.x;
    const int role = t >> 7;
    const int uu = t & 127;

    float er[64];
    {
        const float4* ep = (const float4*)(enc_g + ((size_t)b * 128 + uu) * 64);
        #pragma unroll
        for (int i = 0; i < 16; ++i) {
            const float4 v4 = ep[i];
            er[4*i] = v4.x; er[4*i+1] = v4.y; er[4*i+2] = v4.z; er[4*i+3] = v4.w;
        }
    }
    const float invsq = 0.35355339059327373f;

    for (int ch = 0; ch < 8; ++ch) {
        if (t < 128) {
            const int p2 = t >> 6;
            const int fr = (t >> 4) & 3;
            const int fe = t & 15;
            ((float4*)WqS)[t] =
                ((const float4*)(Wqkv + ((size_t)(p2 * 64 + hb8 + ch * 4 + fr)) * 64))[fe];
        }
        __syncthreads();
        #pragma unroll
        for (int fi = 0; fi < 4; ++fi) {
            const int fl = ch * 4 + fi;
            float a = bqkv[role * 64 + hb8 + fl];
            const float* wr = &WqS[(role * 4 + fi) * 64];
            #pragma unroll
            for (int e = 0; e < 64; e += 4) {
                const float4 w = *(const float4*)(wr + e);
                a += er[e] * w.x + er[e+1] * w.y + er[e+2] * w.z + er[e+3] * w.w;
            }
            if (role == 0) Qs[uu * 34 + fl] = a * invsq;
            else           Ks[uu * 34 + fl] = a;
        }
        __syncthreads();
    }

    const int q = t >> 1, half = t & 1;
    float creg = 0.f;
    for (int h = 0; h < 4; ++h) {
        const int hf = h * 8;
        float qv[8];
        #pragma unroll
        for (int d = 0; d < 8; d += 2) {
            const float2 v2 = *(const float2*)&Qs[q * 34 + hf + d];
            qv[d] = v2.x; qv[d+1] = v2.y;
        }
        float S[64];
        float mx = -3.0e38f;
        #pragma unroll
        for (int kk = 0; kk < 64; ++kk) {
            const float* kr = &Ks[(half * 64 + kk) * 34 + hf];
            float s = 0.f;
            #pragma unroll
            for (int d = 0; d < 8; d += 2) {
                const float2 v2 = *(const float2*)(kr + d);
                s += qv[d] * v2.x + qv[d+1] * v2.y;
            }
            S[kk] = s;
            mx = fmaxf(mx, s);
        }
        mx = fmaxf(mx, __shfl_xor(mx, 1));
        float Z = 0.f;
        #pragma unroll
        for (int kk = 0; kk < 64; ++kk) Z += __expf(S[kk] - mx);
        Z += __shfl_xor(Z, 1);
        if (half == 0) { mrow[q] = mx; zrow[q] = 1.f / Z; }
        __syncthreads();
        float kv[8];
        #pragma unroll
        for (int d = 0; d < 8; d += 2) {
            const float2 v2 = *(const float2*)&Ks[q * 34 + hf + d];
            kv[d] = v2.x; kv[d+1] = v2.y;
        }
        float cs = 0.f;
        for (int qq = 0; qq < 64; ++qq) {
            const int qr = half * 64 + qq;
            const float* qrp = &Qs[qr * 34 + hf];
            float s = 0.f;
            #pragma unroll
            for (int d = 0; d < 8; d += 2) {
                const float2 v2 = *(const float2*)(qrp + d);
                s += kv[d] * v2.x + kv[d+1] * v2.y;
            }
            cs += __expf(s - mrow[qr]) * zrow[qr];
        }
        creg += cs;
        __syncthreads();
    }
    creg += __shfl_xor(creg, 1);
    if (half == 0)
        smean[(size_t)part * 131072 + (size_t)b * 128 + q] = creg * (1.f / 1024.f);
}

__global__ __launch_bounds__(64)
void final_kernel(const float* __restrict__ scores_g, const float* __restrict__ smean,
                  const float* __restrict__ Wc1, const float* __restrict__ bc1,
                  const float* __restrict__ Wc2, const float* __restrict__ bc2,
                  const float* __restrict__ Wc3, const float* __restrict__ bc3,
                  float* __restrict__ out)
{
    __shared__ float sc[128];
    __shared__ float c1[64];
    __shared__ float c2[32];
    const int b = blockIdx.x, t = threadIdx.x;
    const float s0 = scores_g[(size_t)b * 128 + t];
    const float s1 = scores_g[(size_t)b * 128 + 64 + t];
    sc[t] = s0; sc[64 + t] = s1;
    const float v0 = smean[(size_t)b * 128 + t]      + smean[131072 + (size_t)b * 128 + t];
    const float v1 = smean[(size_t)b * 128 + 64 + t] + smean[131072 + (size_t)b * 128 + 64 + t];
    __syncthreads();
    float a = bc1[t];
    #pragma unroll 8
    for (int i = 0; i < 128; ++i) a += sc[i] * Wc1[i * 64 + t];
    c1[t] = fmaxf(a, 0.f);
    __syncthreads();
    if (t < 32) {
        float a2 = bc2[t];
        #pragma unroll 8
        for (int i = 0; i < 64; ++i) a2 += c1[i] * Wc2[i * 32 + t];
        c2[t] = fmaxf(a2, 0.f);
    }
    __syncthreads();
    float p = (t < 32) ? c2[t] * Wc3[t] : 0.f;
    #pragma unroll
    for (int m = 1; m < 64; m <<= 1) p += __shfl_xor(p, m);
    const float cons = 1.f / (1.f + __expf(-(p + bc3[0])));

    float sum = s0 + s1;
    float sq  = s0 * s0 + s1 * s1;
    float wsm = s0 * v0 + s1 * v1;
    float na  = (s0 > 0.1f ? 1.f : 0.f) + (s1 > 0.1f ? 1.f : 0.f);
    #pragma unroll
    for (int m = 1; m < 64; m <<= 1) {
        sum += __shfl_xor(sum, m); sq += __shfl_xor(sq, m);
        wsm += __shfl_xor(wsm, m); na += __shfl_xor(na, m);
    }
    if (t == 0) {
        const float mean = sum * (1.f / 128.f);
        float var = (sq - 128.f * mean * mean) * (1.f / 127.f);
        var = fmaxf(var, 0.f);
        const float agree = 1.f - sqrtf(var) / (mean + 1e-8f);
        out[b]        = cons * wsm;
        out[1024 + b] = (cons > 0.95f) ? 1.f : 0.f;
        out[2048 + b] = agree;
        out[3072 + b] = cons;
        out[4097 + b] = na;
    }
}

__global__ void attnmean_kernel(const float* __restrict__ smean, float* __restrict__ out)
{
    __shared__ float red[256];
    const int t = threadIdx.x;
    float s = 0.f;
    for (int i = t; i < 262144; i += 256) s += smean[i];
    red[t] = s;
    __syncthreads();
    for (int w = 128; w > 0; w >>= 1) {
        if (t < w) red[t] += red[t + w];
        __syncthreads();
    }
    if (t == 0) out[4096] = red[0] * (1.f / 131072.f);
}

extern "C" void kernel_launch(void* const* d_in, const int* in_sizes, int n_in,
                              void* d_out, int out_size, void* d_ws, size_t ws_size,
                              hipStream_t stream)
{
    const float* x    = (const float*)d_in[0];
    const float* fs   = (const float*)d_in[1];
    const float* dm   = (const float*)d_in[2];
    const float* W1   = (const float*)d_in[3];
    const float* b1   = (const float*)d_in[4];
    const float* g1   = (const float*)d_in[5];
    const float* be1  = (const float*)d_in[6];
    const float* W2   = (const float*)d_in[7];
    const float* b2   = (const float*)d_in[8];
    const float* g2   = (const float*)d_in[9];
    const float* be2  = (const float*)d_in[10];
    const float* W3   = (const float*)d_in[11];
    const float* b3   = (const float*)d_in[12];
    const float* Wr   = (const float*)d_in[13];
    const float* br   = (const float*)d_in[14];
    const float* Wa1  = (const float*)d_in[15];
    const float* ba1  = (const float*)d_in[16];
    const float* Wa2  = (const float*)d_in[17];
    const float* ba2  = (const float*)d_in[18];
    const float* Wa3  = (const float*)d_in[19];
    const float* ba3  = (const float*)d_in[20];
    const float* Wqkv = (const float*)d_in[21];
    const float* bqkv = (const float*)d_in[22];
    // d_in[23]=Wo, d_in[24]=bo unused downstream
    const float* Wc1  = (const float*)d_in[25];
    const float* bc1  = (const float*)d_in[26];
    const float* Wc2  = (const float*)d_in[27];
    const float* bc2  = (const float*)d_in[28];
    const float* Wc3  = (const float*)d_in[29];
    const float* bc3  = (const float*)d_in[30];

    float* out = (float*)d_out;
    char*  ws8 = (char*)d_ws;
    float* enc    = (float*)ws8;                       // 8388608 f32
    float* scores = (float*)(ws8 + 33554432);          // 131072 f32
    float* smean  = (float*)(ws8 + 34078720);          // 262144 f32
    unsigned short* xb  = (unsigned short*)(ws8 + 35127296);   // 262144 bf16
    unsigned short* W1t = (unsigned short*)(ws8 + 35651584);   // 8388608 bf16
    unsigned short* W2t = (unsigned short*)(ws8 + 52428800);   // 4194304 bf16
    unsigned short* W3t = (unsigned short*)(ws8 + 60817408);   // 1048576 bf16
    unsigned short* Wrt = (unsigned short*)(ws8 + 62914560);   // 524288 bf16

    prep_kernel<<<3584, 256, 0, stream>>>(W1, W2, W3, Wr, x, W1t, W2t, W3t, Wrt, xb);
    fused_mfma<<<2048, 256, 0, stream>>>(xb, W1t, W2t, W3t, Wrt, fs, dm,
                                         b1, g1, be1, b2, g2, be2, b3, br,
                                         Wa1, ba1, Wa2, ba2, Wa3, ba3,
                                         enc, scores);
    attn_kernel<<<2048, 256, 0, stream>>>(enc, Wqkv, bqkv, smean);
    final_kernel<<<1024, 64, 0, stream>>>(scores, smean, Wc1, bc1, Wc2, bc2, Wc3, bc3, out);
    attnmean_kernel<<<1, 256, 0, stream>>>(smean, out);
}

// Round 3
// 345.039 us; speedup vs baseline: 3.0902x; 1.8179x over previous
//
#include <hip/hip_runtime.h>
#include <math.h>

// U=128, D=256, B=1024, E=64, H=8
// prep_kernel : f32 -> bf16 transposed weights ([n][k]) + x -> bf16 + Wqkv(QK rows) -> bf16
// fused_mfma  : per (u, 64-row batch tile): GEMM1(MFMA)+LN -> GEMM2(MFMA)+LN ->
//               GEMM3(MFMA) -> enc(bf16 out), dmi -> Wr(MFMA) -> z -> VALU tail -> scores
// attn_kernel : MFMA Q/K proj + register-tiled softmax column means -> smean[B][U]
// final/attnmean: outputs

typedef float f32x4 __attribute__((ext_vector_type(4)));
typedef int   i32x4 __attribute__((ext_vector_type(4)));

__device__ __forceinline__ void mfma_bf16(f32x4& c, i32x4 a, i32x4 b) {
    asm("v_mfma_f32_16x16x32_bf16 %0, %1, %2, %0" : "+v"(c) : "v"(a), "v"(b));
}

__device__ __forceinline__ void gl_lds16(const void* g, void* l) {
    __builtin_amdgcn_global_load_lds(
        (const __attribute__((address_space(1))) unsigned int*)g,
        (__attribute__((address_space(3))) unsigned int*)l, 16, 0, 0);
}

__device__ __forceinline__ unsigned short f2bf(float v) {
    union { __bf16 b; unsigned short u; } cv;
    cv.b = (__bf16)v;
    return cv.u;
}
__device__ __forceinline__ float bflo(unsigned int u) {
    union { unsigned int i; float f; } c; c.i = u << 16; return c.f;
}
__device__ __forceinline__ float bfhi(unsigned int u) {
    union { unsigned int i; float f; } c; c.i = u & 0xffff0000u; return c.f;
}

// ---------------- prep: convert + transpose weights to bf16 ----------------
__global__ __launch_bounds__(256)
void prep_kernel(const float* __restrict__ W1, const float* __restrict__ W2,
                 const float* __restrict__ W3, const float* __restrict__ Wr,
                 const float* __restrict__ x, const float* __restrict__ Wqkv,
                 unsigned short* __restrict__ W1t, unsigned short* __restrict__ W2t,
                 unsigned short* __restrict__ W3t, unsigned short* __restrict__ Wrt,
                 unsigned short* __restrict__ xb, unsigned short* __restrict__ wqkvb)
{
    const int bid = blockIdx.x, t = threadIdx.x;
    if (bid >= 3456) {  // plain convert, no transpose
        const float* src; unsigned short* dst; int base;
        if (bid >= 3584) { src = Wqkv; dst = wqkvb; base = (bid - 3584) * 2048 + t * 8; }
        else             { src = x;    dst = xb;    base = (bid - 3456) * 2048 + t * 8; }
        const float4 v0 = *(const float4*)(src + base);
        const float4 v1 = *(const float4*)(src + base + 4);
        __align__(16) unsigned short o[8];
        o[0]=f2bf(v0.x); o[1]=f2bf(v0.y); o[2]=f2bf(v0.z); o[3]=f2bf(v0.w);
        o[4]=f2bf(v1.x); o[5]=f2bf(v1.y); o[6]=f2bf(v1.z); o[7]=f2bf(v1.w);
        *(uint4*)(dst + base) = *(const uint4*)o;
        return;
    }
    const float* src; unsigned short* dst; int u, k0, n0, K, N;
    if (bid < 2048)      { u = bid >> 4;        int tl = bid & 15;       k0 = (tl>>2)*64; n0 = (tl&3)*64; K=256; N=256; src = W1 + (size_t)u*65536; dst = W1t + (size_t)u*65536; }
    else if (bid < 3072) { int b2 = bid - 2048; u = b2 >> 3; int tl = b2 & 7; k0 = (tl>>1)*64; n0 = (tl&1)*64; K=256; N=128; src = W2 + (size_t)u*32768; dst = W2t + (size_t)u*32768; }
    else if (bid < 3328) { int b3 = bid - 3072; u = b3 >> 1; int tl = b3 & 1; k0 = tl*64;      n0 = 0;         K=128; N=64;  src = W3 + (size_t)u*8192;  dst = W3t + (size_t)u*8192;  }
    else                 { u = bid - 3328;      k0 = 0; n0 = 0;                                 K=64;  N=64;  src = Wr + (size_t)u*4096;  dst = Wrt + (size_t)u*4096;  }

    __shared__ unsigned short tile[64 * 65];
    #pragma unroll
    for (int i = 0; i < 16; ++i) {
        const int e = i * 256 + t;
        const int kk = e >> 6, nn = e & 63;
        tile[kk * 65 + nn] = f2bf(src[(size_t)(k0 + kk) * N + n0 + nn]);
    }
    __syncthreads();
    #pragma unroll
    for (int i = 0; i < 16; ++i) {
        const int e = i * 256 + t;
        const int nn = e >> 6, kk = e & 63;
        dst[(size_t)(n0 + nn) * K + k0 + kk] = tile[kk * 65 + nn];
    }
}

// ---------------- fused universe chain (MFMA) ----------------
__global__ __launch_bounds__(256, 2)
void fused_mfma(const unsigned short* __restrict__ xb,
                const unsigned short* __restrict__ W1t, const unsigned short* __restrict__ W2t,
                const unsigned short* __restrict__ W3t, const unsigned short* __restrict__ Wrt,
                const float* __restrict__ fs, const float* __restrict__ dm,
                const float* __restrict__ b1, const float* __restrict__ g1, const float* __restrict__ be1,
                const float* __restrict__ b2, const float* __restrict__ g2, const float* __restrict__ be2,
                const float* __restrict__ b3, const float* __restrict__ br,
                const float* __restrict__ Wa1, const float* __restrict__ ba1,
                const float* __restrict__ Wa2, const float* __restrict__ ba2,
                const float* __restrict__ Wa3, const float* __restrict__ ba3,
                unsigned short* __restrict__ enc_bfg, float* __restrict__ scores_g)
{
    __shared__ __align__(128) char sm[69632];
    char* R0 = sm;             // 32 KB: A_x -> H1 -> H2/enc_bf/z
    char* R1 = sm + 32768;     // 32 KB: B panels -> Wa1/a1/Wa2/a2/Wa3
    char* R2 = sm + 65536;     // 4 KB : pS, pQ(+1024), rstats(+2048), dmi(+2560)
    float* pS = (float*)R2;
    float* pQ = (float*)(R2 + 1024);
    float2* rst = (float2*)(R2 + 2048);
    float* dmis = (float*)(R2 + 2560);

    const int t = threadIdx.x;
    const int wid = t >> 6, lane = t & 63, l15 = lane & 15, lk = lane >> 4;
    const int swz = (l15 & 7) << 4;
    const int bx = blockIdx.x;
    const int xcd = bx & 7, idx = bx >> 3;
    const int u = ((idx >> 4) << 3) + xcd;
    const int b0 = (idx & 15) * 64;

    const float corru = fs[u] * 137.036f;
    const float dmu = dm[u];

    const char* xbase = (const char*)xb + (size_t)b0 * 512;
    const char* w1u = (const char*)W1t + (size_t)u * 131072;
    const char* w2u = (const char*)W2t + (size_t)u * 65536;
    const char* w3u = (const char*)W3t + (size_t)u * 16384;
    const char* wru = (const char*)Wrt + (size_t)u * 8192;

    #pragma unroll
    for (int it = 0; it < 8; ++it) {
        const int d = it * 4096 + t * 16;
        const int s = d ^ (((d >> 9) & 7) << 4);
        gl_lds16(xbase + s, R0 + it * 4096 + wid * 1024);
    }
    #pragma unroll
    for (int it = 0; it < 8; ++it) {
        const int d = it * 4096 + t * 16;
        const int s = d ^ (((d >> 7) & 7) << 4);
        gl_lds16(w1u + (s >> 7) * 512 + (s & 127), R1 + it * 4096 + wid * 1024);
    }
    __syncthreads();

    // ===== GEMM1: [64][256] = A_x @ W1t, K=256 =====
    const f32x4 z4 = {0.f, 0.f, 0.f, 0.f};
    f32x4 acc[4][4];
    #pragma unroll
    for (int mi = 0; mi < 4; ++mi)
        #pragma unroll
        for (int ni = 0; ni < 4; ++ni) acc[mi][ni] = z4;

    for (int p = 0; p < 4; ++p) {
        #pragma unroll
        for (int ks = 0; ks < 2; ++ks) {
            i32x4 af[4], bf[4];
            #pragma unroll
            for (int mi = 0; mi < 4; ++mi) {
                const int off = ((mi * 16 + l15) << 9) + p * 128 + ks * 64 + lk * 16;
                af[mi] = *(const i32x4*)(R0 + (off ^ swz));
            }
            #pragma unroll
            for (int ni = 0; ni < 4; ++ni) {
                const int off = ((wid * 64 + ni * 16 + l15) << 7) + ks * 64 + lk * 16;
                bf[ni] = *(const i32x4*)(R1 + (off ^ swz));
            }
            #pragma unroll
            for (int mi = 0; mi < 4; ++mi)
                #pragma unroll
                for (int ni = 0; ni < 4; ++ni) mfma_bf16(acc[mi][ni], af[mi], bf[ni]);
        }
        if (p < 3) {
            __syncthreads();
            #pragma unroll
            for (int it = 0; it < 8; ++it) {
                const int d = it * 4096 + t * 16;
                const int s = d ^ (((d >> 7) & 7) << 4);
                gl_lds16(w1u + (s >> 7) * 512 + (p + 1) * 128 + (s & 127), R1 + it * 4096 + wid * 1024);
            }
            __syncthreads();
        }
    }

    // ===== LN1 + relu -> H1 bf16 =====
    float bb[4], gg[4], ee[4];
    #pragma unroll
    for (int ni = 0; ni < 4; ++ni) {
        const int c = wid * 64 + ni * 16 + l15;
        bb[ni] = b1[u * 256 + c]; gg[ni] = g1[u * 256 + c]; ee[ni] = be1[u * 256 + c];
    }
    #pragma unroll
    for (int mi = 0; mi < 4; ++mi) {
        #pragma unroll
        for (int j = 0; j < 4; ++j) {
            float s = 0.f, q = 0.f;
            #pragma unroll
            for (int ni = 0; ni < 4; ++ni) {
                const float h = acc[mi][ni][j] * corru + bb[ni];
                acc[mi][ni][j] = h;
                s += h; q += h * h;
            }
            #pragma unroll
            for (int m = 1; m < 16; m <<= 1) { s += __shfl_xor(s, m); q += __shfl_xor(q, m); }
            if (l15 == 0) {
                const int r = mi * 16 + lk * 4 + j;
                pS[wid * 64 + r] = s; pQ[wid * 64 + r] = q;
            }
        }
    }
    __syncthreads();
    if (t < 64) {
        const float s = pS[t] + pS[64 + t] + pS[128 + t] + pS[192 + t];
        const float q = pQ[t] + pQ[64 + t] + pQ[128 + t] + pQ[192 + t];
        const float mean = s * (1.f / 256.f);
        const float var = fmaxf(q * (1.f / 256.f) - mean * mean, 0.f);
        rst[t] = make_float2(mean, rsqrtf(var + 1e-5f));
    }
    #pragma unroll
    for (int it = 0; it < 4; ++it) {
        const int d = it * 4096 + t * 16;
        const int s = d ^ (((d >> 7) & 7) << 4);
        gl_lds16(w2u + (s >> 7) * 512 + (s & 127), R1 + it * 4096 + wid * 1024);
    }
    __syncthreads();
    #pragma unroll
    for (int mi = 0; mi < 4; ++mi) {
        #pragma unroll
        for (int j = 0; j < 4; ++j) {
            const int r = mi * 16 + lk * 4 + j;
            const float2 st = rst[r];
            #pragma unroll
            for (int ni = 0; ni < 4; ++ni) {
                const float h = fmaxf((acc[mi][ni][j] - st.x) * st.y * gg[ni] + ee[ni], 0.f);
                const int c = wid * 64 + ni * 16 + l15;
                const int off = (r << 9) + c * 2;
                *(__bf16*)(R0 + (off ^ ((r & 7) << 4))) = (__bf16)h;
            }
        }
    }
    __syncthreads();

    // ===== GEMM2: [64][128] = H1 @ W2t, K=256 =====
    f32x4 acc2[4][2];
    #pragma unroll
    for (int mi = 0; mi < 4; ++mi) { acc2[mi][0] = z4; acc2[mi][1] = z4; }
    for (int p = 0; p < 4; ++p) {
        if (p < 3) {
            #pragma unroll
            for (int it = 0; it < 4; ++it) {
                const int d = it * 4096 + t * 16;
                const int s = d ^ (((d >> 7) & 7) << 4);
                gl_lds16(w2u + (s >> 7) * 512 + (p + 1) * 128 + (s & 127),
                         R1 + ((p + 1) & 1) * 16384 + it * 4096 + wid * 1024);
            }
        }
        #pragma unroll
        for (int ks = 0; ks < 2; ++ks) {
            i32x4 af[4], bf2[2];
            #pragma unroll
            for (int mi = 0; mi < 4; ++mi) {
                const int off = ((mi * 16 + l15) << 9) + p * 128 + ks * 64 + lk * 16;
                af[mi] = *(const i32x4*)(R0 + (off ^ swz));
            }
            #pragma unroll
            for (int ni = 0; ni < 2; ++ni) {
                const int off = ((wid * 32 + ni * 16 + l15) << 7) + ks * 64 + lk * 16;
                bf2[ni] = *(const i32x4*)(R1 + (p & 1) * 16384 + (off ^ swz));
            }
            #pragma unroll
            for (int mi = 0; mi < 4; ++mi)
                #pragma unroll
                for (int ni = 0; ni < 2; ++ni) mfma_bf16(acc2[mi][ni], af[mi], bf2[ni]);
        }
        __syncthreads();
    }

    // ===== LN2 + relu -> H2 bf16 =====
    float bb2[2], gg2[2], ee2[2];
    #pragma unroll
    for (int ni = 0; ni < 2; ++ni) {
        const int c = wid * 32 + ni * 16 + l15;
        bb2[ni] = b2[u * 128 + c]; gg2[ni] = g2[u * 128 + c]; ee2[ni] = be2[u * 128 + c];
    }
    #pragma unroll
    for (int mi = 0; mi < 4; ++mi) {
        #pragma unroll
        for (int j = 0; j < 4; ++j) {
            float s = 0.f, q = 0.f;
            #pragma unroll
            for (int ni = 0; ni < 2; ++ni) {
                const float h = acc2[mi][ni][j] + bb2[ni];
                acc2[mi][ni][j] = h;
                s += h; q += h * h;
            }
            #pragma unroll
            for (int m = 1; m < 16; m <<= 1) { s += __shfl_xor(s, m); q += __shfl_xor(q, m); }
            if (l15 == 0) {
                const int r = mi * 16 + lk * 4 + j;
                pS[wid * 64 + r] = s; pQ[wid * 64 + r] = q;
            }
        }
    }
    __syncthreads();
    if (t < 64) {
        const float s = pS[t] + pS[64 + t] + pS[128 + t] + pS[192 + t];
        const float q = pQ[t] + pQ[64 + t] + pQ[128 + t] + pQ[192 + t];
        const float mean = s * (1.f / 128.f);
        const float var = fmaxf(q * (1.f / 128.f) - mean * mean, 0.f);
        rst[t] = make_float2(mean, rsqrtf(var + 1e-5f));
    }
    #pragma unroll
    for (int it = 0; it < 4; ++it) {
        const int d = it * 4096 + t * 16;
        const int s = d ^ (((d >> 8) & 7) << 4);
        gl_lds16(w3u + (s >> 8) * 256 + (s & 255), R1 + it * 4096 + wid * 1024);
    }
    __syncthreads();
    #pragma unroll
    for (int mi = 0; mi < 4; ++mi) {
        #pragma unroll
        for (int j = 0; j < 4; ++j) {
            const int r = mi * 16 + lk * 4 + j;
            const float2 st = rst[r];
            #pragma unroll
            for (int ni = 0; ni < 2; ++ni) {
                const float h = fmaxf((acc2[mi][ni][j] - st.x) * st.y * gg2[ni] + ee2[ni], 0.f);
                const int c = wid * 32 + ni * 16 + l15;
                const int off = (r << 8) + c * 2;
                *(__bf16*)(R0 + (off ^ ((r & 7) << 4))) = (__bf16)h;
            }
        }
    }
    __syncthreads();

    // ===== GEMM3: enc [64][64] = H2 @ W3t, K=128 =====
    f32x4 acc3[4];
    #pragma unroll
    for (int mi = 0; mi < 4; ++mi) acc3[mi] = z4;
    #pragma unroll
    for (int ks = 0; ks < 4; ++ks) {
        i32x4 af[4], bfr;
        #pragma unroll
        for (int mi = 0; mi < 4; ++mi) {
            const int off = ((mi * 16 + l15) << 8) + ks * 64 + lk * 16;
            af[mi] = *(const i32x4*)(R0 + (off ^ swz));
        }
        {
            const int off = ((wid * 16 + l15) << 8) + ks * 64 + lk * 16;
            bfr = *(const i32x4*)(R1 + (off ^ swz));
        }
        #pragma unroll
        for (int mi = 0; mi < 4; ++mi) mfma_bf16(acc3[mi], af[mi], bfr);
    }
    // epilogue: +b3, global enc write (bf16), sumsq partials
    const int c16 = wid * 16 + l15;
    const float b3v = b3[u * 64 + c16];
    float encr[4][4];
    #pragma unroll
    for (int mi = 0; mi < 4; ++mi) {
        #pragma unroll
        for (int j = 0; j < 4; ++j) {
            const float e = acc3[mi][j] + b3v;
            encr[mi][j] = e;
            const int r = mi * 16 + lk * 4 + j;
            enc_bfg[((size_t)(b0 + r) * 128 + u) * 64 + c16] = f2bf(e);
            float q = e * e;
            #pragma unroll
            for (int m = 1; m < 16; m <<= 1) q += __shfl_xor(q, m);
            if (l15 == 0) pQ[wid * 64 + r] = q;
        }
    }
    __syncthreads();
    if (t < 64) {
        const float q = pQ[t] + pQ[64 + t] + pQ[128 + t] + pQ[192 + t];
        dmis[t] = tanhf(dmu * q);
    }
    #pragma unroll
    for (int it = 0; it < 2; ++it) {
        const int d = it * 4096 + t * 16;
        const int s = d ^ (((d >> 7) & 7) << 4);
        gl_lds16(wru + (s >> 7) * 128 + (s & 127), R1 + it * 4096 + wid * 1024);
    }
    #pragma unroll
    for (int mi = 0; mi < 4; ++mi) {
        #pragma unroll
        for (int j = 0; j < 4; ++j) {
            const int r = mi * 16 + lk * 4 + j;
            const int off = (r << 7) + c16 * 2;
            *(__bf16*)(R0 + (off ^ ((r & 7) << 4))) = (__bf16)encr[mi][j];
        }
    }
    __syncthreads();

    // ===== Wr: re [64][64] = enc_bf @ Wrt, K=64 =====
    f32x4 accR[4];
    #pragma unroll
    for (int mi = 0; mi < 4; ++mi) accR[mi] = z4;
    #pragma unroll
    for (int ks = 0; ks < 2; ++ks) {
        i32x4 af[4], bfr;
        #pragma unroll
        for (int mi = 0; mi < 4; ++mi) {
            const int off = ((mi * 16 + l15) << 7) + ks * 64 + lk * 16;
            af[mi] = *(const i32x4*)(R0 + (off ^ swz));
        }
        {
            const int off = ((wid * 16 + l15) << 7) + ks * 64 + lk * 16;
            bfr = *(const i32x4*)(R1 + (off ^ swz));
        }
        #pragma unroll
        for (int mi = 0; mi < 4; ++mi) mfma_bf16(accR[mi], af[mi], bfr);
    }
    const float brv = br[u * 64 + c16];
    #pragma unroll
    for (int mi = 0; mi < 4; ++mi) {
        #pragma unroll
        for (int j = 0; j < 4; ++j) {
            const int r = mi * 16 + lk * 4 + j;
            const float zv = accR[mi][j] + brv + dmis[r] * encr[mi][j];
            *(float*)(R0 + 8192 + r * 272 + c16 * 4) = zv;
        }
    }
    __syncthreads();

    #pragma unroll
    for (int it = 0; it < 2; ++it)
        gl_lds16((const char*)Wa1 + (size_t)u * 8192 + it * 4096 + t * 16,
                 R1 + it * 4096 + wid * 1024);
    if (t < 128)
        gl_lds16((const char*)Wa2 + (size_t)u * 2048 + t * 16, R1 + 17408 + wid * 1024);
    if (t < 16) ((float*)(R1 + 24064))[t] = Wa3[u * 16 + t];
    if (t == 16) ((float*)(R1 + 24064))[16] = ba3[u];
    __syncthreads();

    // ===== tail =====
    {
        const int row = t >> 2, g4 = t & 3;
        float accA[8] = {0.f,0.f,0.f,0.f,0.f,0.f,0.f,0.f};
        const float* zrow = (const float*)(R0 + 8192 + row * 272);
        const float* wa1s = (const float*)R1;
        for (int k = 0; k < 64; ++k) {
            const float zv = zrow[k];
            const float4 wA = *(const float4*)(wa1s + k * 32 + g4 * 8);
            const float4 wB = *(const float4*)(wa1s + k * 32 + g4 * 8 + 4);
            accA[0] += zv * wA.x; accA[1] += zv * wA.y; accA[2] += zv * wA.z; accA[3] += zv * wA.w;
            accA[4] += zv * wB.x; accA[5] += zv * wB.y; accA[6] += zv * wB.z; accA[7] += zv * wB.w;
        }
        const float4 bA = *(const float4*)(ba1 + u * 32 + g4 * 8);
        const float4 bB = *(const float4*)(ba1 + u * 32 + g4 * 8 + 4);
        float* a1s = (float*)(R1 + 8192);
        a1s[row * 34 + g4 * 8 + 0] = fmaxf(accA[0] + bA.x, 0.f);
        a1s[row * 34 + g4 * 8 + 1] = fmaxf(accA[1] + bA.y, 0.f);
        a1s[row * 34 + g4 * 8 + 2] = fmaxf(accA[2] + bA.z, 0.f);
        a1s[row * 34 + g4 * 8 + 3] = fmaxf(accA[3] + bA.w, 0.f);
        a1s[row * 34 + g4 * 8 + 4] = fmaxf(accA[4] + bB.x, 0.f);
        a1s[row * 34 + g4 * 8 + 5] = fmaxf(accA[5] + bB.y, 0.f);
        a1s[row * 34 + g4 * 8 + 6] = fmaxf(accA[6] + bB.z, 0.f);
        a1s[row * 34 + g4 * 8 + 7] = fmaxf(accA[7] + bB.w, 0.f);
    }
    __syncthreads();

    {
        const int row = t >> 2, g4 = t & 3;
        const float* a1s = (const float*)(R1 + 8192);
        const float* wa2s = (const float*)(R1 + 17408);
        float accB[4] = {0.f,0.f,0.f,0.f};
        for (int k = 0; k < 32; ++k) {
            const float av = a1s[row * 34 + k];
            const float4 w = *(const float4*)(wa2s + k * 16 + g4 * 4);
            accB[0] += av * w.x; accB[1] += av * w.y; accB[2] += av * w.z; accB[3] += av * w.w;
        }
        const float4 bB = *(const float4*)(ba2 + u * 16 + g4 * 4);
        float* a2s = (float*)(R1 + 19456);
        a2s[row * 18 + g4 * 4 + 0] = fmaxf(accB[0] + bB.x, 0.f);
        a2s[row * 18 + g4 * 4 + 1] = fmaxf(accB[1] + bB.y, 0.f);
        a2s[row * 18 + g4 * 4 + 2] = fmaxf(accB[2] + bB.z, 0.f);
        a2s[row * 18 + g4 * 4 + 3] = fmaxf(accB[3] + bB.w, 0.f);
    }
    __syncthreads();

    if (t < 64) {
        const float* a2s = (const float*)(R1 + 19456);
        const float* w3s = (const float*)(R1 + 24064);
        float a = w3s[16];
        #pragma unroll
        for (int k = 0; k < 16; ++k) a += a2s[t * 18 + k] * w3s[k];
        scores_g[(size_t)(b0 + t) * 128 + u] = 1.f / (1.f + __expf(-a));
    }
}

// ---------------- attention column-means (MFMA proj + register softmax) ----------------
__global__ __launch_bounds__(256, 2)
void attn_kernel(const unsigned short* __restrict__ enc_bf,
                 const unsigned short* __restrict__ wqkv_bf,
                 const float* __restrict__ bqkv, float* __restrict__ smean)
{
    __shared__ __align__(128) char sm[65536];
    char* ENCs = sm;            // 16KB [128][64] bf16 swz(r&7)
    char* Qs   = sm + 16384;    // 16KB [128][64] bf16 swz(r>>3 &7)
    char* Ks   = sm + 32768;    // 16KB
    char* WQs  = sm + 49152;    // 16KB Wqkv rows 0..127
    float* colp = (float*)sm;   // alias (ENC dead after proj)

    const int t = threadIdx.x;
    const int wid = t >> 6, lane = t & 63, l15 = lane & 15, lk = lane >> 4;
    const int swz = (l15 & 7) << 4;
    const int b = blockIdx.x;

    const char* eb = (const char*)(enc_bf + (size_t)b * 8192);
    #pragma unroll
    for (int it = 0; it < 4; ++it) {
        const int d = it * 4096 + t * 16;
        const int s = d ^ (((d >> 7) & 7) << 4);
        gl_lds16(eb + s, ENCs + it * 4096 + wid * 1024);
    }
    const char* wb = (const char*)wqkv_bf;
    #pragma unroll
    for (int it = 0; it < 4; ++it) {
        const int d = it * 4096 + t * 16;
        const int s = d ^ (((d >> 7) & 7) << 4);
        gl_lds16(wb + s, WQs + it * 4096 + wid * 1024);
    }
    __syncthreads();

    // ===== proj: Q,K [128][64] = enc @ Wqkv[0:64 / 64:128]^T =====
    const f32x4 z4 = {0.f,0.f,0.f,0.f};
    f32x4 aq[2][4], ak[2][4];
    #pragma unroll
    for (int mi = 0; mi < 2; ++mi)
        #pragma unroll
        for (int ni = 0; ni < 4; ++ni) { aq[mi][ni] = z4; ak[mi][ni] = z4; }

    i32x4 af[2][2];
    #pragma unroll
    for (int mi = 0; mi < 2; ++mi)
        #pragma unroll
        for (int ks = 0; ks < 2; ++ks) {
            const int off = ((wid * 32 + mi * 16 + l15) << 7) + ks * 64 + lk * 16;
            af[mi][ks] = *(const i32x4*)(ENCs + (off ^ swz));
        }
    #pragma unroll
    for (int ni = 0; ni < 4; ++ni)
        #pragma unroll
        for (int ks = 0; ks < 2; ++ks) {
            const int offq = ((ni * 16 + l15) << 7) + ks * 64 + lk * 16;
            const i32x4 bq = *(const i32x4*)(WQs + (offq ^ swz));
            mfma_bf16(aq[0][ni], af[0][ks], bq);
            mfma_bf16(aq[1][ni], af[1][ks], bq);
            const i32x4 bk = *(const i32x4*)(WQs + ((offq + 8192) ^ swz));
            mfma_bf16(ak[0][ni], af[0][ks], bk);
            mfma_bf16(ak[1][ni], af[1][ks], bk);
        }

    const float invsq = 0.35355339059327373f;
    float bqv[4], bkv[4];
    #pragma unroll
    for (int ni = 0; ni < 4; ++ni) {
        bqv[ni] = bqkv[ni * 16 + l15];
        bkv[ni] = bqkv[64 + ni * 16 + l15];
    }
    #pragma unroll
    for (int mi = 0; mi < 2; ++mi)
        #pragma unroll
        for (int ni = 0; ni < 4; ++ni)
            #pragma unroll
            for (int j = 0; j < 4; ++j) {
                const int row = wid * 32 + mi * 16 + lk * 4 + j;
                const int f = ni * 16 + l15;
                const int addr = row * 128 + f * 2;
                const int phys = addr ^ (((addr >> 10) & 7) << 4);
                *(__bf16*)(Qs + phys) = (__bf16)((aq[mi][ni][j] + bqv[ni]) * invsq);
                *(__bf16*)(Ks + phys) = (__bf16)(ak[mi][ni][j] + bkv[ni]);
            }
    __syncthreads();

    // ===== S = QK^T per head, register-tiled softmax + column sums =====
    const int cg = t & 7, qg = t >> 3;   // col group (16 cols), row group (4 rows)
    float cp[16];
    #pragma unroll
    for (int kk = 0; kk < 16; ++kk) cp[kk] = 0.f;

    for (int h = 0; h < 8; ++h) {
        float qv[4][8];
        #pragma unroll
        for (int j = 0; j < 4; ++j) {
            const int addr = (qg * 4 + j) * 128 + h * 16;
            const uint4 w = *(const uint4*)(Qs + (addr ^ (((addr >> 10) & 7) << 4)));
            qv[j][0]=bflo(w.x); qv[j][1]=bfhi(w.x); qv[j][2]=bflo(w.y); qv[j][3]=bfhi(w.y);
            qv[j][4]=bflo(w.z); qv[j][5]=bfhi(w.z); qv[j][6]=bflo(w.w); qv[j][7]=bfhi(w.w);
        }
        float s[4][16];
        #pragma unroll
        for (int j = 0; j < 4; ++j)
            #pragma unroll
            for (int kk = 0; kk < 16; ++kk) s[j][kk] = 0.f;
        #pragma unroll
        for (int kk = 0; kk < 16; ++kk) {
            const int addr = (cg * 16 + kk) * 128 + h * 16;
            const uint4 w = *(const uint4*)(Ks + (addr ^ (((addr >> 10) & 7) << 4)));
            float kv[8];
            kv[0]=bflo(w.x); kv[1]=bfhi(w.x); kv[2]=bflo(w.y); kv[3]=bfhi(w.y);
            kv[4]=bflo(w.z); kv[5]=bfhi(w.z); kv[6]=bflo(w.w); kv[7]=bfhi(w.w);
            #pragma unroll
            for (int j = 0; j < 4; ++j)
                #pragma unroll
                for (int d = 0; d < 8; ++d)
                    s[j][kk] += qv[j][d] * kv[d];
        }
        #pragma unroll
        for (int j = 0; j < 4; ++j) {
            float mx = s[j][0];
            #pragma unroll
            for (int kk = 1; kk < 16; ++kk) mx = fmaxf(mx, s[j][kk]);
            mx = fmaxf(mx, __shfl_xor(mx, 1));
            mx = fmaxf(mx, __shfl_xor(mx, 2));
            mx = fmaxf(mx, __shfl_xor(mx, 4));
            float z = 0.f;
            #pragma unroll
            for (int kk = 0; kk < 16; ++kk) { s[j][kk] = __expf(s[j][kk] - mx); z += s[j][kk]; }
            z += __shfl_xor(z, 1); z += __shfl_xor(z, 2); z += __shfl_xor(z, 4);
            const float zi = 1.f / z;
            #pragma unroll
            for (int kk = 0; kk < 16; ++kk) cp[kk] += s[j][kk] * zi;
        }
    }
    #pragma unroll
    for (int kk = 0; kk < 16; ++kk) {
        cp[kk] += __shfl_xor(cp[kk], 8);
        cp[kk] += __shfl_xor(cp[kk], 16);
        cp[kk] += __shfl_xor(cp[kk], 32);
    }
    if ((lane & 56) == 0) {
        #pragma unroll
        for (int kk = 0; kk < 16; ++kk) colp[wid * 128 + cg * 16 + kk] = cp[kk];
    }
    __syncthreads();
    if (t < 128) {
        const float v = colp[t] + colp[128 + t] + colp[256 + t] + colp[384 + t];
        smean[(size_t)b * 128 + t] = v * (1.f / 1024.f);
    }
}

__global__ __launch_bounds__(64)
void final_kernel(const float* __restrict__ scores_g, const float* __restrict__ smean,
                  const float* __restrict__ Wc1, const float* __restrict__ bc1,
                  const float* __restrict__ Wc2, const float* __restrict__ bc2,
                  const float* __restrict__ Wc3, const float* __restrict__ bc3,
                  float* __restrict__ out)
{
    __shared__ float sc[128];
    __shared__ float c1[64];
    __shared__ float c2[32];
    const int b = blockIdx.x, t = threadIdx.x;
    const float s0 = scores_g[(size_t)b * 128 + t];
    const float s1 = scores_g[(size_t)b * 128 + 64 + t];
    sc[t] = s0; sc[64 + t] = s1;
    const float v0 = smean[(size_t)b * 128 + t];
    const float v1 = smean[(size_t)b * 128 + 64 + t];
    __syncthreads();
    float a = bc1[t];
    #pragma unroll 8
    for (int i = 0; i < 128; ++i) a += sc[i] * Wc1[i * 64 + t];
    c1[t] = fmaxf(a, 0.f);
    __syncthreads();
    if (t < 32) {
        float a2 = bc2[t];
        #pragma unroll 8
        for (int i = 0; i < 64; ++i) a2 += c1[i] * Wc2[i * 32 + t];
        c2[t] = fmaxf(a2, 0.f);
    }
    __syncthreads();
    float p = (t < 32) ? c2[t] * Wc3[t] : 0.f;
    #pragma unroll
    for (int m = 1; m < 64; m <<= 1) p += __shfl_xor(p, m);
    const float cons = 1.f / (1.f + __expf(-(p + bc3[0])));

    float sum = s0 + s1;
    float sq  = s0 * s0 + s1 * s1;
    float wsm = s0 * v0 + s1 * v1;
    float na  = (s0 > 0.1f ? 1.f : 0.f) + (s1 > 0.1f ? 1.f : 0.f);
    #pragma unroll
    for (int m = 1; m < 64; m <<= 1) {
        sum += __shfl_xor(sum, m); sq += __shfl_xor(sq, m);
        wsm += __shfl_xor(wsm, m); na += __shfl_xor(na, m);
    }
    if (t == 0) {
        const float mean = sum * (1.f / 128.f);
        float var = (sq - 128.f * mean * mean) * (1.f / 127.f);
        var = fmaxf(var, 0.f);
        const float agree = 1.f - sqrtf(var) / (mean + 1e-8f);
        out[b]        = cons * wsm;
        out[1024 + b] = (cons > 0.95f) ? 1.f : 0.f;
        out[2048 + b] = agree;
        out[3072 + b] = cons;
        out[4097 + b] = na;
    }
}

__global__ void attnmean_kernel(const float* __restrict__ smean, float* __restrict__ out)
{
    __shared__ float red[256];
    const int t = threadIdx.x;
    float s = 0.f;
    for (int i = t; i < 131072; i += 256) s += smean[i];
    red[t] = s;
    __syncthreads();
    for (int w = 128; w > 0; w >>= 1) {
        if (t < w) red[t] += red[t + w];
        __syncthreads();
    }
    if (t == 0) out[4096] = red[0] * (1.f / 131072.f);
}

extern "C" void kernel_launch(void* const* d_in, const int* in_sizes, int n_in,
                              void* d_out, int out_size, void* d_ws, size_t ws_size,
                              hipStream_t stream)
{
    const float* x    = (const float*)d_in[0];
    const float* fs   = (const float*)d_in[1];
    const float* dm   = (const float*)d_in[2];
    const float* W1   = (const float*)d_in[3];
    const float* b1   = (const float*)d_in[4];
    const float* g1   = (const float*)d_in[5];
    const float* be1  = (const float*)d_in[6];
    const float* W2   = (const float*)d_in[7];
    const float* b2   = (const float*)d_in[8];
    const float* g2   = (const float*)d_in[9];
    const float* be2  = (const float*)d_in[10];
    const float* W3   = (const float*)d_in[11];
    const float* b3   = (const float*)d_in[12];
    const float* Wr   = (const float*)d_in[13];
    const float* br   = (const float*)d_in[14];
    const float* Wa1  = (const float*)d_in[15];
    const float* ba1  = (const float*)d_in[16];
    const float* Wa2  = (const float*)d_in[17];
    const float* ba2  = (const float*)d_in[18];
    const float* Wa3  = (const float*)d_in[19];
    const float* ba3  = (const float*)d_in[20];
    const float* Wqkv = (const float*)d_in[21];
    const float* bqkv = (const float*)d_in[22];
    // d_in[23]=Wo, d_in[24]=bo unused downstream
    const float* Wc1  = (const float*)d_in[25];
    const float* bc1  = (const float*)d_in[26];
    const float* Wc2  = (const float*)d_in[27];
    const float* bc2  = (const float*)d_in[28];
    const float* Wc3  = (const float*)d_in[29];
    const float* bc3  = (const float*)d_in[30];

    float* out = (float*)d_out;
    char*  ws8 = (char*)d_ws;
    unsigned short* enc_bf = (unsigned short*)ws8;             // 8388608 bf16 (16 MB)
    float* scores = (float*)(ws8 + 16777216);                  // 131072 f32
    float* smean  = (float*)(ws8 + 17301504);                  // 131072 f32
    unsigned short* xb    = (unsigned short*)(ws8 + 17825792); // 262144 bf16
    unsigned short* W1t   = (unsigned short*)(ws8 + 18350080); // 8388608 bf16
    unsigned short* W2t   = (unsigned short*)(ws8 + 35127296); // 4194304 bf16
    unsigned short* W3t   = (unsigned short*)(ws8 + 43515904); // 1048576 bf16
    unsigned short* Wrt   = (unsigned short*)(ws8 + 45613056); // 524288 bf16
    unsigned short* wqkvb = (unsigned short*)(ws8 + 46661632); // 8192 bf16

    prep_kernel<<<3588, 256, 0, stream>>>(W1, W2, W3, Wr, x, Wqkv,
                                          W1t, W2t, W3t, Wrt, xb, wqkvb);
    fused_mfma<<<2048, 256, 0, stream>>>(xb, W1t, W2t, W3t, Wrt, fs, dm,
                                         b1, g1, be1, b2, g2, be2, b3, br,
                                         Wa1, ba1, Wa2, ba2, Wa3, ba3,
                                         enc_bf, scores);
    attn_kernel<<<1024, 256, 0, stream>>>(enc_bf, wqkvb, bqkv, smean);
    final_kernel<<<1024, 64, 0, stream>>>(scores, smean, Wc1, bc1, Wc2, bc2, Wc3, bc3, out);
    attnmean_kernel<<<1, 256, 0, stream>>>(smean, out);
}

// Round 4
// 224.766 us; speedup vs baseline: 4.7437x; 1.5351x over previous
//
#include <hip/hip_runtime.h>
#include <math.h>

// U=128, D=256, B=1024, E=64, H=8
// prep_kernel : f32 -> bf16 transposed weights ([n][k]) + x -> bf16 + Wqkv(QK rows) -> bf16
// fused_mfma  : per (u, 64-row batch tile): GEMM1(MFMA)+LN -> GEMM2(MFMA)+LN ->
//               GEMM3(MFMA) -> enc(bf16 out), dmi -> Wr(MFMA) -> z -> VALU tail -> scores
// attn_kernel : MFMA Q/K proj + register-tiled softmax column means -> smean[B][U], bpart[B]
// final_kernel: consensus MLP + stats
// attnmean    : sum of bpart[1024] -> out[4096]

typedef float f32x4 __attribute__((ext_vector_type(4)));
typedef int   i32x4 __attribute__((ext_vector_type(4)));

__device__ __forceinline__ void mfma_bf16(f32x4& c, i32x4 a, i32x4 b) {
    asm("v_mfma_f32_16x16x32_bf16 %0, %1, %2, %0" : "+v"(c) : "v"(a), "v"(b));
}

__device__ __forceinline__ void gl_lds16(const void* g, void* l) {
    __builtin_amdgcn_global_load_lds(
        (const __attribute__((address_space(1))) unsigned int*)g,
        (__attribute__((address_space(3))) unsigned int*)l, 16, 0, 0);
}

__device__ __forceinline__ unsigned short f2bf(float v) {
    union { __bf16 b; unsigned short u; } cv;
    cv.b = (__bf16)v;
    return cv.u;
}
__device__ __forceinline__ float bflo(unsigned int u) {
    union { unsigned int i; float f; } c; c.i = u << 16; return c.f;
}
__device__ __forceinline__ float bfhi(unsigned int u) {
    union { unsigned int i; float f; } c; c.i = u & 0xffff0000u; return c.f;
}

// ---------------- prep: convert + transpose weights to bf16 ----------------
__global__ __launch_bounds__(256)
void prep_kernel(const float* __restrict__ W1, const float* __restrict__ W2,
                 const float* __restrict__ W3, const float* __restrict__ Wr,
                 const float* __restrict__ x, const float* __restrict__ Wqkv,
                 unsigned short* __restrict__ W1t, unsigned short* __restrict__ W2t,
                 unsigned short* __restrict__ W3t, unsigned short* __restrict__ Wrt,
                 unsigned short* __restrict__ xb, unsigned short* __restrict__ wqkvb)
{
    const int bid = blockIdx.x, t = threadIdx.x;
    if (bid >= 3456) {  // plain convert, no transpose
        const float* src; unsigned short* dst; int base;
        if (bid >= 3584) { src = Wqkv; dst = wqkvb; base = (bid - 3584) * 2048 + t * 8; }
        else             { src = x;    dst = xb;    base = (bid - 3456) * 2048 + t * 8; }
        const float4 v0 = *(const float4*)(src + base);
        const float4 v1 = *(const float4*)(src + base + 4);
        __align__(16) unsigned short o[8];
        o[0]=f2bf(v0.x); o[1]=f2bf(v0.y); o[2]=f2bf(v0.z); o[3]=f2bf(v0.w);
        o[4]=f2bf(v1.x); o[5]=f2bf(v1.y); o[6]=f2bf(v1.z); o[7]=f2bf(v1.w);
        *(uint4*)(dst + base) = *(const uint4*)o;
        return;
    }
    const float* src; unsigned short* dst; int u, k0, n0, K, N;
    if (bid < 2048)      { u = bid >> 4;        int tl = bid & 15;       k0 = (tl>>2)*64; n0 = (tl&3)*64; K=256; N=256; src = W1 + (size_t)u*65536; dst = W1t + (size_t)u*65536; }
    else if (bid < 3072) { int b2 = bid - 2048; u = b2 >> 3; int tl = b2 & 7; k0 = (tl>>1)*64; n0 = (tl&1)*64; K=256; N=128; src = W2 + (size_t)u*32768; dst = W2t + (size_t)u*32768; }
    else if (bid < 3328) { int b3 = bid - 3072; u = b3 >> 1; int tl = b3 & 1; k0 = tl*64;      n0 = 0;         K=128; N=64;  src = W3 + (size_t)u*8192;  dst = W3t + (size_t)u*8192;  }
    else                 { u = bid - 3328;      k0 = 0; n0 = 0;                                 K=64;  N=64;  src = Wr + (size_t)u*4096;  dst = Wrt + (size_t)u*4096;  }

    __shared__ unsigned short tile[64 * 65];
    #pragma unroll
    for (int i = 0; i < 16; ++i) {
        const int e = i * 256 + t;
        const int kk = e >> 6, nn = e & 63;
        tile[kk * 65 + nn] = f2bf(src[(size_t)(k0 + kk) * N + n0 + nn]);
    }
    __syncthreads();
    #pragma unroll
    for (int i = 0; i < 16; ++i) {
        const int e = i * 256 + t;
        const int nn = e >> 6, kk = e & 63;
        dst[(size_t)(n0 + nn) * K + k0 + kk] = tile[kk * 65 + nn];
    }
}

// ---------------- fused universe chain (MFMA) ----------------
__global__ __launch_bounds__(256, 2)
void fused_mfma(const unsigned short* __restrict__ xb,
                const unsigned short* __restrict__ W1t, const unsigned short* __restrict__ W2t,
                const unsigned short* __restrict__ W3t, const unsigned short* __restrict__ Wrt,
                const float* __restrict__ fs, const float* __restrict__ dm,
                const float* __restrict__ b1, const float* __restrict__ g1, const float* __restrict__ be1,
                const float* __restrict__ b2, const float* __restrict__ g2, const float* __restrict__ be2,
                const float* __restrict__ b3, const float* __restrict__ br,
                const float* __restrict__ Wa1, const float* __restrict__ ba1,
                const float* __restrict__ Wa2, const float* __restrict__ ba2,
                const float* __restrict__ Wa3, const float* __restrict__ ba3,
                unsigned short* __restrict__ enc_bfg, float* __restrict__ scores_g)
{
    __shared__ __align__(128) char sm[69632];
    char* R0 = sm;             // 32 KB: A_x -> H1 -> H2/enc_bf/z
    char* R1 = sm + 32768;     // 32 KB: B panels -> Wa1/a1/Wa2/a2/Wa3
    char* R2 = sm + 65536;     // 4 KB : pS, pQ(+1024), rstats(+2048), dmi(+2560)
    float* pS = (float*)R2;
    float* pQ = (float*)(R2 + 1024);
    float2* rst = (float2*)(R2 + 2048);
    float* dmis = (float*)(R2 + 2560);

    const int t = threadIdx.x;
    const int wid = t >> 6, lane = t & 63, l15 = lane & 15, lk = lane >> 4;
    const int swz = (l15 & 7) << 4;
    const int bx = blockIdx.x;
    const int xcd = bx & 7, idx = bx >> 3;
    const int u = ((idx >> 4) << 3) + xcd;
    const int b0 = (idx & 15) * 64;

    const float corru = fs[u] * 137.036f;
    const float dmu = dm[u];

    const char* xbase = (const char*)xb + (size_t)b0 * 512;
    const char* w1u = (const char*)W1t + (size_t)u * 131072;
    const char* w2u = (const char*)W2t + (size_t)u * 65536;
    const char* w3u = (const char*)W3t + (size_t)u * 16384;
    const char* wru = (const char*)Wrt + (size_t)u * 8192;

    #pragma unroll
    for (int it = 0; it < 8; ++it) {
        const int d = it * 4096 + t * 16;
        const int s = d ^ (((d >> 9) & 7) << 4);
        gl_lds16(xbase + s, R0 + it * 4096 + wid * 1024);
    }
    #pragma unroll
    for (int it = 0; it < 8; ++it) {
        const int d = it * 4096 + t * 16;
        const int s = d ^ (((d >> 7) & 7) << 4);
        gl_lds16(w1u + (s >> 7) * 512 + (s & 127), R1 + it * 4096 + wid * 1024);
    }
    __syncthreads();

    // ===== GEMM1: [64][256] = A_x @ W1t, K=256 =====
    const f32x4 z4 = {0.f, 0.f, 0.f, 0.f};
    f32x4 acc[4][4];
    #pragma unroll
    for (int mi = 0; mi < 4; ++mi)
        #pragma unroll
        for (int ni = 0; ni < 4; ++ni) acc[mi][ni] = z4;

    for (int p = 0; p < 4; ++p) {
        #pragma unroll
        for (int ks = 0; ks < 2; ++ks) {
            i32x4 af[4], bf[4];
            #pragma unroll
            for (int mi = 0; mi < 4; ++mi) {
                const int off = ((mi * 16 + l15) << 9) + p * 128 + ks * 64 + lk * 16;
                af[mi] = *(const i32x4*)(R0 + (off ^ swz));
            }
            #pragma unroll
            for (int ni = 0; ni < 4; ++ni) {
                const int off = ((wid * 64 + ni * 16 + l15) << 7) + ks * 64 + lk * 16;
                bf[ni] = *(const i32x4*)(R1 + (off ^ swz));
            }
            #pragma unroll
            for (int mi = 0; mi < 4; ++mi)
                #pragma unroll
                for (int ni = 0; ni < 4; ++ni) mfma_bf16(acc[mi][ni], af[mi], bf[ni]);
        }
        if (p < 3) {
            __syncthreads();
            #pragma unroll
            for (int it = 0; it < 8; ++it) {
                const int d = it * 4096 + t * 16;
                const int s = d ^ (((d >> 7) & 7) << 4);
                gl_lds16(w1u + (s >> 7) * 512 + (p + 1) * 128 + (s & 127), R1 + it * 4096 + wid * 1024);
            }
            __syncthreads();
        }
    }

    // ===== LN1 + relu -> H1 bf16 =====
    float bb[4], gg[4], ee[4];
    #pragma unroll
    for (int ni = 0; ni < 4; ++ni) {
        const int c = wid * 64 + ni * 16 + l15;
        bb[ni] = b1[u * 256 + c]; gg[ni] = g1[u * 256 + c]; ee[ni] = be1[u * 256 + c];
    }
    #pragma unroll
    for (int mi = 0; mi < 4; ++mi) {
        #pragma unroll
        for (int j = 0; j < 4; ++j) {
            float s = 0.f, q = 0.f;
            #pragma unroll
            for (int ni = 0; ni < 4; ++ni) {
                const float h = acc[mi][ni][j] * corru + bb[ni];
                acc[mi][ni][j] = h;
                s += h; q += h * h;
            }
            #pragma unroll
            for (int m = 1; m < 16; m <<= 1) { s += __shfl_xor(s, m); q += __shfl_xor(q, m); }
            if (l15 == 0) {
                const int r = mi * 16 + lk * 4 + j;
                pS[wid * 64 + r] = s; pQ[wid * 64 + r] = q;
            }
        }
    }
    __syncthreads();
    if (t < 64) {
        const float s = pS[t] + pS[64 + t] + pS[128 + t] + pS[192 + t];
        const float q = pQ[t] + pQ[64 + t] + pQ[128 + t] + pQ[192 + t];
        const float mean = s * (1.f / 256.f);
        const float var = fmaxf(q * (1.f / 256.f) - mean * mean, 0.f);
        rst[t] = make_float2(mean, rsqrtf(var + 1e-5f));
    }
    #pragma unroll
    for (int it = 0; it < 4; ++it) {
        const int d = it * 4096 + t * 16;
        const int s = d ^ (((d >> 7) & 7) << 4);
        gl_lds16(w2u + (s >> 7) * 512 + (s & 127), R1 + it * 4096 + wid * 1024);
    }
    __syncthreads();
    #pragma unroll
    for (int mi = 0; mi < 4; ++mi) {
        #pragma unroll
        for (int j = 0; j < 4; ++j) {
            const int r = mi * 16 + lk * 4 + j;
            const float2 st = rst[r];
            #pragma unroll
            for (int ni = 0; ni < 4; ++ni) {
                const float h = fmaxf((acc[mi][ni][j] - st.x) * st.y * gg[ni] + ee[ni], 0.f);
                const int c = wid * 64 + ni * 16 + l15;
                const int off = (r << 9) + c * 2;
                *(__bf16*)(R0 + (off ^ ((r & 7) << 4))) = (__bf16)h;
            }
        }
    }
    __syncthreads();

    // ===== GEMM2: [64][128] = H1 @ W2t, K=256 =====
    f32x4 acc2[4][2];
    #pragma unroll
    for (int mi = 0; mi < 4; ++mi) { acc2[mi][0] = z4; acc2[mi][1] = z4; }
    for (int p = 0; p < 4; ++p) {
        if (p < 3) {
            #pragma unroll
            for (int it = 0; it < 4; ++it) {
                const int d = it * 4096 + t * 16;
                const int s = d ^ (((d >> 7) & 7) << 4);
                gl_lds16(w2u + (s >> 7) * 512 + (p + 1) * 128 + (s & 127),
                         R1 + ((p + 1) & 1) * 16384 + it * 4096 + wid * 1024);
            }
        }
        #pragma unroll
        for (int ks = 0; ks < 2; ++ks) {
            i32x4 af[4], bf2[2];
            #pragma unroll
            for (int mi = 0; mi < 4; ++mi) {
                const int off = ((mi * 16 + l15) << 9) + p * 128 + ks * 64 + lk * 16;
                af[mi] = *(const i32x4*)(R0 + (off ^ swz));
            }
            #pragma unroll
            for (int ni = 0; ni < 2; ++ni) {
                const int off = ((wid * 32 + ni * 16 + l15) << 7) + ks * 64 + lk * 16;
                bf2[ni] = *(const i32x4*)(R1 + (p & 1) * 16384 + (off ^ swz));
            }
            #pragma unroll
            for (int mi = 0; mi < 4; ++mi)
                #pragma unroll
                for (int ni = 0; ni < 2; ++ni) mfma_bf16(acc2[mi][ni], af[mi], bf2[ni]);
        }
        __syncthreads();
    }

    // ===== LN2 + relu -> H2 bf16 =====
    float bb2[2], gg2[2], ee2[2];
    #pragma unroll
    for (int ni = 0; ni < 2; ++ni) {
        const int c = wid * 32 + ni * 16 + l15;
        bb2[ni] = b2[u * 128 + c]; gg2[ni] = g2[u * 128 + c]; ee2[ni] = be2[u * 128 + c];
    }
    #pragma unroll
    for (int mi = 0; mi < 4; ++mi) {
        #pragma unroll
        for (int j = 0; j < 4; ++j) {
            float s = 0.f, q = 0.f;
            #pragma unroll
            for (int ni = 0; ni < 2; ++ni) {
                const float h = acc2[mi][ni][j] + bb2[ni];
                acc2[mi][ni][j] = h;
                s += h; q += h * h;
            }
            #pragma unroll
            for (int m = 1; m < 16; m <<= 1) { s += __shfl_xor(s, m); q += __shfl_xor(q, m); }
            if (l15 == 0) {
                const int r = mi * 16 + lk * 4 + j;
                pS[wid * 64 + r] = s; pQ[wid * 64 + r] = q;
            }
        }
    }
    __syncthreads();
    if (t < 64) {
        const float s = pS[t] + pS[64 + t] + pS[128 + t] + pS[192 + t];
        const float q = pQ[t] + pQ[64 + t] + pQ[128 + t] + pQ[192 + t];
        const float mean = s * (1.f / 128.f);
        const float var = fmaxf(q * (1.f / 128.f) - mean * mean, 0.f);
        rst[t] = make_float2(mean, rsqrtf(var + 1e-5f));
    }
    #pragma unroll
    for (int it = 0; it < 4; ++it) {
        const int d = it * 4096 + t * 16;
        const int s = d ^ (((d >> 8) & 7) << 4);
        gl_lds16(w3u + (s >> 8) * 256 + (s & 255), R1 + it * 4096 + wid * 1024);
    }
    __syncthreads();
    #pragma unroll
    for (int mi = 0; mi < 4; ++mi) {
        #pragma unroll
        for (int j = 0; j < 4; ++j) {
            const int r = mi * 16 + lk * 4 + j;
            const float2 st = rst[r];
            #pragma unroll
            for (int ni = 0; ni < 2; ++ni) {
                const float h = fmaxf((acc2[mi][ni][j] - st.x) * st.y * gg2[ni] + ee2[ni], 0.f);
                const int c = wid * 32 + ni * 16 + l15;
                const int off = (r << 8) + c * 2;
                *(__bf16*)(R0 + (off ^ ((r & 7) << 4))) = (__bf16)h;
            }
        }
    }
    __syncthreads();

    // ===== GEMM3: enc [64][64] = H2 @ W3t, K=128 =====
    f32x4 acc3[4];
    #pragma unroll
    for (int mi = 0; mi < 4; ++mi) acc3[mi] = z4;
    #pragma unroll
    for (int ks = 0; ks < 4; ++ks) {
        i32x4 af[4], bfr;
        #pragma unroll
        for (int mi = 0; mi < 4; ++mi) {
            const int off = ((mi * 16 + l15) << 8) + ks * 64 + lk * 16;
            af[mi] = *(const i32x4*)(R0 + (off ^ swz));
        }
        {
            const int off = ((wid * 16 + l15) << 8) + ks * 64 + lk * 16;
            bfr = *(const i32x4*)(R1 + (off ^ swz));
        }
        #pragma unroll
        for (int mi = 0; mi < 4; ++mi) mfma_bf16(acc3[mi], af[mi], bfr);
    }
    // epilogue: +b3, global enc write (bf16), sumsq partials
    const int c16 = wid * 16 + l15;
    const float b3v = b3[u * 64 + c16];
    float encr[4][4];
    #pragma unroll
    for (int mi = 0; mi < 4; ++mi) {
        #pragma unroll
        for (int j = 0; j < 4; ++j) {
            const float e = acc3[mi][j] + b3v;
            encr[mi][j] = e;
            const int r = mi * 16 + lk * 4 + j;
            enc_bfg[((size_t)(b0 + r) * 128 + u) * 64 + c16] = f2bf(e);
            float q = e * e;
            #pragma unroll
            for (int m = 1; m < 16; m <<= 1) q += __shfl_xor(q, m);
            if (l15 == 0) pQ[wid * 64 + r] = q;
        }
    }
    __syncthreads();
    if (t < 64) {
        const float q = pQ[t] + pQ[64 + t] + pQ[128 + t] + pQ[192 + t];
        dmis[t] = tanhf(dmu * q);
    }
    #pragma unroll
    for (int it = 0; it < 2; ++it) {
        const int d = it * 4096 + t * 16;
        const int s = d ^ (((d >> 7) & 7) << 4);
        gl_lds16(wru + (s >> 7) * 128 + (s & 127), R1 + it * 4096 + wid * 1024);
    }
    #pragma unroll
    for (int mi = 0; mi < 4; ++mi) {
        #pragma unroll
        for (int j = 0; j < 4; ++j) {
            const int r = mi * 16 + lk * 4 + j;
            const int off = (r << 7) + c16 * 2;
            *(__bf16*)(R0 + (off ^ ((r & 7) << 4))) = (__bf16)encr[mi][j];
        }
    }
    __syncthreads();

    // ===== Wr: re [64][64] = enc_bf @ Wrt, K=64 =====
    f32x4 accR[4];
    #pragma unroll
    for (int mi = 0; mi < 4; ++mi) accR[mi] = z4;
    #pragma unroll
    for (int ks = 0; ks < 2; ++ks) {
        i32x4 af[4], bfr;
        #pragma unroll
        for (int mi = 0; mi < 4; ++mi) {
            const int off = ((mi * 16 + l15) << 7) + ks * 64 + lk * 16;
            af[mi] = *(const i32x4*)(R0 + (off ^ swz));
        }
        {
            const int off = ((wid * 16 + l15) << 7) + ks * 64 + lk * 16;
            bfr = *(const i32x4*)(R1 + (off ^ swz));
        }
        #pragma unroll
        for (int mi = 0; mi < 4; ++mi) mfma_bf16(accR[mi], af[mi], bfr);
    }
    const float brv = br[u * 64 + c16];
    #pragma unroll
    for (int mi = 0; mi < 4; ++mi) {
        #pragma unroll
        for (int j = 0; j < 4; ++j) {
            const int r = mi * 16 + lk * 4 + j;
            const float zv = accR[mi][j] + brv + dmis[r] * encr[mi][j];
            *(float*)(R0 + 8192 + r * 272 + c16 * 4) = zv;
        }
    }
    __syncthreads();

    #pragma unroll
    for (int it = 0; it < 2; ++it)
        gl_lds16((const char*)Wa1 + (size_t)u * 8192 + it * 4096 + t * 16,
                 R1 + it * 4096 + wid * 1024);
    if (t < 128)
        gl_lds16((const char*)Wa2 + (size_t)u * 2048 + t * 16, R1 + 17408 + wid * 1024);
    if (t < 16) ((float*)(R1 + 24064))[t] = Wa3[u * 16 + t];
    if (t == 16) ((float*)(R1 + 24064))[16] = ba3[u];
    __syncthreads();

    // ===== tail =====
    {
        const int row = t >> 2, g4 = t & 3;
        float accA[8] = {0.f,0.f,0.f,0.f,0.f,0.f,0.f,0.f};
        const float* zrow = (const float*)(R0 + 8192 + row * 272);
        const float* wa1s = (const float*)R1;
        for (int k = 0; k < 64; ++k) {
            const float zv = zrow[k];
            const float4 wA = *(const float4*)(wa1s + k * 32 + g4 * 8);
            const float4 wB = *(const float4*)(wa1s + k * 32 + g4 * 8 + 4);
            accA[0] += zv * wA.x; accA[1] += zv * wA.y; accA[2] += zv * wA.z; accA[3] += zv * wA.w;
            accA[4] += zv * wB.x; accA[5] += zv * wB.y; accA[6] += zv * wB.z; accA[7] += zv * wB.w;
        }
        const float4 bA = *(const float4*)(ba1 + u * 32 + g4 * 8);
        const float4 bB = *(const float4*)(ba1 + u * 32 + g4 * 8 + 4);
        float* a1s = (float*)(R1 + 8192);
        a1s[row * 34 + g4 * 8 + 0] = fmaxf(accA[0] + bA.x, 0.f);
        a1s[row * 34 + g4 * 8 + 1] = fmaxf(accA[1] + bA.y, 0.f);
        a1s[row * 34 + g4 * 8 + 2] = fmaxf(accA[2] + bA.z, 0.f);
        a1s[row * 34 + g4 * 8 + 3] = fmaxf(accA[3] + bA.w, 0.f);
        a1s[row * 34 + g4 * 8 + 4] = fmaxf(accA[4] + bB.x, 0.f);
        a1s[row * 34 + g4 * 8 + 5] = fmaxf(accA[5] + bB.y, 0.f);
        a1s[row * 34 + g4 * 8 + 6] = fmaxf(accA[6] + bB.z, 0.f);
        a1s[row * 34 + g4 * 8 + 7] = fmaxf(accA[7] + bB.w, 0.f);
    }
    __syncthreads();

    {
        const int row = t >> 2, g4 = t & 3;
        const float* a1s = (const float*)(R1 + 8192);
        const float* wa2s = (const float*)(R1 + 17408);
        float accB[4] = {0.f,0.f,0.f,0.f};
        for (int k = 0; k < 32; ++k) {
            const float av = a1s[row * 34 + k];
            const float4 w = *(const float4*)(wa2s + k * 16 + g4 * 4);
            accB[0] += av * w.x; accB[1] += av * w.y; accB[2] += av * w.z; accB[3] += av * w.w;
        }
        const float4 bB = *(const float4*)(ba2 + u * 16 + g4 * 4);
        float* a2s = (float*)(R1 + 19456);
        a2s[row * 18 + g4 * 4 + 0] = fmaxf(accB[0] + bB.x, 0.f);
        a2s[row * 18 + g4 * 4 + 1] = fmaxf(accB[1] + bB.y, 0.f);
        a2s[row * 18 + g4 * 4 + 2] = fmaxf(accB[2] + bB.z, 0.f);
        a2s[row * 18 + g4 * 4 + 3] = fmaxf(accB[3] + bB.w, 0.f);
    }
    __syncthreads();

    if (t < 64) {
        const float* a2s = (const float*)(R1 + 19456);
        const float* w3s = (const float*)(R1 + 24064);
        float a = w3s[16];
        #pragma unroll
        for (int k = 0; k < 16; ++k) a += a2s[t * 18 + k] * w3s[k];
        scores_g[(size_t)(b0 + t) * 128 + u] = 1.f / (1.f + __expf(-a));
    }
}

// ---------------- attention column-means (MFMA proj + register softmax) ----------------
__global__ __launch_bounds__(256, 2)
void attn_kernel(const unsigned short* __restrict__ enc_bf,
                 const unsigned short* __restrict__ wqkv_bf,
                 const float* __restrict__ bqkv, float* __restrict__ smean,
                 float* __restrict__ bpart)
{
    __shared__ __align__(128) char sm[65536];
    char* ENCs = sm;            // 16KB [128][64] bf16 swz
    char* Qs   = sm + 16384;    // 16KB [128][64] bf16 swz(addr>>10)
    char* Ks   = sm + 32768;    // 16KB
    char* WQs  = sm + 49152;    // 16KB Wqkv rows 0..127
    float* colp = (float*)sm;   // alias (ENC dead after proj)

    const int t = threadIdx.x;
    const int wid = t >> 6, lane = t & 63, l15 = lane & 15, lk = lane >> 4;
    const int swz = (l15 & 7) << 4;
    const int b = blockIdx.x;

    const char* eb = (const char*)(enc_bf + (size_t)b * 8192);
    #pragma unroll
    for (int it = 0; it < 4; ++it) {
        const int d = it * 4096 + t * 16;
        const int s = d ^ (((d >> 7) & 7) << 4);
        gl_lds16(eb + s, ENCs + it * 4096 + wid * 1024);
    }
    const char* wb = (const char*)wqkv_bf;
    #pragma unroll
    for (int it = 0; it < 4; ++it) {
        const int d = it * 4096 + t * 16;
        const int s = d ^ (((d >> 7) & 7) << 4);
        gl_lds16(wb + s, WQs + it * 4096 + wid * 1024);
    }
    __syncthreads();

    // ===== proj: Q,K [128][64] = enc @ Wqkv[0:64 / 64:128]^T =====
    const f32x4 z4 = {0.f,0.f,0.f,0.f};
    f32x4 aq[2][4], ak[2][4];
    #pragma unroll
    for (int mi = 0; mi < 2; ++mi)
        #pragma unroll
        for (int ni = 0; ni < 4; ++ni) { aq[mi][ni] = z4; ak[mi][ni] = z4; }

    i32x4 af[2][2];
    #pragma unroll
    for (int mi = 0; mi < 2; ++mi)
        #pragma unroll
        for (int ks = 0; ks < 2; ++ks) {
            const int off = ((wid * 32 + mi * 16 + l15) << 7) + ks * 64 + lk * 16;
            af[mi][ks] = *(const i32x4*)(ENCs + (off ^ swz));
        }
    #pragma unroll
    for (int ni = 0; ni < 4; ++ni)
        #pragma unroll
        for (int ks = 0; ks < 2; ++ks) {
            const int offq = ((ni * 16 + l15) << 7) + ks * 64 + lk * 16;
            const i32x4 bq = *(const i32x4*)(WQs + (offq ^ swz));
            mfma_bf16(aq[0][ni], af[0][ks], bq);
            mfma_bf16(aq[1][ni], af[1][ks], bq);
            const i32x4 bk = *(const i32x4*)(WQs + ((offq + 8192) ^ swz));
            mfma_bf16(ak[0][ni], af[0][ks], bk);
            mfma_bf16(ak[1][ni], af[1][ks], bk);
        }

    const float invsq = 0.35355339059327373f;
    float bqv[4], bkv[4];
    #pragma unroll
    for (int ni = 0; ni < 4; ++ni) {
        bqv[ni] = bqkv[ni * 16 + l15];
        bkv[ni] = bqkv[64 + ni * 16 + l15];
    }
    #pragma unroll
    for (int mi = 0; mi < 2; ++mi)
        #pragma unroll
        for (int ni = 0; ni < 4; ++ni)
            #pragma unroll
            for (int j = 0; j < 4; ++j) {
                const int row = wid * 32 + mi * 16 + lk * 4 + j;
                const int f = ni * 16 + l15;
                const int addr = row * 128 + f * 2;
                const int phys = addr ^ (((addr >> 10) & 7) << 4);
                *(__bf16*)(Qs + phys) = (__bf16)((aq[mi][ni][j] + bqv[ni]) * invsq);
                *(__bf16*)(Ks + phys) = (__bf16)(ak[mi][ni][j] + bkv[ni]);
            }
    __syncthreads();

    // ===== S = QK^T per head, register-tiled softmax + column sums =====
    const int cg = t & 7, qg = t >> 3;   // col group (16 cols), row group (4 rows)
    float cp[16];
    #pragma unroll
    for (int kk = 0; kk < 16; ++kk) cp[kk] = 0.f;

    for (int h = 0; h < 8; ++h) {
        float qv[4][8];
        #pragma unroll
        for (int j = 0; j < 4; ++j) {
            const int addr = (qg * 4 + j) * 128 + h * 16;
            const uint4 w = *(const uint4*)(Qs + (addr ^ (((addr >> 10) & 7) << 4)));
            qv[j][0]=bflo(w.x); qv[j][1]=bfhi(w.x); qv[j][2]=bflo(w.y); qv[j][3]=bfhi(w.y);
            qv[j][4]=bflo(w.z); qv[j][5]=bfhi(w.z); qv[j][6]=bflo(w.w); qv[j][7]=bfhi(w.w);
        }
        float s[4][16];
        #pragma unroll
        for (int j = 0; j < 4; ++j)
            #pragma unroll
            for (int kk = 0; kk < 16; ++kk) s[j][kk] = 0.f;
        #pragma unroll
        for (int kk = 0; kk < 16; ++kk) {
            const int addr = (cg * 16 + kk) * 128 + h * 16;
            const uint4 w = *(const uint4*)(Ks + (addr ^ (((addr >> 10) & 7) << 4)));
            float kv[8];
            kv[0]=bflo(w.x); kv[1]=bfhi(w.x); kv[2]=bflo(w.y); kv[3]=bfhi(w.y);
            kv[4]=bflo(w.z); kv[5]=bfhi(w.z); kv[6]=bflo(w.w); kv[7]=bfhi(w.w);
            #pragma unroll
            for (int j = 0; j < 4; ++j)
                #pragma unroll
                for (int d = 0; d < 8; ++d)
                    s[j][kk] += qv[j][d] * kv[d];
        }
        #pragma unroll
        for (int j = 0; j < 4; ++j) {
            float mx = s[j][0];
            #pragma unroll
            for (int kk = 1; kk < 16; ++kk) mx = fmaxf(mx, s[j][kk]);
            mx = fmaxf(mx, __shfl_xor(mx, 1));
            mx = fmaxf(mx, __shfl_xor(mx, 2));
            mx = fmaxf(mx, __shfl_xor(mx, 4));
            float z = 0.f;
            #pragma unroll
            for (int kk = 0; kk < 16; ++kk) { s[j][kk] = __expf(s[j][kk] - mx); z += s[j][kk]; }
            z += __shfl_xor(z, 1); z += __shfl_xor(z, 2); z += __shfl_xor(z, 4);
            const float zi = 1.f / z;
            #pragma unroll
            for (int kk = 0; kk < 16; ++kk) cp[kk] += s[j][kk] * zi;
        }
    }
    #pragma unroll
    for (int kk = 0; kk < 16; ++kk) {
        cp[kk] += __shfl_xor(cp[kk], 8);
        cp[kk] += __shfl_xor(cp[kk], 16);
        cp[kk] += __shfl_xor(cp[kk], 32);
    }
    if ((lane & 56) == 0) {
        #pragma unroll
        for (int kk = 0; kk < 16; ++kk) colp[wid * 128 + cg * 16 + kk] = cp[kk];
    }
    __syncthreads();
    float v = 0.f;
    if (t < 128) {
        v = colp[t] + colp[128 + t] + colp[256 + t] + colp[384 + t];
        smean[(size_t)b * 128 + t] = v * (1.f / 1024.f);
    }
    // block partial for the global attn mean: bpart[b] = sum_u smean[b][u]
    #pragma unroll
    for (int m = 1; m < 64; m <<= 1) v += __shfl_xor(v, m);
    if (lane == 0) colp[512 + wid] = v;
    __syncthreads();
    if (t == 0)
        bpart[b] = (colp[512] + colp[513] + colp[514] + colp[515]) * (1.f / 1024.f);
}

__global__ __launch_bounds__(64)
void final_kernel(const float* __restrict__ scores_g, const float* __restrict__ smean,
                  const float* __restrict__ Wc1, const float* __restrict__ bc1,
                  const float* __restrict__ Wc2, const float* __restrict__ bc2,
                  const float* __restrict__ Wc3, const float* __restrict__ bc3,
                  float* __restrict__ out)
{
    __shared__ float sc[128];
    __shared__ float c1[64];
    __shared__ float c2[32];
    const int b = blockIdx.x, t = threadIdx.x;
    const float s0 = scores_g[(size_t)b * 128 + t];
    const float s1 = scores_g[(size_t)b * 128 + 64 + t];
    sc[t] = s0; sc[64 + t] = s1;
    const float v0 = smean[(size_t)b * 128 + t];
    const float v1 = smean[(size_t)b * 128 + 64 + t];
    __syncthreads();
    float a = bc1[t];
    #pragma unroll 8
    for (int i = 0; i < 128; ++i) a += sc[i] * Wc1[i * 64 + t];
    c1[t] = fmaxf(a, 0.f);
    __syncthreads();
    if (t < 32) {
        float a2 = bc2[t];
        #pragma unroll 8
        for (int i = 0; i < 64; ++i) a2 += c1[i] * Wc2[i * 32 + t];
        c2[t] = fmaxf(a2, 0.f);
    }
    __syncthreads();
    float p = (t < 32) ? c2[t] * Wc3[t] : 0.f;
    #pragma unroll
    for (int m = 1; m < 64; m <<= 1) p += __shfl_xor(p, m);
    const float cons = 1.f / (1.f + __expf(-(p + bc3[0])));

    float sum = s0 + s1;
    float sq  = s0 * s0 + s1 * s1;
    float wsm = s0 * v0 + s1 * v1;
    float na  = (s0 > 0.1f ? 1.f : 0.f) + (s1 > 0.1f ? 1.f : 0.f);
    #pragma unroll
    for (int m = 1; m < 64; m <<= 1) {
        sum += __shfl_xor(sum, m); sq += __shfl_xor(sq, m);
        wsm += __shfl_xor(wsm, m); na += __shfl_xor(na, m);
    }
    if (t == 0) {
        const float mean = sum * (1.f / 128.f);
        float var = (sq - 128.f * mean * mean) * (1.f / 127.f);
        var = fmaxf(var, 0.f);
        const float agree = 1.f - sqrtf(var) / (mean + 1e-8f);
        out[b]        = cons * wsm;
        out[1024 + b] = (cons > 0.95f) ? 1.f : 0.f;
        out[2048 + b] = agree;
        out[3072 + b] = cons;
        out[4097 + b] = na;
    }
}

__global__ __launch_bounds__(256)
void attnmean_kernel(const float* __restrict__ bpart, float* __restrict__ out)
{
    __shared__ float red[4];
    const int t = threadIdx.x;
    const int lane = t & 63, wid = t >> 6;
    float s = bpart[t] + bpart[256 + t] + bpart[512 + t] + bpart[768 + t];
    #pragma unroll
    for (int m = 1; m < 64; m <<= 1) s += __shfl_xor(s, m);
    if (lane == 0) red[wid] = s;
    __syncthreads();
    if (t == 0) out[4096] = (red[0] + red[1] + red[2] + red[3]) * (1.f / 131072.f);
}

extern "C" void kernel_launch(void* const* d_in, const int* in_sizes, int n_in,
                              void* d_out, int out_size, void* d_ws, size_t ws_size,
                              hipStream_t stream)
{
    const float* x    = (const float*)d_in[0];
    const float* fs   = (const float*)d_in[1];
    const float* dm   = (const float*)d_in[2];
    const float* W1   = (const float*)d_in[3];
    const float* b1   = (const float*)d_in[4];
    const float* g1   = (const float*)d_in[5];
    const float* be1  = (const float*)d_in[6];
    const float* W2   = (const float*)d_in[7];
    const float* b2   = (const float*)d_in[8];
    const float* g2   = (const float*)d_in[9];
    const float* be2  = (const float*)d_in[10];
    const float* W3   = (const float*)d_in[11];
    const float* b3   = (const float*)d_in[12];
    const float* Wr   = (const float*)d_in[13];
    const float* br   = (const float*)d_in[14];
    const float* Wa1  = (const float*)d_in[15];
    const float* ba1  = (const float*)d_in[16];
    const float* Wa2  = (const float*)d_in[17];
    const float* ba2  = (const float*)d_in[18];
    const float* Wa3  = (const float*)d_in[19];
    const float* ba3  = (const float*)d_in[20];
    const float* Wqkv = (const float*)d_in[21];
    const float* bqkv = (const float*)d_in[22];
    // d_in[23]=Wo, d_in[24]=bo unused downstream
    const float* Wc1  = (const float*)d_in[25];
    const float* bc1  = (const float*)d_in[26];
    const float* Wc2  = (const float*)d_in[27];
    const float* bc2  = (const float*)d_in[28];
    const float* Wc3  = (const float*)d_in[29];
    const float* bc3  = (const float*)d_in[30];

    float* out = (float*)d_out;
    char*  ws8 = (char*)d_ws;
    unsigned short* enc_bf = (unsigned short*)ws8;             // 8388608 bf16 (16 MB)
    float* scores = (float*)(ws8 + 16777216);                  // 131072 f32
    float* smean  = (float*)(ws8 + 17301504);                  // 131072 f32
    float* bpart  = (float*)(ws8 + 17825792);                  // 1024 f32
    unsigned short* xb    = (unsigned short*)(ws8 + 17829888); // 262144 bf16
    unsigned short* W1t   = (unsigned short*)(ws8 + 18354176); // 8388608 bf16
    unsigned short* W2t   = (unsigned short*)(ws8 + 35131392); // 4194304 bf16
    unsigned short* W3t   = (unsigned short*)(ws8 + 43520000); // 1048576 bf16
    unsigned short* Wrt   = (unsigned short*)(ws8 + 45617152); // 524288 bf16
    unsigned short* wqkvb = (unsigned short*)(ws8 + 46665728); // 8192 bf16

    prep_kernel<<<3588, 256, 0, stream>>>(W1, W2, W3, Wr, x, Wqkv,
                                          W1t, W2t, W3t, Wrt, xb, wqkvb);
    fused_mfma<<<2048, 256, 0, stream>>>(xb, W1t, W2t, W3t, Wrt, fs, dm,
                                         b1, g1, be1, b2, g2, be2, b3, br,
                                         Wa1, ba1, Wa2, ba2, Wa3, ba3,
                                         enc_bf, scores);
    attn_kernel<<<1024, 256, 0, stream>>>(enc_bf, wqkvb, bqkv, smean, bpart);
    final_kernel<<<1024, 64, 0, stream>>>(scores, smean, Wc1, bc1, Wc2, bc2, Wc3, bc3, out);
    attnmean_kernel<<<1, 256, 0, stream>>>(bpart, out);
}

// Round 6
// 204.297 us; speedup vs baseline: 5.2190x; 1.1002x over previous
//
#include <hip/hip_runtime.h>
#include <math.h>

// U=128, D=256, B=1024, E=64, H=8
// prep_kernel : f32 -> bf16 frag-tiled weights [n/16][k/32][16][32] + x/wqkv -> bf16
// fused_mfma  : per (u, 64-row batch tile): big GEMMs via MFMA with DIRECT global
//               B-fragment loads (no LDS weight staging); fp32 tail (z/a1/a2) for
//               exact scores. LDS 39.7KB -> 4 blocks/CU.
// attn_kernel : MFMA Q/K proj + register-tiled softmax column means
// final/attnmean: outputs

typedef float f32x4 __attribute__((ext_vector_type(4)));
typedef int   i32x4 __attribute__((ext_vector_type(4)));

__device__ __forceinline__ void mfma_bf16(f32x4& c, i32x4 a, i32x4 b) {
    asm("v_mfma_f32_16x16x32_bf16 %0, %1, %2, %0" : "+v"(c) : "v"(a), "v"(b));
}

__device__ __forceinline__ void gl_lds16(const void* g, void* l) {
    __builtin_amdgcn_global_load_lds(
        (const __attribute__((address_space(1))) unsigned int*)g,
        (__attribute__((address_space(3))) unsigned int*)l, 16, 0, 0);
}

__device__ __forceinline__ unsigned short f2bf(float v) {
    union { __bf16 b; unsigned short u; } cv;
    cv.b = (__bf16)v;
    return cv.u;
}
__device__ __forceinline__ float bflo(unsigned int u) {
    union { unsigned int i; float f; } c; c.i = u << 16; return c.f;
}
__device__ __forceinline__ float bfhi(unsigned int u) {
    union { unsigned int i; float f; } c; c.i = u & 0xffff0000u; return c.f;
}

// ---------------- prep: convert + frag-tile weights to bf16 ----------------
// tiled layout: elem (n,k) -> ((n>>4)*(K/32) + (k>>5))*512 + (n&15)*32 + (k&31)
__global__ __launch_bounds__(256)
void prep_kernel(const float* __restrict__ W1, const float* __restrict__ W2,
                 const float* __restrict__ W3, const float* __restrict__ Wr,
                 const float* __restrict__ x, const float* __restrict__ Wqkv,
                 unsigned short* __restrict__ W1t, unsigned short* __restrict__ W2t,
                 unsigned short* __restrict__ W3t, unsigned short* __restrict__ Wrt,
                 unsigned short* __restrict__ xb, unsigned short* __restrict__ wqkvb)
{
    const int bid = blockIdx.x, t = threadIdx.x;
    if (bid >= 3456) {  // plain convert, no transpose
        const float* src; unsigned short* dst; int base;
        if (bid >= 3584) { src = Wqkv; dst = wqkvb; base = (bid - 3584) * 2048 + t * 8; }
        else             { src = x;    dst = xb;    base = (bid - 3456) * 2048 + t * 8; }
        const float4 v0 = *(const float4*)(src + base);
        const float4 v1 = *(const float4*)(src + base + 4);
        __align__(16) unsigned short o[8];
        o[0]=f2bf(v0.x); o[1]=f2bf(v0.y); o[2]=f2bf(v0.z); o[3]=f2bf(v0.w);
        o[4]=f2bf(v1.x); o[5]=f2bf(v1.y); o[6]=f2bf(v1.z); o[7]=f2bf(v1.w);
        *(uint4*)(dst + base) = *(const uint4*)o;
        return;
    }
    const float* src; unsigned short* dst; int u, k0, n0, N, ktiles;
    if (bid < 2048)      { u = bid >> 4;        int tl = bid & 15;       k0 = (tl>>2)*64; n0 = (tl&3)*64; N=256; ktiles=8; src = W1 + (size_t)u*65536; dst = W1t + (size_t)u*65536; }
    else if (bid < 3072) { int b2 = bid - 2048; u = b2 >> 3; int tl = b2 & 7; k0 = (tl>>1)*64; n0 = (tl&1)*64; N=128; ktiles=8; src = W2 + (size_t)u*32768; dst = W2t + (size_t)u*32768; }
    else if (bid < 3328) { int b3 = bid - 3072; u = b3 >> 1; int tl = b3 & 1; k0 = tl*64;      n0 = 0;         N=64;  ktiles=4; src = W3 + (size_t)u*8192;  dst = W3t + (size_t)u*8192;  }
    else                 { u = bid - 3328;      k0 = 0; n0 = 0;                                 N=64;  ktiles=2; src = Wr + (size_t)u*4096;  dst = Wrt + (size_t)u*4096;  }

    __shared__ unsigned short tile[64 * 65];
    #pragma unroll
    for (int i = 0; i < 16; ++i) {
        const int e = i * 256 + t;
        const int kk = e >> 6, nn = e & 63;
        tile[kk * 65 + nn] = f2bf(src[(size_t)(k0 + kk) * N + n0 + nn]);
    }
    __syncthreads();
    #pragma unroll
    for (int i = 0; i < 16; ++i) {
        const int e = i * 256 + t;
        const int nn = e >> 6, kk = e & 63;
        const int n = n0 + nn, k = k0 + kk;
        dst[(size_t)(((n >> 4) * ktiles + (k >> 5)) * 512 + (n & 15) * 32 + (k & 31))] = tile[kk * 65 + nn];
    }
}

// ---------------- fused universe chain: direct-global B fragments, fp32 tail ----------------
__global__ __launch_bounds__(256, 4)
void fused_mfma(const unsigned short* __restrict__ xb,
                const unsigned short* __restrict__ W1t, const unsigned short* __restrict__ W2t,
                const unsigned short* __restrict__ W3t, const unsigned short* __restrict__ Wrt,
                const float* __restrict__ fs, const float* __restrict__ dm,
                const float* __restrict__ b1, const float* __restrict__ g1, const float* __restrict__ be1,
                const float* __restrict__ b2, const float* __restrict__ g2, const float* __restrict__ be2,
                const float* __restrict__ b3, const float* __restrict__ br,
                const float* __restrict__ Wa1, const float* __restrict__ ba1,
                const float* __restrict__ Wa2, const float* __restrict__ ba2,
                const float* __restrict__ Wa3, const float* __restrict__ ba3,
                unsigned short* __restrict__ enc_bfg, float* __restrict__ scores_g)
{
    // LDS map (39680 B total):
    //  [0,32768)  A_x/H1 bf16 [64][512B]; then H2 bf16 [64][256B] at [0,16K);
    //             then enc bf16 [64][128B] at [0,8K); z f32 [64][68f] at [8192,25600);
    //             Wa1 f32 at [0,8192) (after z); Wa2 f32 [25600,27648);
    //             Wa3/ba3 [27648,27776); a2 f32 [64][18f] at [0,4608)
    //  [28160,36864) a1 f32 [64][34f]
    //  [36864,39680) stats: pS, pQ, rst, dmis
    __shared__ __align__(128) char sm[39680];
    char* R0 = sm;
    float* pS = (float*)(sm + 36864);
    float* pQ = (float*)(sm + 37888);
    float2* rst = (float2*)(sm + 38912);
    float* dmis = (float*)(sm + 39424);

    const int t = threadIdx.x;
    const int wid = t >> 6, lane = t & 63, l15 = lane & 15, lk = lane >> 4;
    const int swz = (l15 & 7) << 4;
    const int lo64 = l15 * 64 + lk * 16;    // lane offset within a 1KB weight fragment tile
    const int bx = blockIdx.x;
    const int xcd = bx & 7, idx = bx >> 3;
    const int u = ((idx >> 4) << 3) + xcd;
    const int b0 = (idx & 15) * 64;

    const float corru = fs[u] * 137.036f;
    const float dmu = dm[u];

    const char* xbase = (const char*)xb + (size_t)b0 * 512;
    const char* w1u = (const char*)W1t + (size_t)u * 131072;
    const char* w2u = (const char*)W2t + (size_t)u * 65536;
    const char* w3u = (const char*)W3t + (size_t)u * 16384;
    const char* wru = (const char*)Wrt + (size_t)u * 8192;

    // stage A_x [64][512B] swz9
    #pragma unroll
    for (int it = 0; it < 8; ++it) {
        const int d = it * 4096 + t * 16;
        const int s = d ^ (((d >> 9) & 7) << 4);
        gl_lds16(xbase + s, R0 + it * 4096 + wid * 1024);
    }
    __syncthreads();  // B0

    // ===== GEMM1: [64][256] = A_x @ W1t, K=256, B direct from global =====
    const f32x4 z4 = {0.f, 0.f, 0.f, 0.f};
    f32x4 acc[4][4];
    #pragma unroll
    for (int mi = 0; mi < 4; ++mi)
        #pragma unroll
        for (int ni = 0; ni < 4; ++ni) acc[mi][ni] = z4;

    for (int p = 0; p < 4; ++p) {
        #pragma unroll
        for (int ks = 0; ks < 2; ++ks) {
            i32x4 af[4], bf[4];
            const int kt = p * 2 + ks;
            #pragma unroll
            for (int ni = 0; ni < 4; ++ni)
                bf[ni] = *(const i32x4*)(w1u + ((wid * 4 + ni) * 8 + kt) * 1024 + lo64);
            #pragma unroll
            for (int mi = 0; mi < 4; ++mi) {
                const int off = ((mi * 16 + l15) << 9) + p * 128 + ks * 64 + lk * 16;
                af[mi] = *(const i32x4*)(R0 + (off ^ swz));
            }
            #pragma unroll
            for (int mi = 0; mi < 4; ++mi)
                #pragma unroll
                for (int ni = 0; ni < 4; ++ni) mfma_bf16(acc[mi][ni], af[mi], bf[ni]);
        }
    }

    // ===== LN1 + relu -> H1 bf16 [64][512B] swz =====
    float bb[4], gg[4], ee[4];
    #pragma unroll
    for (int ni = 0; ni < 4; ++ni) {
        const int c = wid * 64 + ni * 16 + l15;
        bb[ni] = b1[u * 256 + c]; gg[ni] = g1[u * 256 + c]; ee[ni] = be1[u * 256 + c];
    }
    #pragma unroll
    for (int mi = 0; mi < 4; ++mi) {
        #pragma unroll
        for (int j = 0; j < 4; ++j) {
            float s = 0.f, q = 0.f;
            #pragma unroll
            for (int ni = 0; ni < 4; ++ni) {
                const float h = acc[mi][ni][j] * corru + bb[ni];
                acc[mi][ni][j] = h;
                s += h; q += h * h;
            }
            #pragma unroll
            for (int m = 1; m < 16; m <<= 1) { s += __shfl_xor(s, m); q += __shfl_xor(q, m); }
            if (l15 == 0) {
                const int r = mi * 16 + lk * 4 + j;
                pS[wid * 64 + r] = s; pQ[wid * 64 + r] = q;
            }
        }
    }
    __syncthreads();  // B1
    if (t < 64) {
        const float s = pS[t] + pS[64 + t] + pS[128 + t] + pS[192 + t];
        const float q = pQ[t] + pQ[64 + t] + pQ[128 + t] + pQ[192 + t];
        const float mean = s * (1.f / 256.f);
        const float var = fmaxf(q * (1.f / 256.f) - mean * mean, 0.f);
        rst[t] = make_float2(mean, rsqrtf(var + 1e-5f));
    }
    __syncthreads();  // B2
    #pragma unroll
    for (int mi = 0; mi < 4; ++mi) {
        #pragma unroll
        for (int j = 0; j < 4; ++j) {
            const int r = mi * 16 + lk * 4 + j;
            const float2 st = rst[r];
            #pragma unroll
            for (int ni = 0; ni < 4; ++ni) {
                const float h = fmaxf((acc[mi][ni][j] - st.x) * st.y * gg[ni] + ee[ni], 0.f);
                const int c = wid * 64 + ni * 16 + l15;
                const int off = (r << 9) + c * 2;
                *(__bf16*)(R0 + (off ^ ((r & 7) << 4))) = (__bf16)h;
            }
        }
    }
    __syncthreads();  // B3: H1 ready

    // ===== GEMM2: [64][128] = H1 @ W2t, K=256 =====
    f32x4 acc2[4][2];
    #pragma unroll
    for (int mi = 0; mi < 4; ++mi) { acc2[mi][0] = z4; acc2[mi][1] = z4; }
    for (int p = 0; p < 4; ++p) {
        #pragma unroll
        for (int ks = 0; ks < 2; ++ks) {
            i32x4 af[4], bf2[2];
            const int kt = p * 2 + ks;
            #pragma unroll
            for (int ni = 0; ni < 2; ++ni)
                bf2[ni] = *(const i32x4*)(w2u + ((wid * 2 + ni) * 8 + kt) * 1024 + lo64);
            #pragma unroll
            for (int mi = 0; mi < 4; ++mi) {
                const int off = ((mi * 16 + l15) << 9) + p * 128 + ks * 64 + lk * 16;
                af[mi] = *(const i32x4*)(R0 + (off ^ swz));
            }
            #pragma unroll
            for (int mi = 0; mi < 4; ++mi)
                #pragma unroll
                for (int ni = 0; ni < 2; ++ni) mfma_bf16(acc2[mi][ni], af[mi], bf2[ni]);
        }
    }

    // ===== LN2 + relu -> H2 bf16 [64][256B] at [0,16K) =====
    float bb2[2], gg2[2], ee2[2];
    #pragma unroll
    for (int ni = 0; ni < 2; ++ni) {
        const int c = wid * 32 + ni * 16 + l15;
        bb2[ni] = b2[u * 128 + c]; gg2[ni] = g2[u * 128 + c]; ee2[ni] = be2[u * 128 + c];
    }
    #pragma unroll
    for (int mi = 0; mi < 4; ++mi) {
        #pragma unroll
        for (int j = 0; j < 4; ++j) {
            float s = 0.f, q = 0.f;
            #pragma unroll
            for (int ni = 0; ni < 2; ++ni) {
                const float h = acc2[mi][ni][j] + bb2[ni];
                acc2[mi][ni][j] = h;
                s += h; q += h * h;
            }
            #pragma unroll
            for (int m = 1; m < 16; m <<= 1) { s += __shfl_xor(s, m); q += __shfl_xor(q, m); }
            if (l15 == 0) {
                const int r = mi * 16 + lk * 4 + j;
                pS[wid * 64 + r] = s; pQ[wid * 64 + r] = q;
            }
        }
    }
    __syncthreads();  // B4
    if (t < 64) {
        const float s = pS[t] + pS[64 + t] + pS[128 + t] + pS[192 + t];
        const float q = pQ[t] + pQ[64 + t] + pQ[128 + t] + pQ[192 + t];
        const float mean = s * (1.f / 128.f);
        const float var = fmaxf(q * (1.f / 128.f) - mean * mean, 0.f);
        rst[t] = make_float2(mean, rsqrtf(var + 1e-5f));
    }
    __syncthreads();  // B5
    #pragma unroll
    for (int mi = 0; mi < 4; ++mi) {
        #pragma unroll
        for (int j = 0; j < 4; ++j) {
            const int r = mi * 16 + lk * 4 + j;
            const float2 st = rst[r];
            #pragma unroll
            for (int ni = 0; ni < 2; ++ni) {
                const float h = fmaxf((acc2[mi][ni][j] - st.x) * st.y * gg2[ni] + ee2[ni], 0.f);
                const int c = wid * 32 + ni * 16 + l15;
                const int off = (r << 8) + c * 2;
                *(__bf16*)(R0 + (off ^ ((r & 7) << 4))) = (__bf16)h;
            }
        }
    }
    __syncthreads();  // B6: H2 ready

    // ===== GEMM3: enc [64][64] = H2 @ W3t, K=128 =====
    f32x4 acc3[4];
    #pragma unroll
    for (int mi = 0; mi < 4; ++mi) acc3[mi] = z4;
    #pragma unroll
    for (int ks = 0; ks < 4; ++ks) {
        const i32x4 bfr = *(const i32x4*)(w3u + (wid * 4 + ks) * 1024 + lo64);
        #pragma unroll
        for (int mi = 0; mi < 4; ++mi) {
            const int off = ((mi * 16 + l15) << 8) + ks * 64 + lk * 16;
            const i32x4 afm = *(const i32x4*)(R0 + (off ^ swz));
            mfma_bf16(acc3[mi], afm, bfr);
        }
    }
    // epilogue: +b3 (f32 encr regs), global enc write, sumsq partials
    const int c16 = wid * 16 + l15;
    const float b3v = b3[u * 64 + c16];
    float encr[4][4];
    #pragma unroll
    for (int mi = 0; mi < 4; ++mi) {
        #pragma unroll
        for (int j = 0; j < 4; ++j) {
            const float e = acc3[mi][j] + b3v;
            encr[mi][j] = e;
            const int r = mi * 16 + lk * 4 + j;
            enc_bfg[((size_t)(b0 + r) * 128 + u) * 64 + c16] = f2bf(e);
            float q = e * e;
            #pragma unroll
            for (int m = 1; m < 16; m <<= 1) q += __shfl_xor(q, m);
            if (l15 == 0) pQ[wid * 64 + r] = q;
        }
    }
    __syncthreads();  // B7: all GEMM3 H2-reads done, partials visible
    if (t < 64) {
        const float q = pQ[t] + pQ[64 + t] + pQ[128 + t] + pQ[192 + t];
        dmis[t] = tanhf(dmu * q);
    }
    // enc bf16 -> [0,8192) (old H2 low half, dead after B7)
    #pragma unroll
    for (int mi = 0; mi < 4; ++mi) {
        #pragma unroll
        for (int j = 0; j < 4; ++j) {
            const int r = mi * 16 + lk * 4 + j;
            const int off = (r << 7) + c16 * 2;
            *(__bf16*)(R0 + (off ^ ((r & 7) << 4))) = (__bf16)encr[mi][j];
        }
    }
    __syncthreads();  // B8: enc + dmis ready

    // ===== Wr: re [64][64] = enc_bf @ Wrt, K=64; z f32 -> [8192,25600) =====
    f32x4 accR[4];
    #pragma unroll
    for (int mi = 0; mi < 4; ++mi) accR[mi] = z4;
    #pragma unroll
    for (int ks = 0; ks < 2; ++ks) {
        const i32x4 bfr = *(const i32x4*)(wru + (wid * 2 + ks) * 1024 + lo64);
        #pragma unroll
        for (int mi = 0; mi < 4; ++mi) {
            const int off = ((mi * 16 + l15) << 7) + ks * 64 + lk * 16;
            const i32x4 afm = *(const i32x4*)(R0 + (off ^ swz));
            mfma_bf16(accR[mi], afm, bfr);
        }
    }
    const float brv = br[u * 64 + c16];
    #pragma unroll
    for (int mi = 0; mi < 4; ++mi) {
        #pragma unroll
        for (int j = 0; j < 4; ++j) {
            const int r = mi * 16 + lk * 4 + j;
            const float zv = accR[mi][j] + brv + dmis[r] * encr[mi][j];
            *(float*)(R0 + 8192 + r * 272 + c16 * 4) = zv;
        }
    }
    __syncthreads();  // B9: z ready, enc reads done

    // stage Wa1 f32 (8KB) -> [0,8192); Wa2 f32 (2KB) -> [25600); Wa3/ba3 -> [27648)
    #pragma unroll
    for (int it = 0; it < 2; ++it)
        gl_lds16((const char*)Wa1 + (size_t)u * 8192 + it * 4096 + t * 16,
                 R0 + it * 4096 + wid * 1024);
    if (t < 128)
        gl_lds16((const char*)Wa2 + (size_t)u * 2048 + t * 16, R0 + 25600 + wid * 1024);
    if (t < 16) ((float*)(R0 + 27648))[t] = Wa3[u * 16 + t];
    if (t == 16) ((float*)(R0 + 27648))[16] = ba3[u];
    __syncthreads();  // B10

    // ===== tail: a1 = relu(z@Wa1+ba1), fp32 =====
    {
        const int row = t >> 2, g4 = t & 3;
        float accA[8] = {0.f,0.f,0.f,0.f,0.f,0.f,0.f,0.f};
        const float* zrow = (const float*)(R0 + 8192 + row * 272);
        const float* wa1s = (const float*)R0;
        for (int k = 0; k < 64; ++k) {
            const float zv = zrow[k];
            const float4 wA = *(const float4*)(wa1s + k * 32 + g4 * 8);
            const float4 wB = *(const float4*)(wa1s + k * 32 + g4 * 8 + 4);
            accA[0] += zv * wA.x; accA[1] += zv * wA.y; accA[2] += zv * wA.z; accA[3] += zv * wA.w;
            accA[4] += zv * wB.x; accA[5] += zv * wB.y; accA[6] += zv * wB.z; accA[7] += zv * wB.w;
        }
        const float4 bA = *(const float4*)(ba1 + u * 32 + g4 * 8);
        const float4 bB = *(const float4*)(ba1 + u * 32 + g4 * 8 + 4);
        float* a1s = (float*)(R0 + 28160);
        a1s[row * 34 + g4 * 8 + 0] = fmaxf(accA[0] + bA.x, 0.f);
        a1s[row * 34 + g4 * 8 + 1] = fmaxf(accA[1] + bA.y, 0.f);
        a1s[row * 34 + g4 * 8 + 2] = fmaxf(accA[2] + bA.z, 0.f);
        a1s[row * 34 + g4 * 8 + 3] = fmaxf(accA[3] + bA.w, 0.f);
        a1s[row * 34 + g4 * 8 + 4] = fmaxf(accA[4] + bB.x, 0.f);
        a1s[row * 34 + g4 * 8 + 5] = fmaxf(accA[5] + bB.y, 0.f);
        a1s[row * 34 + g4 * 8 + 6] = fmaxf(accA[6] + bB.z, 0.f);
        a1s[row * 34 + g4 * 8 + 7] = fmaxf(accA[7] + bB.w, 0.f);
    }
    __syncthreads();  // B11: a1 ready, Wa1 reads done

    // ===== a2 = relu(a1@Wa2+ba2), fp32; a2 -> [0,4608) =====
    {
        const int row = t >> 2, g4 = t & 3;
        const float* a1s = (const float*)(R0 + 28160);
        const float* wa2s = (const float*)(R0 + 25600);
        float accB[4] = {0.f,0.f,0.f,0.f};
        for (int k = 0; k < 32; ++k) {
            const float av = a1s[row * 34 + k];
            const float4 w = *(const float4*)(wa2s + k * 16 + g4 * 4);
            accB[0] += av * w.x; accB[1] += av * w.y; accB[2] += av * w.z; accB[3] += av * w.w;
        }
        const float4 bB = *(const float4*)(ba2 + u * 16 + g4 * 4);
        float* a2s = (float*)R0;
        a2s[row * 18 + g4 * 4 + 0] = fmaxf(accB[0] + bB.x, 0.f);
        a2s[row * 18 + g4 * 4 + 1] = fmaxf(accB[1] + bB.y, 0.f);
        a2s[row * 18 + g4 * 4 + 2] = fmaxf(accB[2] + bB.z, 0.f);
        a2s[row * 18 + g4 * 4 + 3] = fmaxf(accB[3] + bB.w, 0.f);
    }
    __syncthreads();  // B12

    if (t < 64) {
        const float* a2s = (const float*)R0;
        const float* w3s = (const float*)(R0 + 27648);
        float a = w3s[16];
        #pragma unroll
        for (int k = 0; k < 16; ++k) a += a2s[t * 18 + k] * w3s[k];
        scores_g[(size_t)(b0 + t) * 128 + u] = 1.f / (1.f + __expf(-a));
    }
}

// ---------------- attention column-means (MFMA proj + register softmax) ----------------
__global__ __launch_bounds__(256, 2)
void attn_kernel(const unsigned short* __restrict__ enc_bf,
                 const unsigned short* __restrict__ wqkv_bf,
                 const float* __restrict__ bqkv, float* __restrict__ smean,
                 float* __restrict__ bpart)
{
    __shared__ __align__(128) char sm[65536];
    char* ENCs = sm;            // 16KB [128][64] bf16 swz
    char* Qs   = sm + 16384;    // 16KB [128][64] bf16 swz(addr>>10)
    char* Ks   = sm + 32768;    // 16KB
    char* WQs  = sm + 49152;    // 16KB Wqkv rows 0..127
    float* colp = (float*)sm;   // alias (ENC dead after proj)

    const int t = threadIdx.x;
    const int wid = t >> 6, lane = t & 63, l15 = lane & 15, lk = lane >> 4;
    const int swz = (l15 & 7) << 4;
    const int b = blockIdx.x;

    const char* eb = (const char*)(enc_bf + (size_t)b * 8192);
    #pragma unroll
    for (int it = 0; it < 4; ++it) {
        const int d = it * 4096 + t * 16;
        const int s = d ^ (((d >> 7) & 7) << 4);
        gl_lds16(eb + s, ENCs + it * 4096 + wid * 1024);
    }
    const char* wb = (const char*)wqkv_bf;
    #pragma unroll
    for (int it = 0; it < 4; ++it) {
        const int d = it * 4096 + t * 16;
        const int s = d ^ (((d >> 7) & 7) << 4);
        gl_lds16(wb + s, WQs + it * 4096 + wid * 1024);
    }
    __syncthreads();

    // ===== proj: Q,K [128][64] = enc @ Wqkv[0:64 / 64:128]^T =====
    const f32x4 z4 = {0.f,0.f,0.f,0.f};
    f32x4 aq[2][4], ak[2][4];
    #pragma unroll
    for (int mi = 0; mi < 2; ++mi)
        #pragma unroll
        for (int ni = 0; ni < 4; ++ni) { aq[mi][ni] = z4; ak[mi][ni] = z4; }

    i32x4 af[2][2];
    #pragma unroll
    for (int mi = 0; mi < 2; ++mi)
        #pragma unroll
        for (int ks = 0; ks < 2; ++ks) {
            const int off = ((wid * 32 + mi * 16 + l15) << 7) + ks * 64 + lk * 16;
            af[mi][ks] = *(const i32x4*)(ENCs + (off ^ swz));
        }
    #pragma unroll
    for (int ni = 0; ni < 4; ++ni)
        #pragma unroll
        for (int ks = 0; ks < 2; ++ks) {
            const int offq = ((ni * 16 + l15) << 7) + ks * 64 + lk * 16;
            const i32x4 bq = *(const i32x4*)(WQs + (offq ^ swz));
            mfma_bf16(aq[0][ni], af[0][ks], bq);
            mfma_bf16(aq[1][ni], af[1][ks], bq);
            const i32x4 bk = *(const i32x4*)(WQs + ((offq + 8192) ^ swz));
            mfma_bf16(ak[0][ni], af[0][ks], bk);
            mfma_bf16(ak[1][ni], af[1][ks], bk);
        }

    const float invsq = 0.35355339059327373f;
    float bqv[4], bkv[4];
    #pragma unroll
    for (int ni = 0; ni < 4; ++ni) {
        bqv[ni] = bqkv[ni * 16 + l15];
        bkv[ni] = bqkv[64 + ni * 16 + l15];
    }
    #pragma unroll
    for (int mi = 0; mi < 2; ++mi)
        #pragma unroll
        for (int ni = 0; ni < 4; ++ni)
            #pragma unroll
            for (int j = 0; j < 4; ++j) {
                const int row = wid * 32 + mi * 16 + lk * 4 + j;
                const int f = ni * 16 + l15;
                const int addr = row * 128 + f * 2;
                const int phys = addr ^ (((addr >> 10) & 7) << 4);
                *(__bf16*)(Qs + phys) = (__bf16)((aq[mi][ni][j] + bqv[ni]) * invsq);
                *(__bf16*)(Ks + phys) = (__bf16)(ak[mi][ni][j] + bkv[ni]);
            }
    __syncthreads();

    // ===== S = QK^T per head, register-tiled softmax + column sums =====
    const int cg = t & 7, qg = t >> 3;
    float cp[16];
    #pragma unroll
    for (int kk = 0; kk < 16; ++kk) cp[kk] = 0.f;

    for (int h = 0; h < 8; ++h) {
        float qv[4][8];
        #pragma unroll
        for (int j = 0; j < 4; ++j) {
            const int addr = (qg * 4 + j) * 128 + h * 16;
            const uint4 w = *(const uint4*)(Qs + (addr ^ (((addr >> 10) & 7) << 4)));
            qv[j][0]=bflo(w.x); qv[j][1]=bfhi(w.x); qv[j][2]=bflo(w.y); qv[j][3]=bfhi(w.y);
            qv[j][4]=bflo(w.z); qv[j][5]=bfhi(w.z); qv[j][6]=bflo(w.w); qv[j][7]=bfhi(w.w);
        }
        float s[4][16];
        #pragma unroll
        for (int j = 0; j < 4; ++j)
            #pragma unroll
            for (int kk = 0; kk < 16; ++kk) s[j][kk] = 0.f;
        #pragma unroll
        for (int kk = 0; kk < 16; ++kk) {
            const int addr = (cg * 16 + kk) * 128 + h * 16;
            const uint4 w = *(const uint4*)(Ks + (addr ^ (((addr >> 10) & 7) << 4)));
            float kv[8];
            kv[0]=bflo(w.x); kv[1]=bfhi(w.x); kv[2]=bflo(w.y); kv[3]=bfhi(w.y);
            kv[4]=bflo(w.z); kv[5]=bfhi(w.z); kv[6]=bflo(w.w); kv[7]=bfhi(w.w);
            #pragma unroll
            for (int j = 0; j < 4; ++j)
                #pragma unroll
                for (int d = 0; d < 8; ++d)
                    s[j][kk] += qv[j][d] * kv[d];
        }
        #pragma unroll
        for (int j = 0; j < 4; ++j) {
            float mx = s[j][0];
            #pragma unroll
            for (int kk = 1; kk < 16; ++kk) mx = fmaxf(mx, s[j][kk]);
            mx = fmaxf(mx, __shfl_xor(mx, 1));
            mx = fmaxf(mx, __shfl_xor(mx, 2));
            mx = fmaxf(mx, __shfl_xor(mx, 4));
            float z = 0.f;
            #pragma unroll
            for (int kk = 0; kk < 16; ++kk) { s[j][kk] = __expf(s[j][kk] - mx); z += s[j][kk]; }
            z += __shfl_xor(z, 1); z += __shfl_xor(z, 2); z += __shfl_xor(z, 4);
            const float zi = 1.f / z;
            #pragma unroll
            for (int kk = 0; kk < 16; ++kk) cp[kk] += s[j][kk] * zi;
        }
    }
    #pragma unroll
    for (int kk = 0; kk < 16; ++kk) {
        cp[kk] += __shfl_xor(cp[kk], 8);
        cp[kk] += __shfl_xor(cp[kk], 16);
        cp[kk] += __shfl_xor(cp[kk], 32);
    }
    if ((lane & 56) == 0) {
        #pragma unroll
        for (int kk = 0; kk < 16; ++kk) colp[wid * 128 + cg * 16 + kk] = cp[kk];
    }
    __syncthreads();
    float v = 0.f;
    if (t < 128) {
        v = colp[t] + colp[128 + t] + colp[256 + t] + colp[384 + t];
        smean[(size_t)b * 128 + t] = v * (1.f / 1024.f);
    }
    #pragma unroll
    for (int m = 1; m < 64; m <<= 1) v += __shfl_xor(v, m);
    if (lane == 0) colp[512 + wid] = v;
    __syncthreads();
    if (t == 0)
        bpart[b] = (colp[512] + colp[513] + colp[514] + colp[515]) * (1.f / 1024.f);
}

__global__ __launch_bounds__(64)
void final_kernel(const float* __restrict__ scores_g, const float* __restrict__ smean,
                  const float* __restrict__ Wc1, const float* __restrict__ bc1,
                  const float* __restrict__ Wc2, const float* __restrict__ bc2,
                  const float* __restrict__ Wc3, const float* __restrict__ bc3,
                  float* __restrict__ out)
{
    __shared__ float sc[128];
    __shared__ float c1[64];
    __shared__ float c2[32];
    const int b = blockIdx.x, t = threadIdx.x;
    const float s0 = scores_g[(size_t)b * 128 + t];
    const float s1 = scores_g[(size_t)b * 128 + 64 + t];
    sc[t] = s0; sc[64 + t] = s1;
    const float v0 = smean[(size_t)b * 128 + t];
    const float v1 = smean[(size_t)b * 128 + 64 + t];
    __syncthreads();
    float a = bc1[t];
    #pragma unroll 8
    for (int i = 0; i < 128; ++i) a += sc[i] * Wc1[i * 64 + t];
    c1[t] = fmaxf(a, 0.f);
    __syncthreads();
    if (t < 32) {
        float a2 = bc2[t];
        #pragma unroll 8
        for (int i = 0; i < 64; ++i) a2 += c1[i] * Wc2[i * 32 + t];
        c2[t] = fmaxf(a2, 0.f);
    }
    __syncthreads();
    float p = (t < 32) ? c2[t] * Wc3[t] : 0.f;
    #pragma unroll
    for (int m = 1; m < 64; m <<= 1) p += __shfl_xor(p, m);
    const float cons = 1.f / (1.f + __expf(-(p + bc3[0])));

    float sum = s0 + s1;
    float sq  = s0 * s0 + s1 * s1;
    float wsm = s0 * v0 + s1 * v1;
    float na  = (s0 > 0.1f ? 1.f : 0.f) + (s1 > 0.1f ? 1.f : 0.f);
    #pragma unroll
    for (int m = 1; m < 64; m <<= 1) {
        sum += __shfl_xor(sum, m); sq += __shfl_xor(sq, m);
        wsm += __shfl_xor(wsm, m); na += __shfl_xor(na, m);
    }
    if (t == 0) {
        const float mean = sum * (1.f / 128.f);
        float var = (sq - 128.f * mean * mean) * (1.f / 127.f);
        var = fmaxf(var, 0.f);
        const float agree = 1.f - sqrtf(var) / (mean + 1e-8f);
        out[b]        = cons * wsm;
        out[1024 + b] = (cons > 0.95f) ? 1.f : 0.f;
        out[2048 + b] = agree;
        out[3072 + b] = cons;
        out[4097 + b] = na;
    }
}

__global__ __launch_bounds__(256)
void attnmean_kernel(const float* __restrict__ bpart, float* __restrict__ out)
{
    __shared__ float red[4];
    const int t = threadIdx.x;
    const int lane = t & 63, wid = t >> 6;
    float s = bpart[t] + bpart[256 + t] + bpart[512 + t] + bpart[768 + t];
    #pragma unroll
    for (int m = 1; m < 64; m <<= 1) s += __shfl_xor(s, m);
    if (lane == 0) red[wid] = s;
    __syncthreads();
    if (t == 0) out[4096] = (red[0] + red[1] + red[2] + red[3]) * (1.f / 131072.f);
}

extern "C" void kernel_launch(void* const* d_in, const int* in_sizes, int n_in,
                              void* d_out, int out_size, void* d_ws, size_t ws_size,
                              hipStream_t stream)
{
    const float* x    = (const float*)d_in[0];
    const float* fs   = (const float*)d_in[1];
    const float* dm   = (const float*)d_in[2];
    const float* W1   = (const float*)d_in[3];
    const float* b1   = (const float*)d_in[4];
    const float* g1   = (const float*)d_in[5];
    const float* be1  = (const float*)d_in[6];
    const float* W2   = (const float*)d_in[7];
    const float* b2   = (const float*)d_in[8];
    const float* g2   = (const float*)d_in[9];
    const float* be2  = (const float*)d_in[10];
    const float* W3   = (const float*)d_in[11];
    const float* b3   = (const float*)d_in[12];
    const float* Wr   = (const float*)d_in[13];
    const float* br   = (const float*)d_in[14];
    const float* Wa1  = (const float*)d_in[15];
    const float* ba1  = (const float*)d_in[16];
    const float* Wa2  = (const float*)d_in[17];
    const float* ba2  = (const float*)d_in[18];
    const float* Wa3  = (const float*)d_in[19];
    const float* ba3  = (const float*)d_in[20];
    const float* Wqkv = (const float*)d_in[21];
    const float* bqkv = (const float*)d_in[22];
    // d_in[23]=Wo, d_in[24]=bo unused downstream
    const float* Wc1  = (const float*)d_in[25];
    const float* bc1  = (const float*)d_in[26];
    const float* Wc2  = (const float*)d_in[27];
    const float* bc2  = (const float*)d_in[28];
    const float* Wc3  = (const float*)d_in[29];
    const float* bc3  = (const float*)d_in[30];

    float* out = (float*)d_out;
    char*  ws8 = (char*)d_ws;
    unsigned short* enc_bf = (unsigned short*)ws8;             // 16 MB
    float* scores = (float*)(ws8 + 16777216);                  // 512 KB
    float* smean  = (float*)(ws8 + 17301504);                  // 512 KB
    float* bpart  = (float*)(ws8 + 17825792);                  // 4 KB
    unsigned short* xb    = (unsigned short*)(ws8 + 17829888); // 512 KB
    unsigned short* W1t   = (unsigned short*)(ws8 + 18354176); // 16 MB
    unsigned short* W2t   = (unsigned short*)(ws8 + 35131392); // 8 MB
    unsigned short* W3t   = (unsigned short*)(ws8 + 43520000); // 2 MB
    unsigned short* Wrt   = (unsigned short*)(ws8 + 45617152); // 1 MB
    unsigned short* wqkvb = (unsigned short*)(ws8 + 46665728); // 16 KB

    prep_kernel<<<3588, 256, 0, stream>>>(W1, W2, W3, Wr, x, Wqkv,
                                          W1t, W2t, W3t, Wrt, xb, wqkvb);
    fused_mfma<<<2048, 256, 0, stream>>>(xb, W1t, W2t, W3t, Wrt, fs, dm,
                                         b1, g1, be1, b2, g2, be2, b3, br,
                                         Wa1, ba1, Wa2, ba2, Wa3, ba3,
                                         enc_bf, scores);
    attn_kernel<<<1024, 256, 0, stream>>>(enc_bf, wqkvb, bqkv, smean, bpart);
    final_kernel<<<1024, 64, 0, stream>>>(scores, smean, Wc1, bc1, Wc2, bc2, Wc3, bc3, out);
    attnmean_kernel<<<1, 256, 0, stream>>>(bpart, out);
}

// Round 8
// 148.886 us; speedup vs baseline: 7.1613x; 1.3722x over previous
//
#include <hip/hip_runtime.h>
#include <math.h>

// U=128, D=256, B=1024, E=64, H=8
// prep_kernel : f32 -> bf16 frag-tiled weights [n/16][k/32][16][32] + x/wqkv -> bf16
// fused_mfma  : per (u, 64-row batch tile): big GEMMs via MFMA with DIRECT global
//               B-fragment loads; fp32 tail. (unchanged from round 6)
// attn_kernel : MFMA Q/K proj + per-head MFMA S (zero-padded Q, K=32, in-row
//               wrapped B reads) + in-register softmax + column sums
// final/attnmean: outputs (unchanged)

typedef float f32x4 __attribute__((ext_vector_type(4)));
typedef int   i32x4 __attribute__((ext_vector_type(4)));

__device__ __forceinline__ void mfma_bf16(f32x4& c, i32x4 a, i32x4 b) {
    asm("v_mfma_f32_16x16x32_bf16 %0, %1, %2, %0" : "+v"(c) : "v"(a), "v"(b));
}

__device__ __forceinline__ void gl_lds16(const void* g, void* l) {
    __builtin_amdgcn_global_load_lds(
        (const __attribute__((address_space(1))) unsigned int*)g,
        (__attribute__((address_space(3))) unsigned int*)l, 16, 0, 0);
}

__device__ __forceinline__ unsigned short f2bf(float v) {
    union { __bf16 b; unsigned short u; } cv;
    cv.b = (__bf16)v;
    return cv.u;
}

// ---------------- prep: convert + frag-tile weights to bf16 ----------------
__global__ __launch_bounds__(256)
void prep_kernel(const float* __restrict__ W1, const float* __restrict__ W2,
                 const float* __restrict__ W3, const float* __restrict__ Wr,
                 const float* __restrict__ x, const float* __restrict__ Wqkv,
                 unsigned short* __restrict__ W1t, unsigned short* __restrict__ W2t,
                 unsigned short* __restrict__ W3t, unsigned short* __restrict__ Wrt,
                 unsigned short* __restrict__ xb, unsigned short* __restrict__ wqkvb)
{
    const int bid = blockIdx.x, t = threadIdx.x;
    if (bid >= 3456) {  // plain convert, no transpose
        const float* src; unsigned short* dst; int base;
        if (bid >= 3584) { src = Wqkv; dst = wqkvb; base = (bid - 3584) * 2048 + t * 8; }
        else             { src = x;    dst = xb;    base = (bid - 3456) * 2048 + t * 8; }
        const float4 v0 = *(const float4*)(src + base);
        const float4 v1 = *(const float4*)(src + base + 4);
        __align__(16) unsigned short o[8];
        o[0]=f2bf(v0.x); o[1]=f2bf(v0.y); o[2]=f2bf(v0.z); o[3]=f2bf(v0.w);
        o[4]=f2bf(v1.x); o[5]=f2bf(v1.y); o[6]=f2bf(v1.z); o[7]=f2bf(v1.w);
        *(uint4*)(dst + base) = *(const uint4*)o;
        return;
    }
    const float* src; unsigned short* dst; int u, k0, n0, N, ktiles;
    if (bid < 2048)      { u = bid >> 4;        int tl = bid & 15;       k0 = (tl>>2)*64; n0 = (tl&3)*64; N=256; ktiles=8; src = W1 + (size_t)u*65536; dst = W1t + (size_t)u*65536; }
    else if (bid < 3072) { int b2 = bid - 2048; u = b2 >> 3; int tl = b2 & 7; k0 = (tl>>1)*64; n0 = (tl&1)*64; N=128; ktiles=8; src = W2 + (size_t)u*32768; dst = W2t + (size_t)u*32768; }
    else if (bid < 3328) { int b3 = bid - 3072; u = b3 >> 1; int tl = b3 & 1; k0 = tl*64;      n0 = 0;         N=64;  ktiles=4; src = W3 + (size_t)u*8192;  dst = W3t + (size_t)u*8192;  }
    else                 { u = bid - 3328;      k0 = 0; n0 = 0;                                 N=64;  ktiles=2; src = Wr + (size_t)u*4096;  dst = Wrt + (size_t)u*4096;  }

    __shared__ unsigned short tile[64 * 65];
    #pragma unroll
    for (int i = 0; i < 16; ++i) {
        const int e = i * 256 + t;
        const int kk = e >> 6, nn = e & 63;
        tile[kk * 65 + nn] = f2bf(src[(size_t)(k0 + kk) * N + n0 + nn]);
    }
    __syncthreads();
    #pragma unroll
    for (int i = 0; i < 16; ++i) {
        const int e = i * 256 + t;
        const int nn = e >> 6, kk = e & 63;
        const int n = n0 + nn, k = k0 + kk;
        dst[(size_t)(((n >> 4) * ktiles + (k >> 5)) * 512 + (n & 15) * 32 + (k & 31))] = tile[kk * 65 + nn];
    }
}

// ---------------- fused universe chain (unchanged from round 6) ----------------
__global__ __launch_bounds__(256, 4)
void fused_mfma(const unsigned short* __restrict__ xb,
                const unsigned short* __restrict__ W1t, const unsigned short* __restrict__ W2t,
                const unsigned short* __restrict__ W3t, const unsigned short* __restrict__ Wrt,
                const float* __restrict__ fs, const float* __restrict__ dm,
                const float* __restrict__ b1, const float* __restrict__ g1, const float* __restrict__ be1,
                const float* __restrict__ b2, const float* __restrict__ g2, const float* __restrict__ be2,
                const float* __restrict__ b3, const float* __restrict__ br,
                const float* __restrict__ Wa1, const float* __restrict__ ba1,
                const float* __restrict__ Wa2, const float* __restrict__ ba2,
                const float* __restrict__ Wa3, const float* __restrict__ ba3,
                unsigned short* __restrict__ enc_bfg, float* __restrict__ scores_g)
{
    __shared__ __align__(128) char sm[39680];
    char* R0 = sm;
    float* pS = (float*)(sm + 36864);
    float* pQ = (float*)(sm + 37888);
    float2* rst = (float2*)(sm + 38912);
    float* dmis = (float*)(sm + 39424);

    const int t = threadIdx.x;
    const int wid = t >> 6, lane = t & 63, l15 = lane & 15, lk = lane >> 4;
    const int swz = (l15 & 7) << 4;
    const int lo64 = l15 * 64 + lk * 16;
    const int bx = blockIdx.x;
    const int xcd = bx & 7, idx = bx >> 3;
    const int u = ((idx >> 4) << 3) + xcd;
    const int b0 = (idx & 15) * 64;

    const float corru = fs[u] * 137.036f;
    const float dmu = dm[u];

    const char* xbase = (const char*)xb + (size_t)b0 * 512;
    const char* w1u = (const char*)W1t + (size_t)u * 131072;
    const char* w2u = (const char*)W2t + (size_t)u * 65536;
    const char* w3u = (const char*)W3t + (size_t)u * 16384;
    const char* wru = (const char*)Wrt + (size_t)u * 8192;

    #pragma unroll
    for (int it = 0; it < 8; ++it) {
        const int d = it * 4096 + t * 16;
        const int s = d ^ (((d >> 9) & 7) << 4);
        gl_lds16(xbase + s, R0 + it * 4096 + wid * 1024);
    }
    __syncthreads();  // B0

    const f32x4 z4 = {0.f, 0.f, 0.f, 0.f};
    f32x4 acc[4][4];
    #pragma unroll
    for (int mi = 0; mi < 4; ++mi)
        #pragma unroll
        for (int ni = 0; ni < 4; ++ni) acc[mi][ni] = z4;

    for (int p = 0; p < 4; ++p) {
        #pragma unroll
        for (int ks = 0; ks < 2; ++ks) {
            i32x4 af[4], bf[4];
            const int kt = p * 2 + ks;
            #pragma unroll
            for (int ni = 0; ni < 4; ++ni)
                bf[ni] = *(const i32x4*)(w1u + ((wid * 4 + ni) * 8 + kt) * 1024 + lo64);
            #pragma unroll
            for (int mi = 0; mi < 4; ++mi) {
                const int off = ((mi * 16 + l15) << 9) + p * 128 + ks * 64 + lk * 16;
                af[mi] = *(const i32x4*)(R0 + (off ^ swz));
            }
            #pragma unroll
            for (int mi = 0; mi < 4; ++mi)
                #pragma unroll
                for (int ni = 0; ni < 4; ++ni) mfma_bf16(acc[mi][ni], af[mi], bf[ni]);
        }
    }

    float bb[4], gg[4], ee[4];
    #pragma unroll
    for (int ni = 0; ni < 4; ++ni) {
        const int c = wid * 64 + ni * 16 + l15;
        bb[ni] = b1[u * 256 + c]; gg[ni] = g1[u * 256 + c]; ee[ni] = be1[u * 256 + c];
    }
    #pragma unroll
    for (int mi = 0; mi < 4; ++mi) {
        #pragma unroll
        for (int j = 0; j < 4; ++j) {
            float s = 0.f, q = 0.f;
            #pragma unroll
            for (int ni = 0; ni < 4; ++ni) {
                const float h = acc[mi][ni][j] * corru + bb[ni];
                acc[mi][ni][j] = h;
                s += h; q += h * h;
            }
            #pragma unroll
            for (int m = 1; m < 16; m <<= 1) { s += __shfl_xor(s, m); q += __shfl_xor(q, m); }
            if (l15 == 0) {
                const int r = mi * 16 + lk * 4 + j;
                pS[wid * 64 + r] = s; pQ[wid * 64 + r] = q;
            }
        }
    }
    __syncthreads();  // B1
    if (t < 64) {
        const float s = pS[t] + pS[64 + t] + pS[128 + t] + pS[192 + t];
        const float q = pQ[t] + pQ[64 + t] + pQ[128 + t] + pQ[192 + t];
        const float mean = s * (1.f / 256.f);
        const float var = fmaxf(q * (1.f / 256.f) - mean * mean, 0.f);
        rst[t] = make_float2(mean, rsqrtf(var + 1e-5f));
    }
    __syncthreads();  // B2
    #pragma unroll
    for (int mi = 0; mi < 4; ++mi) {
        #pragma unroll
        for (int j = 0; j < 4; ++j) {
            const int r = mi * 16 + lk * 4 + j;
            const float2 st = rst[r];
            #pragma unroll
            for (int ni = 0; ni < 4; ++ni) {
                const float h = fmaxf((acc[mi][ni][j] - st.x) * st.y * gg[ni] + ee[ni], 0.f);
                const int c = wid * 64 + ni * 16 + l15;
                const int off = (r << 9) + c * 2;
                *(__bf16*)(R0 + (off ^ ((r & 7) << 4))) = (__bf16)h;
            }
        }
    }
    __syncthreads();  // B3

    f32x4 acc2[4][2];
    #pragma unroll
    for (int mi = 0; mi < 4; ++mi) { acc2[mi][0] = z4; acc2[mi][1] = z4; }
    for (int p = 0; p < 4; ++p) {
        #pragma unroll
        for (int ks = 0; ks < 2; ++ks) {
            i32x4 af[4], bf2[2];
            const int kt = p * 2 + ks;
            #pragma unroll
            for (int ni = 0; ni < 2; ++ni)
                bf2[ni] = *(const i32x4*)(w2u + ((wid * 2 + ni) * 8 + kt) * 1024 + lo64);
            #pragma unroll
            for (int mi = 0; mi < 4; ++mi) {
                const int off = ((mi * 16 + l15) << 9) + p * 128 + ks * 64 + lk * 16;
                af[mi] = *(const i32x4*)(R0 + (off ^ swz));
            }
            #pragma unroll
            for (int mi = 0; mi < 4; ++mi)
                #pragma unroll
                for (int ni = 0; ni < 2; ++ni) mfma_bf16(acc2[mi][ni], af[mi], bf2[ni]);
        }
    }

    float bb2[2], gg2[2], ee2[2];
    #pragma unroll
    for (int ni = 0; ni < 2; ++ni) {
        const int c = wid * 32 + ni * 16 + l15;
        bb2[ni] = b2[u * 128 + c]; gg2[ni] = g2[u * 128 + c]; ee2[ni] = be2[u * 128 + c];
    }
    #pragma unroll
    for (int mi = 0; mi < 4; ++mi) {
        #pragma unroll
        for (int j = 0; j < 4; ++j) {
            float s = 0.f, q = 0.f;
            #pragma unroll
            for (int ni = 0; ni < 2; ++ni) {
                const float h = acc2[mi][ni][j] + bb2[ni];
                acc2[mi][ni][j] = h;
                s += h; q += h * h;
            }
            #pragma unroll
            for (int m = 1; m < 16; m <<= 1) { s += __shfl_xor(s, m); q += __shfl_xor(q, m); }
            if (l15 == 0) {
                const int r = mi * 16 + lk * 4 + j;
                pS[wid * 64 + r] = s; pQ[wid * 64 + r] = q;
            }
        }
    }
    __syncthreads();  // B4
    if (t < 64) {
        const float s = pS[t] + pS[64 + t] + pS[128 + t] + pS[192 + t];
        const float q = pQ[t] + pQ[64 + t] + pQ[128 + t] + pQ[192 + t];
        const float mean = s * (1.f / 128.f);
        const float var = fmaxf(q * (1.f / 128.f) - mean * mean, 0.f);
        rst[t] = make_float2(mean, rsqrtf(var + 1e-5f));
    }
    __syncthreads();  // B5
    #pragma unroll
    for (int mi = 0; mi < 4; ++mi) {
        #pragma unroll
        for (int j = 0; j < 4; ++j) {
            const int r = mi * 16 + lk * 4 + j;
            const float2 st = rst[r];
            #pragma unroll
            for (int ni = 0; ni < 2; ++ni) {
                const float h = fmaxf((acc2[mi][ni][j] - st.x) * st.y * gg2[ni] + ee2[ni], 0.f);
                const int c = wid * 32 + ni * 16 + l15;
                const int off = (r << 8) + c * 2;
                *(__bf16*)(R0 + (off ^ ((r & 7) << 4))) = (__bf16)h;
            }
        }
    }
    __syncthreads();  // B6

    f32x4 acc3[4];
    #pragma unroll
    for (int mi = 0; mi < 4; ++mi) acc3[mi] = z4;
    #pragma unroll
    for (int ks = 0; ks < 4; ++ks) {
        const i32x4 bfr = *(const i32x4*)(w3u + (wid * 4 + ks) * 1024 + lo64);
        #pragma unroll
        for (int mi = 0; mi < 4; ++mi) {
            const int off = ((mi * 16 + l15) << 8) + ks * 64 + lk * 16;
            const i32x4 afm = *(const i32x4*)(R0 + (off ^ swz));
            mfma_bf16(acc3[mi], afm, bfr);
        }
    }
    const int c16 = wid * 16 + l15;
    const float b3v = b3[u * 64 + c16];
    float encr[4][4];
    #pragma unroll
    for (int mi = 0; mi < 4; ++mi) {
        #pragma unroll
        for (int j = 0; j < 4; ++j) {
            const float e = acc3[mi][j] + b3v;
            encr[mi][j] = e;
            const int r = mi * 16 + lk * 4 + j;
            enc_bfg[((size_t)(b0 + r) * 128 + u) * 64 + c16] = f2bf(e);
            float q = e * e;
            #pragma unroll
            for (int m = 1; m < 16; m <<= 1) q += __shfl_xor(q, m);
            if (l15 == 0) pQ[wid * 64 + r] = q;
        }
    }
    __syncthreads();  // B7
    if (t < 64) {
        const float q = pQ[t] + pQ[64 + t] + pQ[128 + t] + pQ[192 + t];
        dmis[t] = tanhf(dmu * q);
    }
    #pragma unroll
    for (int mi = 0; mi < 4; ++mi) {
        #pragma unroll
        for (int j = 0; j < 4; ++j) {
            const int r = mi * 16 + lk * 4 + j;
            const int off = (r << 7) + c16 * 2;
            *(__bf16*)(R0 + (off ^ ((r & 7) << 4))) = (__bf16)encr[mi][j];
        }
    }
    __syncthreads();  // B8

    f32x4 accR[4];
    #pragma unroll
    for (int mi = 0; mi < 4; ++mi) accR[mi] = z4;
    #pragma unroll
    for (int ks = 0; ks < 2; ++ks) {
        const i32x4 bfr = *(const i32x4*)(wru + (wid * 2 + ks) * 1024 + lo64);
        #pragma unroll
        for (int mi = 0; mi < 4; ++mi) {
            const int off = ((mi * 16 + l15) << 7) + ks * 64 + lk * 16;
            const i32x4 afm = *(const i32x4*)(R0 + (off ^ swz));
            mfma_bf16(accR[mi], afm, bfr);
        }
    }
    const float brv = br[u * 64 + c16];
    #pragma unroll
    for (int mi = 0; mi < 4; ++mi) {
        #pragma unroll
        for (int j = 0; j < 4; ++j) {
            const int r = mi * 16 + lk * 4 + j;
            const float zv = accR[mi][j] + brv + dmis[r] * encr[mi][j];
            *(float*)(R0 + 8192 + r * 272 + c16 * 4) = zv;
        }
    }
    __syncthreads();  // B9

    #pragma unroll
    for (int it = 0; it < 2; ++it)
        gl_lds16((const char*)Wa1 + (size_t)u * 8192 + it * 4096 + t * 16,
                 R0 + it * 4096 + wid * 1024);
    if (t < 128)
        gl_lds16((const char*)Wa2 + (size_t)u * 2048 + t * 16, R0 + 25600 + wid * 1024);
    if (t < 16) ((float*)(R0 + 27648))[t] = Wa3[u * 16 + t];
    if (t == 16) ((float*)(R0 + 27648))[16] = ba3[u];
    __syncthreads();  // B10

    {
        const int row = t >> 2, g4 = t & 3;
        float accA[8] = {0.f,0.f,0.f,0.f,0.f,0.f,0.f,0.f};
        const float* zrow = (const float*)(R0 + 8192 + row * 272);
        const float* wa1s = (const float*)R0;
        for (int k = 0; k < 64; ++k) {
            const float zv = zrow[k];
            const float4 wA = *(const float4*)(wa1s + k * 32 + g4 * 8);
            const float4 wB = *(const float4*)(wa1s + k * 32 + g4 * 8 + 4);
            accA[0] += zv * wA.x; accA[1] += zv * wA.y; accA[2] += zv * wA.z; accA[3] += zv * wA.w;
            accA[4] += zv * wB.x; accA[5] += zv * wB.y; accA[6] += zv * wB.z; accA[7] += zv * wB.w;
        }
        const float4 bA = *(const float4*)(ba1 + u * 32 + g4 * 8);
        const float4 bB = *(const float4*)(ba1 + u * 32 + g4 * 8 + 4);
        float* a1s = (float*)(R0 + 28160);
        a1s[row * 34 + g4 * 8 + 0] = fmaxf(accA[0] + bA.x, 0.f);
        a1s[row * 34 + g4 * 8 + 1] = fmaxf(accA[1] + bA.y, 0.f);
        a1s[row * 34 + g4 * 8 + 2] = fmaxf(accA[2] + bA.z, 0.f);
        a1s[row * 34 + g4 * 8 + 3] = fmaxf(accA[3] + bA.w, 0.f);
        a1s[row * 34 + g4 * 8 + 4] = fmaxf(accA[4] + bB.x, 0.f);
        a1s[row * 34 + g4 * 8 + 5] = fmaxf(accA[5] + bB.y, 0.f);
        a1s[row * 34 + g4 * 8 + 6] = fmaxf(accA[6] + bB.z, 0.f);
        a1s[row * 34 + g4 * 8 + 7] = fmaxf(accA[7] + bB.w, 0.f);
    }
    __syncthreads();  // B11

    {
        const int row = t >> 2, g4 = t & 3;
        const float* a1s = (const float*)(R0 + 28160);
        const float* wa2s = (const float*)(R0 + 25600);
        float accB[4] = {0.f,0.f,0.f,0.f};
        for (int k = 0; k < 32; ++k) {
            const float av = a1s[row * 34 + k];
            const float4 w = *(const float4*)(wa2s + k * 16 + g4 * 4);
            accB[0] += av * w.x; accB[1] += av * w.y; accB[2] += av * w.z; accB[3] += av * w.w;
        }
        const float4 bB = *(const float4*)(ba2 + u * 16 + g4 * 4);
        float* a2s = (float*)R0;
        a2s[row * 18 + g4 * 4 + 0] = fmaxf(accB[0] + bB.x, 0.f);
        a2s[row * 18 + g4 * 4 + 1] = fmaxf(accB[1] + bB.y, 0.f);
        a2s[row * 18 + g4 * 4 + 2] = fmaxf(accB[2] + bB.z, 0.f);
        a2s[row * 18 + g4 * 4 + 3] = fmaxf(accB[3] + bB.w, 0.f);
    }
    __syncthreads();  // B12

    if (t < 64) {
        const float* a2s = (const float*)R0;
        const float* w3s = (const float*)(R0 + 27648);
        float a = w3s[16];
        #pragma unroll
        for (int k = 0; k < 16; ++k) a += a2s[t * 18 + k] * w3s[k];
        scores_g[(size_t)(b0 + t) * 128 + u] = 1.f / (1.f + __expf(-a));
    }
}

// ---------------- attention: MFMA proj + per-head MFMA S + register softmax ----------------
__global__ __launch_bounds__(256, 3)
void attn_kernel(const unsigned short* __restrict__ enc_bf,
                 const unsigned short* __restrict__ wqkv_bf,
                 const float* __restrict__ bqkv, float* __restrict__ smean,
                 float* __restrict__ bpart)
{
    // LDS: Qp [2][128][32]bf16 (pads zero) at [0,16K); Ks [128][64]bf16 swz at
    // [16K,32K); colp at 32832 (4*128+4 f32).
    // Staging aliases: ENCs=[0,16K), WQs=[16K,32K).
    __shared__ __align__(128) char sm[34944];
    char* Qp = sm;
    char* Ks = sm + 16384;
    float* colp = (float*)(sm + 32832);
    char* ENCs = sm;
    char* WQs  = sm + 16384;

    const int t = threadIdx.x;
    const int wid = t >> 6, lane = t & 63, l15 = lane & 15, lk = lane >> 4;
    const int swz = (l15 & 7) << 4;
    const int b = blockIdx.x;

    const char* eb = (const char*)(enc_bf + (size_t)b * 8192);
    #pragma unroll
    for (int it = 0; it < 4; ++it) {
        const int d = it * 4096 + t * 16;
        const int s = d ^ (((d >> 7) & 7) << 4);
        gl_lds16(eb + s, ENCs + it * 4096 + wid * 1024);
    }
    const char* wb = (const char*)wqkv_bf;
    #pragma unroll
    for (int it = 0; it < 4; ++it) {
        const int d = it * 4096 + t * 16;
        const int s = d ^ (((d >> 7) & 7) << 4);
        gl_lds16(wb + s, WQs + it * 4096 + wid * 1024);
    }
    __syncthreads();

    // ===== proj: Q,K [128][64] = enc @ Wqkv^T (each wave: its 32 rows) =====
    const f32x4 z4 = {0.f,0.f,0.f,0.f};
    f32x4 aq[2][4], ak[2][4];
    #pragma unroll
    for (int mi = 0; mi < 2; ++mi)
        #pragma unroll
        for (int ni = 0; ni < 4; ++ni) { aq[mi][ni] = z4; ak[mi][ni] = z4; }

    i32x4 af[2][2];
    #pragma unroll
    for (int mi = 0; mi < 2; ++mi)
        #pragma unroll
        for (int ks = 0; ks < 2; ++ks) {
            const int off = ((wid * 32 + mi * 16 + l15) << 7) + ks * 64 + lk * 16;
            af[mi][ks] = *(const i32x4*)(ENCs + (off ^ swz));
        }
    #pragma unroll
    for (int ni = 0; ni < 4; ++ni)
        #pragma unroll
        for (int ks = 0; ks < 2; ++ks) {
            const int offq = ((ni * 16 + l15) << 7) + ks * 64 + lk * 16;
            const i32x4 bq = *(const i32x4*)(WQs + (offq ^ swz));
            mfma_bf16(aq[0][ni], af[0][ks], bq);
            mfma_bf16(aq[1][ni], af[1][ks], bq);
            const i32x4 bk = *(const i32x4*)(WQs + ((offq + 8192) ^ swz));
            mfma_bf16(ak[0][ni], af[0][ks], bk);
            mfma_bf16(ak[1][ni], af[1][ks], bk);
        }

    float bqv[4], bkv[4];
    #pragma unroll
    for (int ni = 0; ni < 4; ++ni) {
        bqv[ni] = bqkv[ni * 16 + l15];
        bkv[ni] = bqkv[64 + ni * 16 + l15];
    }
    __syncthreads();  // proj LDS reads complete in all waves

    // zero Qp pads (dims 8..31 of each of 2*128 rows)
    {
        const int par = t >> 7, row = t & 127;
        char* base = Qp + par * 8192 + row * 64;
        *(f32x4*)(base + 16) = z4;
        *(f32x4*)(base + 32) = z4;
        *(f32x4*)(base + 48) = z4;
    }
    // write K full [128][64] swz (each wave its own rows; all cols)
    #pragma unroll
    for (int mi = 0; mi < 2; ++mi)
        #pragma unroll
        for (int ni = 0; ni < 4; ++ni)
            #pragma unroll
            for (int j = 0; j < 4; ++j) {
                const int row = wid * 32 + mi * 16 + lk * 4 + j;
                const int f = ni * 16 + l15;
                const int off = row * 128 + f * 2;
                *(__bf16*)(Ks + (off ^ ((row & 7) << 4))) = (__bf16)(ak[mi][ni][j] + bkv[ni]);
            }
    __syncthreads();  // Ks + pads ready

    const float qscale = 0.35355339059327373f;  // 1/sqrt(8)
    float cp[8] = {0.f,0.f,0.f,0.f,0.f,0.f,0.f,0.f};

    #pragma unroll
    for (int p = 0; p < 4; ++p) {
        // pack Q for head pair (2p, 2p+1): feature f = p*16 + l15 -> head 2p+(l15>>3), dim l15&7
        #pragma unroll
        for (int mi = 0; mi < 2; ++mi)
            #pragma unroll
            for (int j = 0; j < 4; ++j) {
                const int row = wid * 32 + mi * 16 + lk * 4 + j;
                *(__bf16*)(Qp + (l15 >> 3) * 8192 + row * 64 + (l15 & 7) * 2) =
                    (__bf16)((aq[mi][p][j] + bqv[p]) * qscale);
            }
        __syncthreads();  // pack visible

        #pragma unroll 1
        for (int par = 0; par < 2; ++par) {
            const int h = p * 2 + par;
            // A-frags: own 32 rows, K=32 (dims 8..31 zero)
            const i32x4 aQ0 = *(const i32x4*)(Qp + par * 8192 + (wid * 32 + l15) * 64 + lk * 16);
            const i32x4 aQ1 = *(const i32x4*)(Qp + par * 8192 + (wid * 32 + 16 + l15) * 64 + lk * 16);
            f32x4 accS[2][8];
            #pragma unroll
            for (int ci = 0; ci < 8; ++ci) { accS[0][ci] = z4; accS[1][ci] = z4; }
            #pragma unroll
            for (int ci = 0; ci < 8; ++ci) {
                const int col = ci * 16 + l15;
                // B: head block WRAPPED in-row ((h+lk)&7) so k>=8 lanes read real,
                // FINITE K data (multiplied by A's exact-zero pads -> 0).
                // NOTE: un-wrapped overread hit stale LDS; bf16 views of stale f32
                // bits can be Inf/NaN and 0*Inf = NaN (round-7 failure).
                const i32x4 bK = *(const i32x4*)(Ks + ((col * 128 + ((h + lk) & 7) * 16) ^ ((col & 7) << 4)));
                mfma_bf16(accS[0][ci], aQ0, bK);
                mfma_bf16(accS[1][ci], aQ1, bK);
            }
            // softmax rows (no max-pass: |S| small) + column accumulation
            #pragma unroll
            for (int mi = 0; mi < 2; ++mi)
                #pragma unroll
                for (int j = 0; j < 4; ++j) {
                    float e[8];
                    float z = 0.f;
                    #pragma unroll
                    for (int ci = 0; ci < 8; ++ci) { e[ci] = __expf(accS[mi][ci][j]); z += e[ci]; }
                    z += __shfl_xor(z, 1); z += __shfl_xor(z, 2);
                    z += __shfl_xor(z, 4); z += __shfl_xor(z, 8);
                    const float zi = 1.f / z;
                    #pragma unroll
                    for (int ci = 0; ci < 8; ++ci) cp[ci] += e[ci] * zi;
                }
        }
        __syncthreads();  // S reads done before next pack overwrites Qp
    }

    // reduce cp over lk, store per-wave column sums
    #pragma unroll
    for (int ci = 0; ci < 8; ++ci) {
        cp[ci] += __shfl_xor(cp[ci], 16);
        cp[ci] += __shfl_xor(cp[ci], 32);
    }
    if (lk == 0) {
        #pragma unroll
        for (int ci = 0; ci < 8; ++ci)
            colp[wid * 128 + ci * 16 + l15] = cp[ci];
    }
    __syncthreads();
    float v = 0.f;
    if (t < 128) {
        v = colp[t] + colp[128 + t] + colp[256 + t] + colp[384 + t];
        smean[(size_t)b * 128 + t] = v * (1.f / 1024.f);
    }
    #pragma unroll
    for (int m = 1; m < 64; m <<= 1) v += __shfl_xor(v, m);
    if (lane == 0) colp[512 + wid] = v;
    __syncthreads();
    if (t == 0)
        bpart[b] = (colp[512] + colp[513] + colp[514] + colp[515]) * (1.f / 1024.f);
}

__global__ __launch_bounds__(64)
void final_kernel(const float* __restrict__ scores_g, const float* __restrict__ smean,
                  const float* __restrict__ Wc1, const float* __restrict__ bc1,
                  const float* __restrict__ Wc2, const float* __restrict__ bc2,
                  const float* __restrict__ Wc3, const float* __restrict__ bc3,
                  float* __restrict__ out)
{
    __shared__ float sc[128];
    __shared__ float c1[64];
    __shared__ float c2[32];
    const int b = blockIdx.x, t = threadIdx.x;
    const float s0 = scores_g[(size_t)b * 128 + t];
    const float s1 = scores_g[(size_t)b * 128 + 64 + t];
    sc[t] = s0; sc[64 + t] = s1;
    const float v0 = smean[(size_t)b * 128 + t];
    const float v1 = smean[(size_t)b * 128 + 64 + t];
    __syncthreads();
    float a = bc1[t];
    #pragma unroll 8
    for (int i = 0; i < 128; ++i) a += sc[i] * Wc1[i * 64 + t];
    c1[t] = fmaxf(a, 0.f);
    __syncthreads();
    if (t < 32) {
        float a2 = bc2[t];
        #pragma unroll 8
        for (int i = 0; i < 64; ++i) a2 += c1[i] * Wc2[i * 32 + t];
        c2[t] = fmaxf(a2, 0.f);
    }
    __syncthreads();
    float p = (t < 32) ? c2[t] * Wc3[t] : 0.f;
    #pragma unroll
    for (int m = 1; m < 64; m <<= 1) p += __shfl_xor(p, m);
    const float cons = 1.f / (1.f + __expf(-(p + bc3[0])));

    float sum = s0 + s1;
    float sq  = s0 * s0 + s1 * s1;
    float wsm = s0 * v0 + s1 * v1;
    float na  = (s0 > 0.1f ? 1.f : 0.f) + (s1 > 0.1f ? 1.f : 0.f);
    #pragma unroll
    for (int m = 1; m < 64; m <<= 1) {
        sum += __shfl_xor(sum, m); sq += __shfl_xor(sq, m);
        wsm += __shfl_xor(wsm, m); na += __shfl_xor(na, m);
    }
    if (t == 0) {
        const float mean = sum * (1.f / 128.f);
        float var = (sq - 128.f * mean * mean) * (1.f / 127.f);
        var = fmaxf(var, 0.f);
        const float agree = 1.f - sqrtf(var) / (mean + 1e-8f);
        out[b]        = cons * wsm;
        out[1024 + b] = (cons > 0.95f) ? 1.f : 0.f;
        out[2048 + b] = agree;
        out[3072 + b] = cons;
        out[4097 + b] = na;
    }
}

__global__ __launch_bounds__(256)
void attnmean_kernel(const float* __restrict__ bpart, float* __restrict__ out)
{
    __shared__ float red[4];
    const int t = threadIdx.x;
    const int lane = t & 63, wid = t >> 6;
    float s = bpart[t] + bpart[256 + t] + bpart[512 + t] + bpart[768 + t];
    #pragma unroll
    for (int m = 1; m < 64; m <<= 1) s += __shfl_xor(s, m);
    if (lane == 0) red[wid] = s;
    __syncthreads();
    if (t == 0) out[4096] = (red[0] + red[1] + red[2] + red[3]) * (1.f / 131072.f);
}

extern "C" void kernel_launch(void* const* d_in, const int* in_sizes, int n_in,
                              void* d_out, int out_size, void* d_ws, size_t ws_size,
                              hipStream_t stream)
{
    const float* x    = (const float*)d_in[0];
    const float* fs   = (const float*)d_in[1];
    const float* dm   = (const float*)d_in[2];
    const float* W1   = (const float*)d_in[3];
    const float* b1   = (const float*)d_in[4];
    const float* g1   = (const float*)d_in[5];
    const float* be1  = (const float*)d_in[6];
    const float* W2   = (const float*)d_in[7];
    const float* b2   = (const float*)d_in[8];
    const float* g2   = (const float*)d_in[9];
    const float* be2  = (const float*)d_in[10];
    const float* W3   = (const float*)d_in[11];
    const float* b3   = (const float*)d_in[12];
    const float* Wr   = (const float*)d_in[13];
    const float* br   = (const float*)d_in[14];
    const float* Wa1  = (const float*)d_in[15];
    const float* ba1  = (const float*)d_in[16];
    const float* Wa2  = (const float*)d_in[17];
    const float* ba2  = (const float*)d_in[18];
    const float* Wa3  = (const float*)d_in[19];
    const float* ba3  = (const float*)d_in[20];
    const float* Wqkv = (const float*)d_in[21];
    const float* bqkv = (const float*)d_in[22];
    // d_in[23]=Wo, d_in[24]=bo unused downstream
    const float* Wc1  = (const float*)d_in[25];
    const float* bc1  = (const float*)d_in[26];
    const float* Wc2  = (const float*)d_in[27];
    const float* bc2  = (const float*)d_in[28];
    const float* Wc3  = (const float*)d_in[29];
    const float* bc3  = (const float*)d_in[30];

    float* out = (float*)d_out;
    char*  ws8 = (char*)d_ws;
    unsigned short* enc_bf = (unsigned short*)ws8;             // 16 MB
    float* scores = (float*)(ws8 + 16777216);                  // 512 KB
    float* smean  = (float*)(ws8 + 17301504);                  // 512 KB
    float* bpart  = (float*)(ws8 + 17825792);                  // 4 KB
    unsigned short* xb    = (unsigned short*)(ws8 + 17829888); // 512 KB
    unsigned short* W1t   = (unsigned short*)(ws8 + 18354176); // 16 MB
    unsigned short* W2t   = (unsigned short*)(ws8 + 35131392); // 8 MB
    unsigned short* W3t   = (unsigned short*)(ws8 + 43520000); // 2 MB
    unsigned short* Wrt   = (unsigned short*)(ws8 + 45617152); // 1 MB
    unsigned short* wqkvb = (unsigned short*)(ws8 + 46665728); // 16 KB

    prep_kernel<<<3588, 256, 0, stream>>>(W1, W2, W3, Wr, x, Wqkv,
                                          W1t, W2t, W3t, Wrt, xb, wqkvb);
    fused_mfma<<<2048, 256, 0, stream>>>(xb, W1t, W2t, W3t, Wrt, fs, dm,
                                         b1, g1, be1, b2, g2, be2, b3, br,
                                         Wa1, ba1, Wa2, ba2, Wa3, ba3,
                                         enc_bf, scores);
    attn_kernel<<<1024, 256, 0, stream>>>(enc_bf, wqkvb, bqkv, smean, bpart);
    final_kernel<<<1024, 64, 0, stream>>>(scores, smean, Wc1, bc1, Wc2, bc2, Wc3, bc3, out);
    attnmean_kernel<<<1, 256, 0, stream>>>(bpart, out);
}